// Round 6
// baseline (1345.991 us; speedup 1.0000x reference)
//
#include <hip/hip_runtime.h>

// ---------------------------------------------------------------------------
// GCN: 5x GCNConv + final linear.  N=100000, E=1.6M, D_IN=D_H=128, N_CLS=100.
//
// Collapsed algebra (see R1-R3): h1 = relu(S x W1 + 1 b1^T),
//   out = S^4 h1 Wc + S^3 1 c2^T + S^2 1 c3^T + S 1 c4^T + 1 cb^T.
// Feature buffers are COLUMN-SLICED fp16: buf[slice][node][16], slice=0..7,
// and agg blocks pick slice = blockIdx.x%8 -> XCD-affine (round-robin
// dispatch) so each XCD's 4MB L2 holds its 3.2MB slice: gathers become L2 hits.
// s_k = S^k 1 ride along as columns 100..102 (slice 6).
// ---------------------------------------------------------------------------

typedef _Float16 h16;
typedef _Float16 __attribute__((ext_vector_type(2))) h16x2;
typedef _Float16 __attribute__((ext_vector_type(4))) h16x4;
typedef _Float16 __attribute__((ext_vector_type(8))) h16x8;
typedef float __attribute__((ext_vector_type(4))) f32x4;

static __device__ __forceinline__ float f4get(const float4& v, int k) {
  switch (k) { case 0: return v.x; case 1: return v.y; case 2: return v.z; default: return v.w; }
}

// ---- edge dtype detection: if input is int64, odd int32 slots (hi words) are 0
__global__ void k_detect(const int* __restrict__ edge, int* __restrict__ flag) {
  int t = threadIdx.x;
  if (edge[2 * t + 1] != 0) atomicOr(flag, 1);
}

static __device__ __forceinline__ int load_idx(const int* edge, const int* flag, size_t pos) {
  bool is64 = (*flag == 0);
  if (is64) return (int)((const long long*)edge)[pos];
  return edge[pos];
}

__global__ void k_count(const int* __restrict__ edge, const int* __restrict__ flag,
                        int* __restrict__ counts, int* __restrict__ rank, int E) {
  int i = blockIdx.x * 256 + threadIdx.x;
  if (i >= E) return;
  int d = load_idx(edge, flag, (size_t)E + i);
  rank[i] = atomicAdd(&counts[d], 1);
}

__global__ void k_dinv(const int* __restrict__ counts, float* __restrict__ dinv, int n) {
  int i = blockIdx.x * 256 + threadIdx.x;
  if (i < n) dinv[i] = rsqrtf((float)counts[i] + 1.0f);
}

// ---- CSR build: chunk sums -> root scan -> per-chunk rescan ----
__global__ void k_chunksum(const int* __restrict__ counts, int* __restrict__ chunksums, int n) {
  __shared__ int sd[256];
  int t = threadIdx.x;
  int base = blockIdx.x * 1024 + t * 4;
  int s = 0;
#pragma unroll
  for (int j = 0; j < 4; ++j) { int i = base + j; if (i < n) s += counts[i]; }
  sd[t] = s; __syncthreads();
  for (int off = 128; off > 0; off >>= 1) {
    if (t < off) sd[t] += sd[t + off];
    __syncthreads();
  }
  if (t == 0) chunksums[blockIdx.x] = sd[0];
}

__global__ void k_root(const int* __restrict__ chunksums, int* __restrict__ chunkbase, int nchunks) {
  __shared__ int sc[128];
  int t = threadIdx.x;
  int v = (t < nchunks) ? chunksums[t] : 0;
  sc[t] = v; __syncthreads();
  for (int off = 1; off < 128; off <<= 1) {
    int x = (t >= off) ? sc[t - off] : 0;
    __syncthreads();
    sc[t] += x;
    __syncthreads();
  }
  if (t < nchunks) chunkbase[t] = sc[t] - v;
}

__global__ void k_scan3(const int* __restrict__ counts, const int* __restrict__ chunkbase,
                        int* __restrict__ offsets, int n, int E) {
  __shared__ int sd[256];
  int t = threadIdx.x;
  int base = blockIdx.x * 1024 + t * 4;
  int c[4]; int s = 0;
#pragma unroll
  for (int j = 0; j < 4; ++j) { int i = base + j; c[j] = (i < n) ? counts[i] : 0; s += c[j]; }
  sd[t] = s; __syncthreads();
  int v = s;
  for (int off = 1; off < 256; off <<= 1) {
    int x = (t >= off) ? sd[t - off] : 0;
    __syncthreads();
    sd[t] += x;
    __syncthreads();
  }
  int run = chunkbase[blockIdx.x] + sd[t] - v;
#pragma unroll
  for (int j = 0; j < 4; ++j) {
    int i = base + j;
    if (i < n) offsets[i] = run;
    run += c[j];
  }
  if (blockIdx.x == 0 && t == 0) offsets[n] = E;
}

__global__ void k_fill(const int* __restrict__ edge, const int* __restrict__ flag,
                       const int* __restrict__ offsets, const int* __restrict__ rank,
                       int* __restrict__ col, int E) {
  int i = blockIdx.x * 256 + threadIdx.x;
  if (i >= E) return;
  int s = load_idx(edge, flag, (size_t)i);
  int d = load_idx(edge, flag, (size_t)E + i);
  col[offsets[d] + rank[i]] = s;
}

// ---- tiny fp64 matmul for the weight chain ----
template <typename TB>
__global__ void k_smm(const float* __restrict__ A, const TB* __restrict__ B,
                      double* __restrict__ C, int M, int K, int Nc) {
  int idx = blockIdx.x * 256 + threadIdx.x;
  if (idx >= M * Nc) return;
  int i = idx / Nc, j = idx % Nc;
  double acc = 0.0;
  for (int k = 0; k < K; ++k) acc += (double)A[i * K + k] * (double)B[k * Nc + j];
  C[idx] = acc;
}

__global__ void k_d2f(const double* __restrict__ in, float* __restrict__ out, int n) {
  int i = blockIdx.x * 256 + threadIdx.x;
  if (i < n) out[i] = (float)in[i];
}

__global__ void k_cvec(const float* __restrict__ b2, const float* __restrict__ b3,
                       const float* __restrict__ b4, const float* __restrict__ b5,
                       const float* __restrict__ bl, const float* __restrict__ Wl,
                       const double* __restrict__ R3, const double* __restrict__ R4,
                       const double* __restrict__ R5, double* __restrict__ corr) {
  int j = threadIdx.x;
  if (j >= 100) return;
  double a2 = 0.0, a3 = 0.0, a4 = 0.0, acb = 0.0;
  for (int k = 0; k < 128; ++k) {
    a2 += (double)b2[k] * R3[k * 100 + j];
    a3 += (double)b3[k] * R4[k * 100 + j];
    a4 += (double)b4[k] * R5[k * 100 + j];
  }
  for (int k = 0; k < 100; ++k) acb += (double)b5[k] * (double)Wl[k * 100 + j];
  corr[j] = a2; corr[128 + j] = a3; corr[256 + j] = a4; corr[384 + j] = acb + (double)bl[j];
}

// ---- matmul: out sliced fp16 [8][n][16]; out[r][c] = (X@W)[r][c]*dinv[r].
// Split-K chunks of 32 -> LDS 34.5 KB -> 3-4 blocks/CU.
// AUG: col 100 = dinv[r] (s-chain seed), cols >=M (and 101..127) = 0.
template <typename TX, int K, int M, int AUG>
__launch_bounds__(256)
__global__ void k_mm(const TX* __restrict__ X, const float* __restrict__ W,
                     const float* __restrict__ dinv, h16* __restrict__ out, int n) {
  __shared__ float Xs[128 * 36];
  __shared__ float Ws[32 * 132];
  int tid = threadIdx.x;
  int row0 = blockIdx.x * 128;
  int tc = tid & 15, tr = tid >> 4;
  int c0 = tc * 8;
  float acc[8][8];
#pragma unroll
  for (int i = 0; i < 8; ++i)
#pragma unroll
    for (int j = 0; j < 8; ++j) acc[i][j] = 0.f;

  for (int kc = 0; kc < K; kc += 32) {
    __syncthreads();
    // stage W chunk rows kc..kc+31, cols 0..127 (zero-pad past M)
    for (int idx = tid * 4; idx < 32 * 128; idx += 1024) {
      int r = idx >> 7, c = idx & 127;
      float4 v = make_float4(0.f, 0.f, 0.f, 0.f);
      if (c < M) v = *(const float4*)&W[(size_t)(kc + r) * M + c];
      *(float4*)&Ws[r * 132 + c] = v;
    }
    // stage X chunk rows 0..127, cols kc..kc+31
    if (sizeof(TX) == 4) {
      for (int idx = tid * 4; idx < 128 * 32; idx += 1024) {
        int r = idx >> 5, c = idx & 31;
        f32x4 v = {0.f, 0.f, 0.f, 0.f};
        if (row0 + r < n)
          v = __builtin_nontemporal_load(
              (const f32x4*)&((const float*)X)[(size_t)(row0 + r) * K + kc + c]);
        *(f32x4*)&Xs[r * 36 + c] = v;
      }
    } else {
      for (int idx = tid * 8; idx < 128 * 32; idx += 2048) {
        int r = idx >> 5, c = idx & 31;      // c in {0,8,16,24}
        int gc = kc + c;
        float f[8];
#pragma unroll
        for (int q = 0; q < 8; ++q) f[q] = 0.f;
        if (row0 + r < n) {
          const h16* p = &((const h16*)X)[((size_t)(gc >> 4) * n + row0 + r) * 16 + (gc & 15)];
          h16x8 v8 = __builtin_nontemporal_load((const h16x8*)p);
#pragma unroll
          for (int q = 0; q < 8; ++q) f[q] = (float)v8[q];
        }
        *(float4*)&Xs[r * 36 + c]     = make_float4(f[0], f[1], f[2], f[3]);
        *(float4*)&Xs[r * 36 + c + 4] = make_float4(f[4], f[5], f[6], f[7]);
      }
    }
    __syncthreads();

    for (int k = 0; k < 32; k += 4) {
      float4 xf[8];
#pragma unroll
      for (int i = 0; i < 8; ++i) xf[i] = *(const float4*)&Xs[(tr + 16 * i) * 36 + k];
      float4 wa[4], wb[4];
#pragma unroll
      for (int kk = 0; kk < 4; ++kk) {
        wa[kk] = *(const float4*)&Ws[(k + kk) * 132 + c0];
        wb[kk] = *(const float4*)&Ws[(k + kk) * 132 + c0 + 4];
      }
#pragma unroll
      for (int i = 0; i < 8; ++i) {
#pragma unroll
        for (int kk = 0; kk < 4; ++kk) {
          float xv = f4get(xf[i], kk);
          acc[i][0] = fmaf(xv, wa[kk].x, acc[i][0]);
          acc[i][1] = fmaf(xv, wa[kk].y, acc[i][1]);
          acc[i][2] = fmaf(xv, wa[kk].z, acc[i][2]);
          acc[i][3] = fmaf(xv, wa[kk].w, acc[i][3]);
          acc[i][4] = fmaf(xv, wb[kk].x, acc[i][4]);
          acc[i][5] = fmaf(xv, wb[kk].y, acc[i][5]);
          acc[i][6] = fmaf(xv, wb[kk].z, acc[i][6]);
          acc[i][7] = fmaf(xv, wb[kk].w, acc[i][7]);
        }
      }
    }
  }

  // epilogue: sliced fp16 write (nt -> don't pollute this XCD's L2)
#pragma unroll
  for (int i = 0; i < 8; ++i) {
    int grow = row0 + tr + 16 * i;
    if (grow >= n) continue;
    float sc = dinv[grow];
    h16x8 pk;
#pragma unroll
    for (int j = 0; j < 8; ++j) {
      int colj = c0 + j;
      float vv = (colj < M) ? acc[i][j] * sc : ((AUG && colj == 100) ? sc : 0.f);
      pk[j] = (h16)vv;
    }
    h16* o = &out[((size_t)(c0 >> 4) * n + grow) * 16 + (c0 & 15)];
    __builtin_nontemporal_store(pk, (h16x8*)o);
  }
}

// ---- sliced aggregation.  slice = blockIdx%8 (XCD-affine); 8 lanes/node.
// MODE 0: relu(dinv*(sum+self)+bias), 8 slices.  MODE 1: dinv^2*(sum+self)
// (pre-scaled), slices 0..6, fresh col seeded = dinv.  MODE 2: final + rank-1
// corrections -> fp32 out [n][100], slices 0..6.
template <int MODE>
__global__ void k_agg(const h16* __restrict__ hs, const int* __restrict__ offsets,
                      const int* __restrict__ col, const float* __restrict__ dinv,
                      const float* __restrict__ bias, const double* __restrict__ corr,
                      void* __restrict__ out, int n, int fresh) {
  int slice = blockIdx.x & 7;
  if (MODE != 0 && slice == 7) return;
  int tid = threadIdx.x;
  int lane = tid & 63;
  int g = lane >> 3, sub = lane & 7;
  int v = (int)(blockIdx.x >> 3) * 32 + (tid >> 6) * 8 + g;
  if (v >= n) return;
  int c = slice * 16 + sub * 2;
  if (MODE == 2 && c >= 100) return;
  const size_t sbase = (size_t)slice * n * 16;
  const int coff = sub * 2;
  h16x2 sv = *(const h16x2*)&hs[sbase + (size_t)v * 16 + coff];
  float ax = (float)sv.x, ay = (float)sv.y;
  int s = offsets[v], e = offsets[v + 1];
  for (int i = s; i < e; i += 8) {
    float mx[8], my[8];
#pragma unroll
    for (int j = 0; j < 8; ++j) {
      int idx = i + j;
      bool ok = idx < e;
      int u = ok ? __builtin_nontemporal_load(&col[idx]) : v;
      h16x2 t = *(const h16x2*)&hs[sbase + (size_t)u * 16 + coff];
      mx[j] = ok ? (float)t.x : 0.f;
      my[j] = ok ? (float)t.y : 0.f;
    }
#pragma unroll
    for (int j = 0; j < 8; ++j) { ax += mx[j]; ay += my[j]; }
  }
  float w = dinv[v];
  if (MODE == 0) {
    float rx = fmaxf(fmaf(ax, w, bias[c]), 0.f);
    float ry = fmaxf(fmaf(ay, w, bias[c + 1]), 0.f);
    h16x2 p; p.x = (h16)rx; p.y = (h16)ry;
    *(h16x2*)&((h16*)out)[sbase + (size_t)v * 16 + coff] = p;
  } else if (MODE == 1) {
    float w2 = w * w;
    float rx = ax * w2, ry = ay * w2;
    if (c == fresh) rx = w;             // seed column: dinv * 1
    else if (c + 1 == fresh) ry = w;
    h16x2 p; p.x = (h16)rx; p.y = (h16)ry;
    *(h16x2*)&((h16*)out)[sbase + (size_t)v * 16 + coff] = p;
  } else {
    // s-chain scalars live in slice 6, in-slice cols 4..6 (global 100..102)
    h16x4 sc4 = *(const h16x4*)&hs[((size_t)6 * n + v) * 16 + 4];
    float inv_w = 1.0f / w;
    float v3 = (float)sc4[0] * inv_w, v2 = (float)sc4[1] * inv_w, v1 = (float)sc4[2] * inv_w;
    float rx = ax * w + v3 * (float)corr[c]     + v2 * (float)corr[128 + c]
             + v1 * (float)corr[256 + c] + (float)corr[384 + c];
    float ry = ay * w + v3 * (float)corr[c + 1] + v2 * (float)corr[128 + c + 1]
             + v1 * (float)corr[256 + c + 1] + (float)corr[384 + c + 1];
    *(float2*)&((float*)out)[(size_t)v * 100 + c] = make_float2(rx, ry);
  }
}

// ---------------------------------------------------------------------------
extern "C" void kernel_launch(void* const* d_in, const int* in_sizes, int n_in,
                              void* d_out, int out_size, void* d_ws, size_t ws_size,
                              hipStream_t stream) {
  const float* x    = (const float*)d_in[0];
  const int*   edge = (const int*)d_in[1];
  const float* W1 = (const float*)d_in[2];  const float* b1 = (const float*)d_in[3];
  const float* W2 = (const float*)d_in[4];  const float* b2 = (const float*)d_in[5];
  const float* W3 = (const float*)d_in[6];  const float* b3 = (const float*)d_in[7];
  const float* W4 = (const float*)d_in[8];  const float* b4 = (const float*)d_in[9];
  const float* W5 = (const float*)d_in[10]; const float* b5 = (const float*)d_in[11];
  const float* Wl = (const float*)d_in[12]; const float* bl = (const float*)d_in[13];

  const int N = in_sizes[0] / 128;
  const int E = in_sizes[1] / 2;

  char* ws = (char*)d_ws;
  size_t cur = 0;
  auto alloc = [&](size_t bytes) -> char* {
    char* p = ws + cur;
    cur = (cur + bytes + 255) & ~(size_t)255;
    return p;
  };
  int*    counts    = (int*)alloc((size_t)N * 4);
  int*    flag      = (int*)alloc(4);
  int*    offsets   = (int*)alloc((size_t)(N + 1) * 4);
  float*  dinv      = (float*)alloc((size_t)N * 4);
  int*    chunksums = (int*)alloc(128 * 4);
  int*    chunkbase = (int*)alloc(128 * 4);
  double* R5        = (double*)alloc(128 * 100 * 8);
  double* R4        = (double*)alloc(128 * 100 * 8);
  double* R3        = (double*)alloc(128 * 100 * 8);
  double* Wcd       = (double*)alloc(128 * 100 * 8);
  float*  Wc        = (float*)alloc(128 * 100 * 4);
  double* corr      = (double*)alloc(512 * 8);
  int*    rank      = (int*)alloc((size_t)E * 4);
  int*    col       = (int*)alloc(((size_t)E + 8) * 4);   // +pad for group reads
  h16*    bufA      = (h16*)alloc((size_t)8 * N * 16 * 2);
  h16*    bufB      = (h16*)alloc((size_t)8 * N * 16 * 2);
  (void)ws_size; (void)n_in; (void)out_size;

  hipMemsetAsync(counts, 0, (size_t)N * 4, stream);
  hipMemsetAsync(flag, 0, 4, stream);

  const int nchunks = (N + 1023) / 1024;
  const int egrid = (E + 255) / 256;
  const int ngrid = (N + 255) / 256;

  k_detect<<<1, 256, 0, stream>>>(edge, flag);
  k_count<<<egrid, 256, 0, stream>>>(edge, flag, counts, rank, E);
  k_dinv<<<ngrid, 256, 0, stream>>>(counts, dinv, N);
  k_chunksum<<<nchunks, 256, 0, stream>>>(counts, chunksums, N);
  k_root<<<1, 128, 0, stream>>>(chunksums, chunkbase, nchunks);
  k_scan3<<<nchunks, 256, 0, stream>>>(counts, chunkbase, offsets, N, E);
  k_fill<<<egrid, 256, 0, stream>>>(edge, flag, offsets, rank, col, E);

  // weight chain (fp64): R5 = W5 Wl; R4 = W4 R5; R3 = W3 R4; Wc = W2 R3
  const int sgrid = (128 * 100 + 255) / 256;
  k_smm<float><<<sgrid, 256, 0, stream>>>(W5, Wl, R5, 128, 100, 100);
  k_smm<double><<<sgrid, 256, 0, stream>>>(W4, R5, R4, 128, 128, 100);
  k_smm<double><<<sgrid, 256, 0, stream>>>(W3, R4, R3, 128, 128, 100);
  k_smm<double><<<sgrid, 256, 0, stream>>>(W2, R3, Wcd, 128, 128, 100);
  k_d2f<<<sgrid, 256, 0, stream>>>(Wcd, Wc, 128 * 100);
  k_cvec<<<1, 128, 0, stream>>>(b2, b3, b4, b5, bl, Wl, R3, R4, R5, corr);

  const int mmgrid = (N + 127) / 128;
  const int agrid = ((N + 31) / 32) * 8;

  // hs0 = (x W1) * dinv  [sliced fp16]
  k_mm<float, 128, 128, 0><<<mmgrid, 256, 0, stream>>>(x, W1, dinv, bufA, N);
  // h1 = relu(dinv*(gather+self) + b1)
  k_agg<0><<<agrid, 256, 0, stream>>>(bufA, offsets, col, dinv, b1, nullptr, bufB, N, 0);
  // g_scaled = (h1 Wc) * dinv, col100 = dinv seed
  k_mm<h16, 128, 100, 1><<<mmgrid, 256, 0, stream>>>(bufB, Wc, dinv, bufA, N);
  // three chained S applications (pre-scaled); s-chain in cols 100..102
  k_agg<1><<<agrid, 256, 0, stream>>>(bufA, offsets, col, dinv, nullptr, nullptr, bufB, N, 101);
  k_agg<1><<<agrid, 256, 0, stream>>>(bufB, offsets, col, dinv, nullptr, nullptr, bufA, N, 102);
  k_agg<1><<<agrid, 256, 0, stream>>>(bufA, offsets, col, dinv, nullptr, nullptr, bufB, N, -1);
  // final S application + corrections -> d_out [fp32, N x 100]
  k_agg<2><<<agrid, 256, 0, stream>>>(bufB, offsets, col, dinv, nullptr, corr, (float*)d_out, N, -1);
}

// Round 7
// 1039.118 us; speedup vs baseline: 1.2953x; 1.2953x over previous
//
#include <hip/hip_runtime.h>

// ---------------------------------------------------------------------------
// GCN: 5x GCNConv + final linear.  N=100000, E=1.6M, D_IN=D_H=128, N_CLS=100.
//
// Collapsed algebra (R1-R3): h1 = relu(S x W1 + 1 b1^T),
//   out = S^4 h1 Wc + S^3 1 c2^T + S^2 1 c3^T + S 1 c4^T + 1 cb^T,
// weight chain in fp64 on device.  s_k = S^k 1 ride as feature cols 100..102.
// Feature buffers fp16 row-major (stride 128 / 104).  R6's column slicing
// REVERTED (divergence + no L2 win).  Split-K matmul kept (occupancy).
// Nontemporal on streaming col reads + output stores (keep L2 for gathers).
// ---------------------------------------------------------------------------

typedef _Float16 h16;
typedef _Float16 __attribute__((ext_vector_type(2))) h16x2;
typedef _Float16 __attribute__((ext_vector_type(8))) h16x8;
typedef float __attribute__((ext_vector_type(2))) f32x2;
typedef float __attribute__((ext_vector_type(4))) f32x4;

static __device__ __forceinline__ float f4get(const float4& v, int k) {
  switch (k) { case 0: return v.x; case 1: return v.y; case 2: return v.z; default: return v.w; }
}

// ---- edge dtype detection: if input is int64, odd int32 slots (hi words) are 0
__global__ void k_detect(const int* __restrict__ edge, int* __restrict__ flag) {
  int t = threadIdx.x;
  if (edge[2 * t + 1] != 0) atomicOr(flag, 1);
}

static __device__ __forceinline__ int load_idx(const int* edge, const int* flag, size_t pos) {
  bool is64 = (*flag == 0);
  if (is64) return (int)((const long long*)edge)[pos];
  return edge[pos];
}

__global__ void k_count(const int* __restrict__ edge, const int* __restrict__ flag,
                        int* __restrict__ counts, int* __restrict__ rank, int E) {
  int i = blockIdx.x * 256 + threadIdx.x;
  if (i >= E) return;
  int d = load_idx(edge, flag, (size_t)E + i);
  rank[i] = atomicAdd(&counts[d], 1);
}

__global__ void k_dinv(const int* __restrict__ counts, float* __restrict__ dinv, int n) {
  int i = blockIdx.x * 256 + threadIdx.x;
  if (i < n) dinv[i] = rsqrtf((float)counts[i] + 1.0f);
}

// ---- CSR build: chunk sums -> root scan -> per-chunk rescan ----
__global__ void k_chunksum(const int* __restrict__ counts, int* __restrict__ chunksums, int n) {
  __shared__ int sd[256];
  int t = threadIdx.x;
  int base = blockIdx.x * 1024 + t * 4;
  int s = 0;
#pragma unroll
  for (int j = 0; j < 4; ++j) { int i = base + j; if (i < n) s += counts[i]; }
  sd[t] = s; __syncthreads();
  for (int off = 128; off > 0; off >>= 1) {
    if (t < off) sd[t] += sd[t + off];
    __syncthreads();
  }
  if (t == 0) chunksums[blockIdx.x] = sd[0];
}

__global__ void k_root(const int* __restrict__ chunksums, int* __restrict__ chunkbase, int nchunks) {
  __shared__ int sc[128];
  int t = threadIdx.x;
  int v = (t < nchunks) ? chunksums[t] : 0;
  sc[t] = v; __syncthreads();
  for (int off = 1; off < 128; off <<= 1) {
    int x = (t >= off) ? sc[t - off] : 0;
    __syncthreads();
    sc[t] += x;
    __syncthreads();
  }
  if (t < nchunks) chunkbase[t] = sc[t] - v;
}

__global__ void k_scan3(const int* __restrict__ counts, const int* __restrict__ chunkbase,
                        int* __restrict__ offsets, int n, int E) {
  __shared__ int sd[256];
  int t = threadIdx.x;
  int base = blockIdx.x * 1024 + t * 4;
  int c[4]; int s = 0;
#pragma unroll
  for (int j = 0; j < 4; ++j) { int i = base + j; c[j] = (i < n) ? counts[i] : 0; s += c[j]; }
  sd[t] = s; __syncthreads();
  int v = s;
  for (int off = 1; off < 256; off <<= 1) {
    int x = (t >= off) ? sd[t - off] : 0;
    __syncthreads();
    sd[t] += x;
    __syncthreads();
  }
  int run = chunkbase[blockIdx.x] + sd[t] - v;
#pragma unroll
  for (int j = 0; j < 4; ++j) {
    int i = base + j;
    if (i < n) offsets[i] = run;
    run += c[j];
  }
  if (blockIdx.x == 0 && t == 0) offsets[n] = E;
}

__global__ void k_fill(const int* __restrict__ edge, const int* __restrict__ flag,
                       const int* __restrict__ offsets, const int* __restrict__ rank,
                       int* __restrict__ col, int E) {
  int i = blockIdx.x * 256 + threadIdx.x;
  if (i >= E) return;
  int s = load_idx(edge, flag, (size_t)i);
  int d = load_idx(edge, flag, (size_t)E + i);
  col[offsets[d] + rank[i]] = s;
}

// ---- tiny fp64 matmul for the weight chain ----
template <typename TB>
__global__ void k_smm(const float* __restrict__ A, const TB* __restrict__ B,
                      double* __restrict__ C, int M, int K, int Nc) {
  int idx = blockIdx.x * 256 + threadIdx.x;
  if (idx >= M * Nc) return;
  int i = idx / Nc, j = idx % Nc;
  double acc = 0.0;
  for (int k = 0; k < K; ++k) acc += (double)A[i * K + k] * (double)B[k * Nc + j];
  C[idx] = acc;
}

__global__ void k_d2f(const double* __restrict__ in, float* __restrict__ out, int n) {
  int i = blockIdx.x * 256 + threadIdx.x;
  if (i < n) out[i] = (float)in[i];
}

__global__ void k_cvec(const float* __restrict__ b2, const float* __restrict__ b3,
                       const float* __restrict__ b4, const float* __restrict__ b5,
                       const float* __restrict__ bl, const float* __restrict__ Wl,
                       const double* __restrict__ R3, const double* __restrict__ R4,
                       const double* __restrict__ R5, double* __restrict__ corr) {
  int j = threadIdx.x;
  if (j >= 100) return;
  double a2 = 0.0, a3 = 0.0, a4 = 0.0, acb = 0.0;
  for (int k = 0; k < 128; ++k) {
    a2 += (double)b2[k] * R3[k * 100 + j];
    a3 += (double)b3[k] * R4[k * 100 + j];
    a4 += (double)b4[k] * R5[k * 100 + j];
  }
  for (int k = 0; k < 100; ++k) acb += (double)b5[k] * (double)Wl[k * 100 + j];
  corr[j] = a2; corr[128 + j] = a3; corr[256 + j] = a4; corr[384 + j] = acb + (double)bl[j];
}

// ---- matmul: out[r][c] = (X@W)[r][c]*dinv[r], fp16 out, stride OS (linear).
// Split-K chunks of 32 -> LDS ~34.8 KB -> 3-4 blocks/CU.
// AUG: col 100 = dinv[r] (s-chain seed), cols in [M,OS) except 100 -> 0.
template <typename TX, int K, int M, int OS, int AUG>
__launch_bounds__(256)
__global__ void k_mm(const TX* __restrict__ X, const float* __restrict__ W,
                     const float* __restrict__ dinv, h16* __restrict__ out, int n) {
  __shared__ float Xs[128 * 36];
  __shared__ float Ws[32 * 132];
  int tid = threadIdx.x;
  int row0 = blockIdx.x * 128;
  int tc = tid & 15, tr = tid >> 4;
  int c0 = tc * 8;
  float acc[8][8];
#pragma unroll
  for (int i = 0; i < 8; ++i)
#pragma unroll
    for (int j = 0; j < 8; ++j) acc[i][j] = 0.f;

  for (int kc = 0; kc < K; kc += 32) {
    __syncthreads();
    // stage W chunk rows kc..kc+31, cols 0..127 (zero-pad past M)
    for (int idx = tid * 4; idx < 32 * 128; idx += 1024) {
      int r = idx >> 7, c = idx & 127;
      float4 v = make_float4(0.f, 0.f, 0.f, 0.f);
      if (c < M) v = *(const float4*)&W[(size_t)(kc + r) * M + c];
      *(float4*)&Ws[r * 132 + c] = v;
    }
    // stage X chunk rows 0..127, cols kc..kc+31
    if (sizeof(TX) == 4) {
      for (int idx = tid * 4; idx < 128 * 32; idx += 1024) {
        int r = idx >> 5, c = idx & 31;
        f32x4 v = {0.f, 0.f, 0.f, 0.f};
        if (row0 + r < n)
          v = __builtin_nontemporal_load(
              (const f32x4*)&((const float*)X)[(size_t)(row0 + r) * K + kc + c]);
        *(f32x4*)&Xs[r * 36 + c] = v;
      }
    } else {
      for (int idx = tid * 8; idx < 128 * 32; idx += 2048) {
        int r = idx >> 5, c = idx & 31;      // c in {0,8,16,24}
        float f[8];
#pragma unroll
        for (int q = 0; q < 8; ++q) f[q] = 0.f;
        if (row0 + r < n) {
          const h16* p = &((const h16*)X)[(size_t)(row0 + r) * K + kc + c];
          h16x8 v8 = __builtin_nontemporal_load((const h16x8*)p);
#pragma unroll
          for (int q = 0; q < 8; ++q) f[q] = (float)v8[q];
        }
        *(float4*)&Xs[r * 36 + c]     = make_float4(f[0], f[1], f[2], f[3]);
        *(float4*)&Xs[r * 36 + c + 4] = make_float4(f[4], f[5], f[6], f[7]);
      }
    }
    __syncthreads();

    for (int k = 0; k < 32; k += 4) {
      float4 xf[8];
#pragma unroll
      for (int i = 0; i < 8; ++i) xf[i] = *(const float4*)&Xs[(tr + 16 * i) * 36 + k];
      float4 wa[4], wb[4];
#pragma unroll
      for (int kk = 0; kk < 4; ++kk) {
        wa[kk] = *(const float4*)&Ws[(k + kk) * 132 + c0];
        wb[kk] = *(const float4*)&Ws[(k + kk) * 132 + c0 + 4];
      }
#pragma unroll
      for (int i = 0; i < 8; ++i) {
#pragma unroll
        for (int kk = 0; kk < 4; ++kk) {
          float xv = f4get(xf[i], kk);
          acc[i][0] = fmaf(xv, wa[kk].x, acc[i][0]);
          acc[i][1] = fmaf(xv, wa[kk].y, acc[i][1]);
          acc[i][2] = fmaf(xv, wa[kk].z, acc[i][2]);
          acc[i][3] = fmaf(xv, wa[kk].w, acc[i][3]);
          acc[i][4] = fmaf(xv, wb[kk].x, acc[i][4]);
          acc[i][5] = fmaf(xv, wb[kk].y, acc[i][5]);
          acc[i][6] = fmaf(xv, wb[kk].z, acc[i][6]);
          acc[i][7] = fmaf(xv, wb[kk].w, acc[i][7]);
        }
      }
    }
  }

  // epilogue: linear fp16 rows, nontemporal (don't evict gather working set)
#pragma unroll
  for (int i = 0; i < 8; ++i) {
    int grow = row0 + tr + 16 * i;
    if (grow >= n) continue;
    if (c0 >= OS) continue;
    float sc = dinv[grow];
    h16x8 pk;
#pragma unroll
    for (int j = 0; j < 8; ++j) {
      int colj = c0 + j;
      float vv = (colj < M) ? acc[i][j] * sc : ((AUG && colj == 100) ? sc : 0.f);
      pk[j] = (h16)vv;
    }
    h16* o = &out[(size_t)grow * OS + c0];
    __builtin_nontemporal_store(pk, (h16x8*)o);
  }
}

// ---- aggregation: one wave per node, h16x2/lane, edge loads in groups of 8.
// MODE 0: relu(dinv*(sum+self)+bias) [stride 128]
// MODE 1: dinv^2*(sum+self) (pre-scaled), fresh col seeded = dinv [stride 104]
// MODE 2: final + rank-1 corrections -> fp32 out [n][100]
template <int STRIDE, int WIDTH, int MODE>
__global__ void k_agg(const h16* __restrict__ hs, const int* __restrict__ offsets,
                      const int* __restrict__ col, const float* __restrict__ dinv,
                      const float* __restrict__ bias, const double* __restrict__ corr,
                      void* __restrict__ out, int n, int fresh) {
  int wid = (blockIdx.x * 256 + threadIdx.x) >> 6;
  int lane = threadIdx.x & 63;
  int c = lane * 2;
  if (wid >= n) return;
  if (WIDTH != 128 && c >= WIDTH) return;
  const h16* row = &hs[(size_t)wid * STRIDE];
  h16x2 self = *(const h16x2*)&row[c];
  float ax = (float)self.x, ay = (float)self.y;
  int s = offsets[wid], e = offsets[wid + 1];
  for (int i = s; i < e; i += 8) {
    h16x2 m[8];
#pragma unroll
    for (int j = 0; j < 8; ++j) {
      m[j].x = (h16)0.f; m[j].y = (h16)0.f;
      if (i + j < e) {
        int u = __builtin_nontemporal_load(&col[i + j]);
        m[j] = *(const h16x2*)&hs[(size_t)u * STRIDE + c];
      }
    }
#pragma unroll
    for (int j = 0; j < 8; ++j) { ax += (float)m[j].x; ay += (float)m[j].y; }
  }
  float w = dinv[wid];
  if (MODE == 0) {
    float rx = fmaxf(fmaf(ax, w, bias[c]), 0.f);
    float ry = fmaxf(fmaf(ay, w, bias[c + 1]), 0.f);
    h16x2 p; p.x = (h16)rx; p.y = (h16)ry;
    __builtin_nontemporal_store(p, (h16x2*)&((h16*)out)[(size_t)wid * STRIDE + c]);
  } else if (MODE == 1) {
    float w2 = w * w;
    float rx = ax * w2, ry = ay * w2;
    if (c == fresh) rx = w;             // seed column: dinv * 1
    else if (c + 1 == fresh) ry = w;
    h16x2 p; p.x = (h16)rx; p.y = (h16)ry;
    __builtin_nontemporal_store(p, (h16x2*)&((h16*)out)[(size_t)wid * STRIDE + c]);
  } else {
    float inv_w = 1.0f / w;
    float v3 = (float)row[100] * inv_w;
    float v2 = (float)row[101] * inv_w;
    float v1 = (float)row[102] * inv_w;
    float rx = ax * w + v3 * (float)corr[c]     + v2 * (float)corr[128 + c]
             + v1 * (float)corr[256 + c] + (float)corr[384 + c];
    float ry = ay * w + v3 * (float)corr[c + 1] + v2 * (float)corr[128 + c + 1]
             + v1 * (float)corr[256 + c + 1] + (float)corr[384 + c + 1];
    f32x2 p; p.x = rx; p.y = ry;
    __builtin_nontemporal_store(p, (f32x2*)&((float*)out)[(size_t)wid * 100 + c]);
  }
}

// ---------------------------------------------------------------------------
extern "C" void kernel_launch(void* const* d_in, const int* in_sizes, int n_in,
                              void* d_out, int out_size, void* d_ws, size_t ws_size,
                              hipStream_t stream) {
  const float* x    = (const float*)d_in[0];
  const int*   edge = (const int*)d_in[1];
  const float* W1 = (const float*)d_in[2];  const float* b1 = (const float*)d_in[3];
  const float* W2 = (const float*)d_in[4];  const float* b2 = (const float*)d_in[5];
  const float* W3 = (const float*)d_in[6];  const float* b3 = (const float*)d_in[7];
  const float* W4 = (const float*)d_in[8];  const float* b4 = (const float*)d_in[9];
  const float* W5 = (const float*)d_in[10]; const float* b5 = (const float*)d_in[11];
  const float* Wl = (const float*)d_in[12]; const float* bl = (const float*)d_in[13];

  const int N = in_sizes[0] / 128;
  const int E = in_sizes[1] / 2;

  char* ws = (char*)d_ws;
  size_t cur = 0;
  auto alloc = [&](size_t bytes) -> char* {
    char* p = ws + cur;
    cur = (cur + bytes + 255) & ~(size_t)255;
    return p;
  };
  int*    counts    = (int*)alloc((size_t)N * 4);
  int*    flag      = (int*)alloc(4);
  int*    offsets   = (int*)alloc((size_t)(N + 1) * 4);
  float*  dinv      = (float*)alloc((size_t)N * 4);
  int*    chunksums = (int*)alloc(128 * 4);
  int*    chunkbase = (int*)alloc(128 * 4);
  double* R5        = (double*)alloc(128 * 100 * 8);
  double* R4        = (double*)alloc(128 * 100 * 8);
  double* R3        = (double*)alloc(128 * 100 * 8);
  double* Wcd       = (double*)alloc(128 * 100 * 8);
  float*  Wc        = (float*)alloc(128 * 100 * 4);
  double* corr      = (double*)alloc(512 * 8);
  int*    rank      = (int*)alloc((size_t)E * 4);
  int*    col       = (int*)alloc(((size_t)E + 8) * 4);   // +pad for group reads
  h16*    bufA      = (h16*)alloc((size_t)N * 128 * 2);
  h16*    bufB      = (h16*)alloc((size_t)N * 128 * 2);
  (void)ws_size; (void)n_in; (void)out_size;

  hipMemsetAsync(counts, 0, (size_t)N * 4, stream);
  hipMemsetAsync(flag, 0, 4, stream);

  const int nchunks = (N + 1023) / 1024;
  const int egrid = (E + 255) / 256;
  const int ngrid = (N + 255) / 256;

  k_detect<<<1, 256, 0, stream>>>(edge, flag);
  k_count<<<egrid, 256, 0, stream>>>(edge, flag, counts, rank, E);
  k_dinv<<<ngrid, 256, 0, stream>>>(counts, dinv, N);
  k_chunksum<<<nchunks, 256, 0, stream>>>(counts, chunksums, N);
  k_root<<<1, 128, 0, stream>>>(chunksums, chunkbase, nchunks);
  k_scan3<<<nchunks, 256, 0, stream>>>(counts, chunkbase, offsets, N, E);
  k_fill<<<egrid, 256, 0, stream>>>(edge, flag, offsets, rank, col, E);

  // weight chain (fp64): R5 = W5 Wl; R4 = W4 R5; R3 = W3 R4; Wc = W2 R3
  const int sgrid = (128 * 100 + 255) / 256;
  k_smm<float><<<sgrid, 256, 0, stream>>>(W5, Wl, R5, 128, 100, 100);
  k_smm<double><<<sgrid, 256, 0, stream>>>(W4, R5, R4, 128, 128, 100);
  k_smm<double><<<sgrid, 256, 0, stream>>>(W3, R4, R3, 128, 128, 100);
  k_smm<double><<<sgrid, 256, 0, stream>>>(W2, R3, Wcd, 128, 128, 100);
  k_d2f<<<sgrid, 256, 0, stream>>>(Wcd, Wc, 128 * 100);
  k_cvec<<<1, 128, 0, stream>>>(b2, b3, b4, b5, bl, Wl, R3, R4, R5, corr);

  const int mmgrid = (N + 127) / 128;
  const int agrid = (N + 3) / 4;

  // hs0 = (x W1) * dinv  [fp16, stride 128]
  k_mm<float, 128, 128, 128, 0><<<mmgrid, 256, 0, stream>>>(x, W1, dinv, bufA, N);
  // h1 = relu(dinv*(gather+self) + b1)  [fp16, stride 128]
  k_agg<128, 128, 0><<<agrid, 256, 0, stream>>>(bufA, offsets, col, dinv, b1, nullptr, bufB, N, 0);
  // g_scaled = (h1 Wc) * dinv, col100 = dinv seed  [fp16, stride 104]
  k_mm<h16, 128, 100, 104, 1><<<mmgrid, 256, 0, stream>>>(bufB, Wc, dinv, bufA, N);
  // three chained S applications (pre-scaled); s-chain in cols 100..102
  k_agg<104, 104, 1><<<agrid, 256, 0, stream>>>(bufA, offsets, col, dinv, nullptr, nullptr, bufB, N, 101);
  k_agg<104, 104, 1><<<agrid, 256, 0, stream>>>(bufB, offsets, col, dinv, nullptr, nullptr, bufA, N, 102);
  k_agg<104, 104, 1><<<agrid, 256, 0, stream>>>(bufA, offsets, col, dinv, nullptr, nullptr, bufB, N, -1);
  // final S application + corrections -> d_out [fp32, N x 100]
  k_agg<104, 100, 2><<<agrid, 256, 0, stream>>>(bufB, offsets, col, dinv, nullptr, corr, (float*)d_out, N, -1);
}

// Round 8
// 896.769 us; speedup vs baseline: 1.5009x; 1.1587x over previous
//
#include <hip/hip_runtime.h>

// ---------------------------------------------------------------------------
// GCN: 5x GCNConv + final linear.  N=100000, E=1.6M, D_IN=D_H=128, N_CLS=100.
//
// Collapsed algebra (R1-R3): h1 = relu(S x W1 + 1 b1^T),
//   out = S^4 h1 Wc + S^3 1 c2^T + S^2 1 c3^T + S 1 c4^T + 1 cb^T,
// weight chain in fp64 on device.  s_k = S^k 1 ride as feature cols 100..102.
// Feature buffers fp16 row-major (stride 128 / 104).
// Lessons: R6 column slicing REVERTED (divergence, no L2 win).
//          R7 nontemporal stores REVERTED (outputs feed next gather; nt
//          stores raised FETCH 222->239MB and agg 111->140us).
// Split-K matmul kept (35 KB LDS -> 3 blocks/CU vs 1).  nt only on mm X reads.
// ---------------------------------------------------------------------------

typedef _Float16 h16;
typedef _Float16 __attribute__((ext_vector_type(2))) h16x2;
typedef _Float16 __attribute__((ext_vector_type(8))) h16x8;
typedef float __attribute__((ext_vector_type(4))) f32x4;

static __device__ __forceinline__ float f4get(const float4& v, int k) {
  switch (k) { case 0: return v.x; case 1: return v.y; case 2: return v.z; default: return v.w; }
}

// ---- edge dtype detection: if input is int64, odd int32 slots (hi words) are 0
__global__ void k_detect(const int* __restrict__ edge, int* __restrict__ flag) {
  int t = threadIdx.x;
  if (edge[2 * t + 1] != 0) atomicOr(flag, 1);
}

static __device__ __forceinline__ int load_idx(const int* edge, const int* flag, size_t pos) {
  bool is64 = (*flag == 0);
  if (is64) return (int)((const long long*)edge)[pos];
  return edge[pos];
}

__global__ void k_count(const int* __restrict__ edge, const int* __restrict__ flag,
                        int* __restrict__ counts, int* __restrict__ rank, int E) {
  int i = blockIdx.x * 256 + threadIdx.x;
  if (i >= E) return;
  int d = load_idx(edge, flag, (size_t)E + i);
  rank[i] = atomicAdd(&counts[d], 1);
}

__global__ void k_dinv(const int* __restrict__ counts, float* __restrict__ dinv, int n) {
  int i = blockIdx.x * 256 + threadIdx.x;
  if (i < n) dinv[i] = rsqrtf((float)counts[i] + 1.0f);
}

// ---- CSR build: chunk sums -> root scan -> per-chunk rescan ----
__global__ void k_chunksum(const int* __restrict__ counts, int* __restrict__ chunksums, int n) {
  __shared__ int sd[256];
  int t = threadIdx.x;
  int base = blockIdx.x * 1024 + t * 4;
  int s = 0;
#pragma unroll
  for (int j = 0; j < 4; ++j) { int i = base + j; if (i < n) s += counts[i]; }
  sd[t] = s; __syncthreads();
  for (int off = 128; off > 0; off >>= 1) {
    if (t < off) sd[t] += sd[t + off];
    __syncthreads();
  }
  if (t == 0) chunksums[blockIdx.x] = sd[0];
}

__global__ void k_root(const int* __restrict__ chunksums, int* __restrict__ chunkbase, int nchunks) {
  __shared__ int sc[128];
  int t = threadIdx.x;
  int v = (t < nchunks) ? chunksums[t] : 0;
  sc[t] = v; __syncthreads();
  for (int off = 1; off < 128; off <<= 1) {
    int x = (t >= off) ? sc[t - off] : 0;
    __syncthreads();
    sc[t] += x;
    __syncthreads();
  }
  if (t < nchunks) chunkbase[t] = sc[t] - v;
}

__global__ void k_scan3(const int* __restrict__ counts, const int* __restrict__ chunkbase,
                        int* __restrict__ offsets, int n, int E) {
  __shared__ int sd[256];
  int t = threadIdx.x;
  int base = blockIdx.x * 1024 + t * 4;
  int c[4]; int s = 0;
#pragma unroll
  for (int j = 0; j < 4; ++j) { int i = base + j; c[j] = (i < n) ? counts[i] : 0; s += c[j]; }
  sd[t] = s; __syncthreads();
  int v = s;
  for (int off = 1; off < 256; off <<= 1) {
    int x = (t >= off) ? sd[t - off] : 0;
    __syncthreads();
    sd[t] += x;
    __syncthreads();
  }
  int run = chunkbase[blockIdx.x] + sd[t] - v;
#pragma unroll
  for (int j = 0; j < 4; ++j) {
    int i = base + j;
    if (i < n) offsets[i] = run;
    run += c[j];
  }
  if (blockIdx.x == 0 && t == 0) offsets[n] = E;
}

__global__ void k_fill(const int* __restrict__ edge, const int* __restrict__ flag,
                       const int* __restrict__ offsets, const int* __restrict__ rank,
                       int* __restrict__ col, int E) {
  int i = blockIdx.x * 256 + threadIdx.x;
  if (i >= E) return;
  int s = load_idx(edge, flag, (size_t)i);
  int d = load_idx(edge, flag, (size_t)E + i);
  col[offsets[d] + rank[i]] = s;
}

// ---- tiny fp64 matmul for the weight chain ----
template <typename TB>
__global__ void k_smm(const float* __restrict__ A, const TB* __restrict__ B,
                      double* __restrict__ C, int M, int K, int Nc) {
  int idx = blockIdx.x * 256 + threadIdx.x;
  if (idx >= M * Nc) return;
  int i = idx / Nc, j = idx % Nc;
  double acc = 0.0;
  for (int k = 0; k < K; ++k) acc += (double)A[i * K + k] * (double)B[k * Nc + j];
  C[idx] = acc;
}

__global__ void k_d2f(const double* __restrict__ in, float* __restrict__ out, int n) {
  int i = blockIdx.x * 256 + threadIdx.x;
  if (i < n) out[i] = (float)in[i];
}

__global__ void k_cvec(const float* __restrict__ b2, const float* __restrict__ b3,
                       const float* __restrict__ b4, const float* __restrict__ b5,
                       const float* __restrict__ bl, const float* __restrict__ Wl,
                       const double* __restrict__ R3, const double* __restrict__ R4,
                       const double* __restrict__ R5, double* __restrict__ corr) {
  int j = threadIdx.x;
  if (j >= 100) return;
  double a2 = 0.0, a3 = 0.0, a4 = 0.0, acb = 0.0;
  for (int k = 0; k < 128; ++k) {
    a2 += (double)b2[k] * R3[k * 100 + j];
    a3 += (double)b3[k] * R4[k * 100 + j];
    a4 += (double)b4[k] * R5[k * 100 + j];
  }
  for (int k = 0; k < 100; ++k) acb += (double)b5[k] * (double)Wl[k * 100 + j];
  corr[j] = a2; corr[128 + j] = a3; corr[256 + j] = a4; corr[384 + j] = acb + (double)bl[j];
}

// ---- matmul: out[r][c] = (X@W)[r][c]*dinv[r], fp16 out, stride OS (linear).
// Split-K chunks of 32 -> LDS ~35 KB -> ~3 blocks/CU.
// AUG: col 100 = dinv[r] (s-chain seed), cols in [M,OS) except 100 -> 0.
// Epilogue stores are NORMAL (cached): output feeds the next gather pass.
template <typename TX, int K, int M, int OS, int AUG>
__launch_bounds__(256)
__global__ void k_mm(const TX* __restrict__ X, const float* __restrict__ W,
                     const float* __restrict__ dinv, h16* __restrict__ out, int n) {
  __shared__ float Xs[128 * 36];
  __shared__ float Ws[32 * 132];
  int tid = threadIdx.x;
  int row0 = blockIdx.x * 128;
  int tc = tid & 15, tr = tid >> 4;
  int c0 = tc * 8;
  float acc[8][8];
#pragma unroll
  for (int i = 0; i < 8; ++i)
#pragma unroll
    for (int j = 0; j < 8; ++j) acc[i][j] = 0.f;

  for (int kc = 0; kc < K; kc += 32) {
    __syncthreads();
    // stage W chunk rows kc..kc+31, cols 0..127 (zero-pad past M)
    for (int idx = tid * 4; idx < 32 * 128; idx += 1024) {
      int r = idx >> 7, c = idx & 127;
      float4 v = make_float4(0.f, 0.f, 0.f, 0.f);
      if (c < M) v = *(const float4*)&W[(size_t)(kc + r) * M + c];
      *(float4*)&Ws[r * 132 + c] = v;
    }
    // stage X chunk rows 0..127, cols kc..kc+31 (nt: streaming, never re-read)
    if (sizeof(TX) == 4) {
      for (int idx = tid * 4; idx < 128 * 32; idx += 1024) {
        int r = idx >> 5, c = idx & 31;
        f32x4 v = {0.f, 0.f, 0.f, 0.f};
        if (row0 + r < n)
          v = __builtin_nontemporal_load(
              (const f32x4*)&((const float*)X)[(size_t)(row0 + r) * K + kc + c]);
        *(f32x4*)&Xs[r * 36 + c] = v;
      }
    } else {
      for (int idx = tid * 8; idx < 128 * 32; idx += 2048) {
        int r = idx >> 5, c = idx & 31;      // c in {0,8,16,24}
        float f[8];
#pragma unroll
        for (int q = 0; q < 8; ++q) f[q] = 0.f;
        if (row0 + r < n) {
          const h16* p = &((const h16*)X)[(size_t)(row0 + r) * K + kc + c];
          h16x8 v8 = __builtin_nontemporal_load((const h16x8*)p);
#pragma unroll
          for (int q = 0; q < 8; ++q) f[q] = (float)v8[q];
        }
        *(float4*)&Xs[r * 36 + c]     = make_float4(f[0], f[1], f[2], f[3]);
        *(float4*)&Xs[r * 36 + c + 4] = make_float4(f[4], f[5], f[6], f[7]);
      }
    }
    __syncthreads();

    for (int k = 0; k < 32; k += 4) {
      float4 xf[8];
#pragma unroll
      for (int i = 0; i < 8; ++i) xf[i] = *(const float4*)&Xs[(tr + 16 * i) * 36 + k];
      float4 wa[4], wb[4];
#pragma unroll
      for (int kk = 0; kk < 4; ++kk) {
        wa[kk] = *(const float4*)&Ws[(k + kk) * 132 + c0];
        wb[kk] = *(const float4*)&Ws[(k + kk) * 132 + c0 + 4];
      }
#pragma unroll
      for (int i = 0; i < 8; ++i) {
#pragma unroll
        for (int kk = 0; kk < 4; ++kk) {
          float xv = f4get(xf[i], kk);
          acc[i][0] = fmaf(xv, wa[kk].x, acc[i][0]);
          acc[i][1] = fmaf(xv, wa[kk].y, acc[i][1]);
          acc[i][2] = fmaf(xv, wa[kk].z, acc[i][2]);
          acc[i][3] = fmaf(xv, wa[kk].w, acc[i][3]);
          acc[i][4] = fmaf(xv, wb[kk].x, acc[i][4]);
          acc[i][5] = fmaf(xv, wb[kk].y, acc[i][5]);
          acc[i][6] = fmaf(xv, wb[kk].z, acc[i][6]);
          acc[i][7] = fmaf(xv, wb[kk].w, acc[i][7]);
        }
      }
    }
  }

  // epilogue: linear fp16 rows, normal stores (populate L2 for gathers)
#pragma unroll
  for (int i = 0; i < 8; ++i) {
    int grow = row0 + tr + 16 * i;
    if (grow >= n) continue;
    if (c0 >= OS) continue;
    float sc = dinv[grow];
    h16x8 pk;
#pragma unroll
    for (int j = 0; j < 8; ++j) {
      int colj = c0 + j;
      float vv = (colj < M) ? acc[i][j] * sc : ((AUG && colj == 100) ? sc : 0.f);
      pk[j] = (h16)vv;
    }
    *(h16x8*)&out[(size_t)grow * OS + c0] = pk;
  }
}

// ---- aggregation: one wave per node, h16x2/lane, edge loads in groups of 16.
// MODE 0: relu(dinv*(sum+self)+bias) [stride 128]
// MODE 1: dinv^2*(sum+self) (pre-scaled), fresh col seeded = dinv [stride 104]
// MODE 2: final + rank-1 corrections -> fp32 out [n][100]
template <int STRIDE, int WIDTH, int MODE>
__global__ void k_agg(const h16* __restrict__ hs, const int* __restrict__ offsets,
                      const int* __restrict__ col, const float* __restrict__ dinv,
                      const float* __restrict__ bias, const double* __restrict__ corr,
                      void* __restrict__ out, int n, int fresh) {
  int wid = (blockIdx.x * 256 + threadIdx.x) >> 6;
  int lane = threadIdx.x & 63;
  int c = lane * 2;
  if (wid >= n) return;
  if (WIDTH != 128 && c >= WIDTH) return;
  const h16* row = &hs[(size_t)wid * STRIDE];
  h16x2 self = *(const h16x2*)&row[c];
  float ax = (float)self.x, ay = (float)self.y;
  int s = offsets[wid], e = offsets[wid + 1];
  for (int i = s; i < e; i += 16) {
    h16x2 m[16];
#pragma unroll
    for (int j = 0; j < 16; ++j) {
      m[j].x = (h16)0.f; m[j].y = (h16)0.f;
      if (i + j < e) {
        int u = col[i + j];
        m[j] = *(const h16x2*)&hs[(size_t)u * STRIDE + c];
      }
    }
#pragma unroll
    for (int j = 0; j < 16; ++j) { ax += (float)m[j].x; ay += (float)m[j].y; }
  }
  float w = dinv[wid];
  if (MODE == 0) {
    float rx = fmaxf(fmaf(ax, w, bias[c]), 0.f);
    float ry = fmaxf(fmaf(ay, w, bias[c + 1]), 0.f);
    h16x2 p; p.x = (h16)rx; p.y = (h16)ry;
    *(h16x2*)&((h16*)out)[(size_t)wid * STRIDE + c] = p;
  } else if (MODE == 1) {
    float w2 = w * w;
    float rx = ax * w2, ry = ay * w2;
    if (c == fresh) rx = w;             // seed column: dinv * 1
    else if (c + 1 == fresh) ry = w;
    h16x2 p; p.x = (h16)rx; p.y = (h16)ry;
    *(h16x2*)&((h16*)out)[(size_t)wid * STRIDE + c] = p;
  } else {
    float inv_w = 1.0f / w;
    float v3 = (float)row[100] * inv_w;
    float v2 = (float)row[101] * inv_w;
    float v1 = (float)row[102] * inv_w;
    float rx = ax * w + v3 * (float)corr[c]     + v2 * (float)corr[128 + c]
             + v1 * (float)corr[256 + c] + (float)corr[384 + c];
    float ry = ay * w + v3 * (float)corr[c + 1] + v2 * (float)corr[128 + c + 1]
             + v1 * (float)corr[256 + c + 1] + (float)corr[384 + c + 1];
    *(float2*)&((float*)out)[(size_t)wid * 100 + c] = make_float2(rx, ry);
  }
}

// ---------------------------------------------------------------------------
extern "C" void kernel_launch(void* const* d_in, const int* in_sizes, int n_in,
                              void* d_out, int out_size, void* d_ws, size_t ws_size,
                              hipStream_t stream) {
  const float* x    = (const float*)d_in[0];
  const int*   edge = (const int*)d_in[1];
  const float* W1 = (const float*)d_in[2];  const float* b1 = (const float*)d_in[3];
  const float* W2 = (const float*)d_in[4];  const float* b2 = (const float*)d_in[5];
  const float* W3 = (const float*)d_in[6];  const float* b3 = (const float*)d_in[7];
  const float* W4 = (const float*)d_in[8];  const float* b4 = (const float*)d_in[9];
  const float* W5 = (const float*)d_in[10]; const float* b5 = (const float*)d_in[11];
  const float* Wl = (const float*)d_in[12]; const float* bl = (const float*)d_in[13];

  const int N = in_sizes[0] / 128;
  const int E = in_sizes[1] / 2;

  char* ws = (char*)d_ws;
  size_t cur = 0;
  auto alloc = [&](size_t bytes) -> char* {
    char* p = ws + cur;
    cur = (cur + bytes + 255) & ~(size_t)255;
    return p;
  };
  int*    counts    = (int*)alloc((size_t)N * 4);
  int*    flag      = (int*)alloc(4);
  int*    offsets   = (int*)alloc((size_t)(N + 1) * 4);
  float*  dinv      = (float*)alloc((size_t)N * 4);
  int*    chunksums = (int*)alloc(128 * 4);
  int*    chunkbase = (int*)alloc(128 * 4);
  double* R5        = (double*)alloc(128 * 100 * 8);
  double* R4        = (double*)alloc(128 * 100 * 8);
  double* R3        = (double*)alloc(128 * 100 * 8);
  double* Wcd       = (double*)alloc(128 * 100 * 8);
  float*  Wc        = (float*)alloc(128 * 100 * 4);
  double* corr      = (double*)alloc(512 * 8);
  int*    rank      = (int*)alloc((size_t)E * 4);
  int*    col       = (int*)alloc(((size_t)E + 16) * 4);  // +pad for group reads
  h16*    bufA      = (h16*)alloc((size_t)N * 128 * 2);
  h16*    bufB      = (h16*)alloc((size_t)N * 128 * 2);
  (void)ws_size; (void)n_in; (void)out_size;

  hipMemsetAsync(counts, 0, (size_t)N * 4, stream);
  hipMemsetAsync(flag, 0, 4, stream);

  const int nchunks = (N + 1023) / 1024;
  const int egrid = (E + 255) / 256;
  const int ngrid = (N + 255) / 256;

  k_detect<<<1, 256, 0, stream>>>(edge, flag);
  k_count<<<egrid, 256, 0, stream>>>(edge, flag, counts, rank, E);
  k_dinv<<<ngrid, 256, 0, stream>>>(counts, dinv, N);
  k_chunksum<<<nchunks, 256, 0, stream>>>(counts, chunksums, N);
  k_root<<<1, 128, 0, stream>>>(chunksums, chunkbase, nchunks);
  k_scan3<<<nchunks, 256, 0, stream>>>(counts, chunkbase, offsets, N, E);
  k_fill<<<egrid, 256, 0, stream>>>(edge, flag, offsets, rank, col, E);

  // weight chain (fp64): R5 = W5 Wl; R4 = W4 R5; R3 = W3 R4; Wc = W2 R3
  const int sgrid = (128 * 100 + 255) / 256;
  k_smm<float><<<sgrid, 256, 0, stream>>>(W5, Wl, R5, 128, 100, 100);
  k_smm<double><<<sgrid, 256, 0, stream>>>(W4, R5, R4, 128, 128, 100);
  k_smm<double><<<sgrid, 256, 0, stream>>>(W3, R4, R3, 128, 128, 100);
  k_smm<double><<<sgrid, 256, 0, stream>>>(W2, R3, Wcd, 128, 128, 100);
  k_d2f<<<sgrid, 256, 0, stream>>>(Wcd, Wc, 128 * 100);
  k_cvec<<<1, 128, 0, stream>>>(b2, b3, b4, b5, bl, Wl, R3, R4, R5, corr);

  const int mmgrid = (N + 127) / 128;
  const int agrid = (N + 3) / 4;

  // hs0 = (x W1) * dinv  [fp16, stride 128]
  k_mm<float, 128, 128, 128, 0><<<mmgrid, 256, 0, stream>>>(x, W1, dinv, bufA, N);
  // h1 = relu(dinv*(gather+self) + b1)  [fp16, stride 128]
  k_agg<128, 128, 0><<<agrid, 256, 0, stream>>>(bufA, offsets, col, dinv, b1, nullptr, bufB, N, 0);
  // g_scaled = (h1 Wc) * dinv, col100 = dinv seed  [fp16, stride 104]
  k_mm<h16, 128, 100, 104, 1><<<mmgrid, 256, 0, stream>>>(bufB, Wc, dinv, bufA, N);
  // three chained S applications (pre-scaled); s-chain in cols 100..102
  k_agg<104, 104, 1><<<agrid, 256, 0, stream>>>(bufA, offsets, col, dinv, nullptr, nullptr, bufB, N, 101);
  k_agg<104, 104, 1><<<agrid, 256, 0, stream>>>(bufB, offsets, col, dinv, nullptr, nullptr, bufA, N, 102);
  k_agg<104, 104, 1><<<agrid, 256, 0, stream>>>(bufA, offsets, col, dinv, nullptr, nullptr, bufB, N, -1);
  // final S application + corrections -> d_out [fp32, N x 100]
  k_agg<104, 100, 2><<<agrid, 256, 0, stream>>>(bufB, offsets, col, dinv, nullptr, corr, (float*)d_out, N, -1);
}

// Round 9
// 896.233 us; speedup vs baseline: 1.5018x; 1.0006x over previous
//
#include <hip/hip_runtime.h>

// ---------------------------------------------------------------------------
// GCN: 5x GCNConv + final linear.  N=100000, E=1.6M, D_IN=D_H=128, N_CLS=100.
//
// Collapsed algebra (R1-R3): h1 = relu(S x W1 + 1 b1^T),
//   out = S^4 h1 Wc + S^3 1 c2^T + S^2 1 c3^T + S 1 c4^T + 1 cb^T,
// weight chain in fp64 on device.  s_k = S^k 1 ride as feature cols 100..102.
// Feature buffers fp16 row-major, stride 128 (256B = 2 aligned L2 lines per
// row; R8 used stride 104 whose unaligned 208B rows touched ~2.6 lines).
// Lessons: R6 column slicing REVERTED; R7 nt stores REVERTED.
// Split-K matmul kept.  nt only on mm X reads.
// ---------------------------------------------------------------------------

typedef _Float16 h16;
typedef _Float16 __attribute__((ext_vector_type(2))) h16x2;
typedef _Float16 __attribute__((ext_vector_type(8))) h16x8;
typedef float __attribute__((ext_vector_type(4))) f32x4;

static __device__ __forceinline__ float f4get(const float4& v, int k) {
  switch (k) { case 0: return v.x; case 1: return v.y; case 2: return v.z; default: return v.w; }
}

// ---- edge dtype detection: if input is int64, odd int32 slots (hi words) are 0
__global__ void k_detect(const int* __restrict__ edge, int* __restrict__ flag) {
  int t = threadIdx.x;
  if (edge[2 * t + 1] != 0) atomicOr(flag, 1);
}

static __device__ __forceinline__ int load_idx(const int* edge, const int* flag, size_t pos) {
  bool is64 = (*flag == 0);
  if (is64) return (int)((const long long*)edge)[pos];
  return edge[pos];
}

__global__ void k_count(const int* __restrict__ edge, const int* __restrict__ flag,
                        int* __restrict__ counts, int* __restrict__ rank, int E) {
  int i = blockIdx.x * 256 + threadIdx.x;
  if (i >= E) return;
  int d = load_idx(edge, flag, (size_t)E + i);
  rank[i] = atomicAdd(&counts[d], 1);
}

__global__ void k_dinv(const int* __restrict__ counts, float* __restrict__ dinv, int n) {
  int i = blockIdx.x * 256 + threadIdx.x;
  if (i < n) dinv[i] = rsqrtf((float)counts[i] + 1.0f);
}

// ---- CSR build: chunk sums -> root scan -> per-chunk rescan ----
__global__ void k_chunksum(const int* __restrict__ counts, int* __restrict__ chunksums, int n) {
  __shared__ int sd[256];
  int t = threadIdx.x;
  int base = blockIdx.x * 1024 + t * 4;
  int s = 0;
#pragma unroll
  for (int j = 0; j < 4; ++j) { int i = base + j; if (i < n) s += counts[i]; }
  sd[t] = s; __syncthreads();
  for (int off = 128; off > 0; off >>= 1) {
    if (t < off) sd[t] += sd[t + off];
    __syncthreads();
  }
  if (t == 0) chunksums[blockIdx.x] = sd[0];
}

__global__ void k_root(const int* __restrict__ chunksums, int* __restrict__ chunkbase, int nchunks) {
  __shared__ int sc[128];
  int t = threadIdx.x;
  int v = (t < nchunks) ? chunksums[t] : 0;
  sc[t] = v; __syncthreads();
  for (int off = 1; off < 128; off <<= 1) {
    int x = (t >= off) ? sc[t - off] : 0;
    __syncthreads();
    sc[t] += x;
    __syncthreads();
  }
  if (t < nchunks) chunkbase[t] = sc[t] - v;
}

__global__ void k_scan3(const int* __restrict__ counts, const int* __restrict__ chunkbase,
                        int* __restrict__ offsets, int n, int E) {
  __shared__ int sd[256];
  int t = threadIdx.x;
  int base = blockIdx.x * 1024 + t * 4;
  int c[4]; int s = 0;
#pragma unroll
  for (int j = 0; j < 4; ++j) { int i = base + j; c[j] = (i < n) ? counts[i] : 0; s += c[j]; }
  sd[t] = s; __syncthreads();
  int v = s;
  for (int off = 1; off < 256; off <<= 1) {
    int x = (t >= off) ? sd[t - off] : 0;
    __syncthreads();
    sd[t] += x;
    __syncthreads();
  }
  int run = chunkbase[blockIdx.x] + sd[t] - v;
#pragma unroll
  for (int j = 0; j < 4; ++j) {
    int i = base + j;
    if (i < n) offsets[i] = run;
    run += c[j];
  }
  if (blockIdx.x == 0 && t == 0) offsets[n] = E;
}

__global__ void k_fill(const int* __restrict__ edge, const int* __restrict__ flag,
                       const int* __restrict__ offsets, const int* __restrict__ rank,
                       int* __restrict__ col, int E) {
  int i = blockIdx.x * 256 + threadIdx.x;
  if (i >= E) return;
  int s = load_idx(edge, flag, (size_t)i);
  int d = load_idx(edge, flag, (size_t)E + i);
  col[offsets[d] + rank[i]] = s;
}

// ---- tiny fp64 matmul for the weight chain ----
template <typename TB>
__global__ void k_smm(const float* __restrict__ A, const TB* __restrict__ B,
                      double* __restrict__ C, int M, int K, int Nc) {
  int idx = blockIdx.x * 256 + threadIdx.x;
  if (idx >= M * Nc) return;
  int i = idx / Nc, j = idx % Nc;
  double acc = 0.0;
  for (int k = 0; k < K; ++k) acc += (double)A[i * K + k] * (double)B[k * Nc + j];
  C[idx] = acc;
}

__global__ void k_d2f(const double* __restrict__ in, float* __restrict__ out, int n) {
  int i = blockIdx.x * 256 + threadIdx.x;
  if (i < n) out[i] = (float)in[i];
}

__global__ void k_cvec(const float* __restrict__ b2, const float* __restrict__ b3,
                       const float* __restrict__ b4, const float* __restrict__ b5,
                       const float* __restrict__ bl, const float* __restrict__ Wl,
                       const double* __restrict__ R3, const double* __restrict__ R4,
                       const double* __restrict__ R5, double* __restrict__ corr) {
  int j = threadIdx.x;
  if (j >= 100) return;
  double a2 = 0.0, a3 = 0.0, a4 = 0.0, acb = 0.0;
  for (int k = 0; k < 128; ++k) {
    a2 += (double)b2[k] * R3[k * 100 + j];
    a3 += (double)b3[k] * R4[k * 100 + j];
    a4 += (double)b4[k] * R5[k * 100 + j];
  }
  for (int k = 0; k < 100; ++k) acb += (double)b5[k] * (double)Wl[k * 100 + j];
  corr[j] = a2; corr[128 + j] = a3; corr[256 + j] = a4; corr[384 + j] = acb + (double)bl[j];
}

// ---- matmul: out[r][c] = (X@W)[r][c]*dinv[r], fp16 out, stride OS (linear).
// Split-K chunks of 32 -> LDS ~35 KB -> ~3 blocks/CU.
// AUG: col 100 = dinv[r] (s-chain seed), cols in [M,OS) except 100 -> 0.
// Epilogue stores NORMAL (cached): output feeds the next gather pass.
template <typename TX, int K, int M, int OS, int AUG>
__launch_bounds__(256)
__global__ void k_mm(const TX* __restrict__ X, const float* __restrict__ W,
                     const float* __restrict__ dinv, h16* __restrict__ out, int n) {
  __shared__ float Xs[128 * 36];
  __shared__ float Ws[32 * 132];
  int tid = threadIdx.x;
  int row0 = blockIdx.x * 128;
  int tc = tid & 15, tr = tid >> 4;
  int c0 = tc * 8;
  float acc[8][8];
#pragma unroll
  for (int i = 0; i < 8; ++i)
#pragma unroll
    for (int j = 0; j < 8; ++j) acc[i][j] = 0.f;

  for (int kc = 0; kc < K; kc += 32) {
    __syncthreads();
    // stage W chunk rows kc..kc+31, cols 0..127 (zero-pad past M)
    for (int idx = tid * 4; idx < 32 * 128; idx += 1024) {
      int r = idx >> 7, c = idx & 127;
      float4 v = make_float4(0.f, 0.f, 0.f, 0.f);
      if (c < M) v = *(const float4*)&W[(size_t)(kc + r) * M + c];
      *(float4*)&Ws[r * 132 + c] = v;
    }
    // stage X chunk rows 0..127, cols kc..kc+31 (nt: streaming, never re-read)
    if (sizeof(TX) == 4) {
      for (int idx = tid * 4; idx < 128 * 32; idx += 1024) {
        int r = idx >> 5, c = idx & 31;
        f32x4 v = {0.f, 0.f, 0.f, 0.f};
        if (row0 + r < n)
          v = __builtin_nontemporal_load(
              (const f32x4*)&((const float*)X)[(size_t)(row0 + r) * K + kc + c]);
        *(f32x4*)&Xs[r * 36 + c] = v;
      }
    } else {
      for (int idx = tid * 8; idx < 128 * 32; idx += 2048) {
        int r = idx >> 5, c = idx & 31;      // c in {0,8,16,24}
        float f[8];
#pragma unroll
        for (int q = 0; q < 8; ++q) f[q] = 0.f;
        if (row0 + r < n) {
          const h16* p = &((const h16*)X)[(size_t)(row0 + r) * K + kc + c];
          h16x8 v8 = __builtin_nontemporal_load((const h16x8*)p);
#pragma unroll
          for (int q = 0; q < 8; ++q) f[q] = (float)v8[q];
        }
        *(float4*)&Xs[r * 36 + c]     = make_float4(f[0], f[1], f[2], f[3]);
        *(float4*)&Xs[r * 36 + c + 4] = make_float4(f[4], f[5], f[6], f[7]);
      }
    }
    __syncthreads();

    for (int k = 0; k < 32; k += 4) {
      float4 xf[8];
#pragma unroll
      for (int i = 0; i < 8; ++i) xf[i] = *(const float4*)&Xs[(tr + 16 * i) * 36 + k];
      float4 wa[4], wb[4];
#pragma unroll
      for (int kk = 0; kk < 4; ++kk) {
        wa[kk] = *(const float4*)&Ws[(k + kk) * 132 + c0];
        wb[kk] = *(const float4*)&Ws[(k + kk) * 132 + c0 + 4];
      }
#pragma unroll
      for (int i = 0; i < 8; ++i) {
#pragma unroll
        for (int kk = 0; kk < 4; ++kk) {
          float xv = f4get(xf[i], kk);
          acc[i][0] = fmaf(xv, wa[kk].x, acc[i][0]);
          acc[i][1] = fmaf(xv, wa[kk].y, acc[i][1]);
          acc[i][2] = fmaf(xv, wa[kk].z, acc[i][2]);
          acc[i][3] = fmaf(xv, wa[kk].w, acc[i][3]);
          acc[i][4] = fmaf(xv, wb[kk].x, acc[i][4]);
          acc[i][5] = fmaf(xv, wb[kk].y, acc[i][5]);
          acc[i][6] = fmaf(xv, wb[kk].z, acc[i][6]);
          acc[i][7] = fmaf(xv, wb[kk].w, acc[i][7]);
        }
      }
    }
  }

  // epilogue: linear fp16 rows, normal stores (populate L2 for gathers)
#pragma unroll
  for (int i = 0; i < 8; ++i) {
    int grow = row0 + tr + 16 * i;
    if (grow >= n) continue;
    if (c0 >= OS) continue;
    float sc = dinv[grow];
    h16x8 pk;
#pragma unroll
    for (int j = 0; j < 8; ++j) {
      int colj = c0 + j;
      float vv = (colj < M) ? acc[i][j] * sc : ((AUG && colj == 100) ? sc : 0.f);
      pk[j] = (h16)vv;
    }
    *(h16x8*)&out[(size_t)grow * OS + c0] = pk;
  }
}

// ---- aggregation: one wave per node, h16x2/lane, edge loads in groups of 16.
// All feature buffers stride 128 fp16 (256B aligned rows = 2 L2 lines).
// MODE 0: relu(dinv*(sum+self)+bias)  [width 128]
// MODE 1: dinv^2*(sum+self) (pre-scaled), fresh col seeded = dinv [width 104]
// MODE 2: final + rank-1 corrections -> fp32 out [n][100]  [width 100]
template <int WIDTH, int MODE>
__global__ void k_agg(const h16* __restrict__ hs, const int* __restrict__ offsets,
                      const int* __restrict__ col, const float* __restrict__ dinv,
                      const float* __restrict__ bias, const double* __restrict__ corr,
                      void* __restrict__ out, int n, int fresh) {
  const int STRIDE = 128;
  int wid = (blockIdx.x * 256 + threadIdx.x) >> 6;
  int lane = threadIdx.x & 63;
  int c = lane * 2;
  if (wid >= n) return;
  if (WIDTH != 128 && c >= WIDTH) return;
  const h16* row = &hs[(size_t)wid * STRIDE];
  h16x2 self = *(const h16x2*)&row[c];
  float ax = (float)self.x, ay = (float)self.y;
  int s = offsets[wid], e = offsets[wid + 1];
  for (int i = s; i < e; i += 16) {
    h16x2 m[16];
#pragma unroll
    for (int j = 0; j < 16; ++j) {
      m[j].x = (h16)0.f; m[j].y = (h16)0.f;
      if (i + j < e) {
        int u = col[i + j];
        m[j] = *(const h16x2*)&hs[(size_t)u * STRIDE + c];
      }
    }
#pragma unroll
    for (int j = 0; j < 16; ++j) { ax += (float)m[j].x; ay += (float)m[j].y; }
  }
  float w = dinv[wid];
  if (MODE == 0) {
    float rx = fmaxf(fmaf(ax, w, bias[c]), 0.f);
    float ry = fmaxf(fmaf(ay, w, bias[c + 1]), 0.f);
    h16x2 p; p.x = (h16)rx; p.y = (h16)ry;
    *(h16x2*)&((h16*)out)[(size_t)wid * STRIDE + c] = p;
  } else if (MODE == 1) {
    float w2 = w * w;
    float rx = ax * w2, ry = ay * w2;
    if (c == fresh) rx = w;             // seed column: dinv * 1
    else if (c + 1 == fresh) ry = w;
    h16x2 p; p.x = (h16)rx; p.y = (h16)ry;
    *(h16x2*)&((h16*)out)[(size_t)wid * STRIDE + c] = p;
  } else {
    float inv_w = 1.0f / w;
    float v3 = (float)row[100] * inv_w;
    float v2 = (float)row[101] * inv_w;
    float v1 = (float)row[102] * inv_w;
    float rx = ax * w + v3 * (float)corr[c]     + v2 * (float)corr[128 + c]
             + v1 * (float)corr[256 + c] + (float)corr[384 + c];
    float ry = ay * w + v3 * (float)corr[c + 1] + v2 * (float)corr[128 + c + 1]
             + v1 * (float)corr[256 + c + 1] + (float)corr[384 + c + 1];
    *(float2*)&((float*)out)[(size_t)wid * 100 + c] = make_float2(rx, ry);
  }
}

// ---------------------------------------------------------------------------
extern "C" void kernel_launch(void* const* d_in, const int* in_sizes, int n_in,
                              void* d_out, int out_size, void* d_ws, size_t ws_size,
                              hipStream_t stream) {
  const float* x    = (const float*)d_in[0];
  const int*   edge = (const int*)d_in[1];
  const float* W1 = (const float*)d_in[2];  const float* b1 = (const float*)d_in[3];
  const float* W2 = (const float*)d_in[4];  const float* b2 = (const float*)d_in[5];
  const float* W3 = (const float*)d_in[6];  const float* b3 = (const float*)d_in[7];
  const float* W4 = (const float*)d_in[8];  const float* b4 = (const float*)d_in[9];
  const float* W5 = (const float*)d_in[10]; const float* b5 = (const float*)d_in[11];
  const float* Wl = (const float*)d_in[12]; const float* bl = (const float*)d_in[13];

  const int N = in_sizes[0] / 128;
  const int E = in_sizes[1] / 2;

  char* ws = (char*)d_ws;
  size_t cur = 0;
  auto alloc = [&](size_t bytes) -> char* {
    char* p = ws + cur;
    cur = (cur + bytes + 255) & ~(size_t)255;
    return p;
  };
  int*    counts    = (int*)alloc((size_t)N * 4);
  int*    flag      = (int*)alloc(4);
  int*    offsets   = (int*)alloc((size_t)(N + 1) * 4);
  float*  dinv      = (float*)alloc((size_t)N * 4);
  int*    chunksums = (int*)alloc(128 * 4);
  int*    chunkbase = (int*)alloc(128 * 4);
  double* R5        = (double*)alloc(128 * 100 * 8);
  double* R4        = (double*)alloc(128 * 100 * 8);
  double* R3        = (double*)alloc(128 * 100 * 8);
  double* Wcd       = (double*)alloc(128 * 100 * 8);
  float*  Wc        = (float*)alloc(128 * 100 * 4);
  double* corr      = (double*)alloc(512 * 8);
  int*    rank      = (int*)alloc((size_t)E * 4);
  int*    col       = (int*)alloc(((size_t)E + 16) * 4);  // +pad for group reads
  h16*    bufA      = (h16*)alloc((size_t)N * 128 * 2);   // stride 128, 256B-aligned rows
  h16*    bufB      = (h16*)alloc((size_t)N * 128 * 2);
  (void)ws_size; (void)n_in; (void)out_size;

  hipMemsetAsync(counts, 0, (size_t)N * 4, stream);
  hipMemsetAsync(flag, 0, 4, stream);

  const int nchunks = (N + 1023) / 1024;
  const int egrid = (E + 255) / 256;
  const int ngrid = (N + 255) / 256;

  k_detect<<<1, 256, 0, stream>>>(edge, flag);
  k_count<<<egrid, 256, 0, stream>>>(edge, flag, counts, rank, E);
  k_dinv<<<ngrid, 256, 0, stream>>>(counts, dinv, N);
  k_chunksum<<<nchunks, 256, 0, stream>>>(counts, chunksums, N);
  k_root<<<1, 128, 0, stream>>>(chunksums, chunkbase, nchunks);
  k_scan3<<<nchunks, 256, 0, stream>>>(counts, chunkbase, offsets, N, E);
  k_fill<<<egrid, 256, 0, stream>>>(edge, flag, offsets, rank, col, E);

  // weight chain (fp64): R5 = W5 Wl; R4 = W4 R5; R3 = W3 R4; Wc = W2 R3
  const int sgrid = (128 * 100 + 255) / 256;
  k_smm<float><<<sgrid, 256, 0, stream>>>(W5, Wl, R5, 128, 100, 100);
  k_smm<double><<<sgrid, 256, 0, stream>>>(W4, R5, R4, 128, 128, 100);
  k_smm<double><<<sgrid, 256, 0, stream>>>(W3, R4, R3, 128, 128, 100);
  k_smm<double><<<sgrid, 256, 0, stream>>>(W2, R3, Wcd, 128, 128, 100);
  k_d2f<<<sgrid, 256, 0, stream>>>(Wcd, Wc, 128 * 100);
  k_cvec<<<1, 128, 0, stream>>>(b2, b3, b4, b5, bl, Wl, R3, R4, R5, corr);

  const int mmgrid = (N + 127) / 128;
  const int agrid = (N + 3) / 4;

  // hs0 = (x W1) * dinv  [fp16, stride 128]
  k_mm<float, 128, 128, 128, 0><<<mmgrid, 256, 0, stream>>>(x, W1, dinv, bufA, N);
  // h1 = relu(dinv*(gather+self) + b1)  [fp16, stride 128]
  k_agg<128, 0><<<agrid, 256, 0, stream>>>(bufA, offsets, col, dinv, b1, nullptr, bufB, N, 0);
  // g_scaled = (h1 Wc) * dinv, col100 = dinv seed  [fp16, stride 128]
  k_mm<h16, 128, 100, 128, 1><<<mmgrid, 256, 0, stream>>>(bufB, Wc, dinv, bufA, N);
  // three chained S applications (pre-scaled); s-chain in cols 100..102
  k_agg<104, 1><<<agrid, 256, 0, stream>>>(bufA, offsets, col, dinv, nullptr, nullptr, bufB, N, 101);
  k_agg<104, 1><<<agrid, 256, 0, stream>>>(bufB, offsets, col, dinv, nullptr, nullptr, bufA, N, 102);
  k_agg<104, 1><<<agrid, 256, 0, stream>>>(bufA, offsets, col, dinv, nullptr, nullptr, bufB, N, -1);
  // final S application + corrections -> d_out [fp32, N x 100]
  k_agg<100, 2><<<agrid, 256, 0, stream>>>(bufB, offsets, col, dinv, nullptr, corr, (float*)d_out, N, -1);
}

// Round 10
// 745.705 us; speedup vs baseline: 1.8050x; 1.2019x over previous
//
#include <hip/hip_runtime.h>

// ---------------------------------------------------------------------------
// GCN: 5x GCNConv + final linear.  N=100000, E=1.6M, D_IN=D_H=128, N_CLS=100.
//
// Collapsed algebra (R1-R3): h1 = relu(S x W1 + 1 b1^T),
//   out = S^4 h1 Wc + S^3 1 c2^T + S^2 1 c3^T + S 1 c4^T + 1 cb^T,
// weight chain in fp64 on device.  s_k = S^k 1 ride as feature cols 100..102.
// Feature buffers fp16 row-major, stride 128 (256B aligned rows = 2 L2 lines).
// Aggregation: 2 nodes per wave (32 lanes x h16x4 = one 256B row per half),
// 16 edge-rows in flight per node -> 64 lines/wave MLP (R9 had 32).
// Lessons: R6 column slicing REVERTED; R7 nt stores REVERTED; R9 showed
// fetch-line reduction is time-neutral (latency/MLP-bound, not byte-bound).
// ---------------------------------------------------------------------------

typedef _Float16 h16;
typedef _Float16 __attribute__((ext_vector_type(4))) h16x4;
typedef _Float16 __attribute__((ext_vector_type(8))) h16x8;
typedef float __attribute__((ext_vector_type(4))) f32x4;

static __device__ __forceinline__ float f4get(const float4& v, int k) {
  switch (k) { case 0: return v.x; case 1: return v.y; case 2: return v.z; default: return v.w; }
}

// ---- edge dtype detection: if input is int64, odd int32 slots (hi words) are 0
__global__ void k_detect(const int* __restrict__ edge, int* __restrict__ flag) {
  int t = threadIdx.x;
  if (edge[2 * t + 1] != 0) atomicOr(flag, 1);
}

static __device__ __forceinline__ int load_idx(const int* edge, const int* flag, size_t pos) {
  bool is64 = (*flag == 0);
  if (is64) return (int)((const long long*)edge)[pos];
  return edge[pos];
}

__global__ void k_count(const int* __restrict__ edge, const int* __restrict__ flag,
                        int* __restrict__ counts, int* __restrict__ rank, int E) {
  int i = blockIdx.x * 256 + threadIdx.x;
  if (i >= E) return;
  int d = load_idx(edge, flag, (size_t)E + i);
  rank[i] = atomicAdd(&counts[d], 1);
}

__global__ void k_dinv(const int* __restrict__ counts, float* __restrict__ dinv, int n) {
  int i = blockIdx.x * 256 + threadIdx.x;
  if (i < n) dinv[i] = rsqrtf((float)counts[i] + 1.0f);
}

// ---- CSR build: chunk sums -> root scan -> per-chunk rescan ----
__global__ void k_chunksum(const int* __restrict__ counts, int* __restrict__ chunksums, int n) {
  __shared__ int sd[256];
  int t = threadIdx.x;
  int base = blockIdx.x * 1024 + t * 4;
  int s = 0;
#pragma unroll
  for (int j = 0; j < 4; ++j) { int i = base + j; if (i < n) s += counts[i]; }
  sd[t] = s; __syncthreads();
  for (int off = 128; off > 0; off >>= 1) {
    if (t < off) sd[t] += sd[t + off];
    __syncthreads();
  }
  if (t == 0) chunksums[blockIdx.x] = sd[0];
}

__global__ void k_root(const int* __restrict__ chunksums, int* __restrict__ chunkbase, int nchunks) {
  __shared__ int sc[128];
  int t = threadIdx.x;
  int v = (t < nchunks) ? chunksums[t] : 0;
  sc[t] = v; __syncthreads();
  for (int off = 1; off < 128; off <<= 1) {
    int x = (t >= off) ? sc[t - off] : 0;
    __syncthreads();
    sc[t] += x;
    __syncthreads();
  }
  if (t < nchunks) chunkbase[t] = sc[t] - v;
}

__global__ void k_scan3(const int* __restrict__ counts, const int* __restrict__ chunkbase,
                        int* __restrict__ offsets, int n, int E) {
  __shared__ int sd[256];
  int t = threadIdx.x;
  int base = blockIdx.x * 1024 + t * 4;
  int c[4]; int s = 0;
#pragma unroll
  for (int j = 0; j < 4; ++j) { int i = base + j; c[j] = (i < n) ? counts[i] : 0; s += c[j]; }
  sd[t] = s; __syncthreads();
  int v = s;
  for (int off = 1; off < 256; off <<= 1) {
    int x = (t >= off) ? sd[t - off] : 0;
    __syncthreads();
    sd[t] += x;
    __syncthreads();
  }
  int run = chunkbase[blockIdx.x] + sd[t] - v;
#pragma unroll
  for (int j = 0; j < 4; ++j) {
    int i = base + j;
    if (i < n) offsets[i] = run;
    run += c[j];
  }
  if (blockIdx.x == 0 && t == 0) offsets[n] = E;
}

__global__ void k_fill(const int* __restrict__ edge, const int* __restrict__ flag,
                       const int* __restrict__ offsets, const int* __restrict__ rank,
                       int* __restrict__ col, int E) {
  int i = blockIdx.x * 256 + threadIdx.x;
  if (i >= E) return;
  int s = load_idx(edge, flag, (size_t)i);
  int d = load_idx(edge, flag, (size_t)E + i);
  col[offsets[d] + rank[i]] = s;
}

// ---- tiny fp64 matmul for the weight chain ----
template <typename TB>
__global__ void k_smm(const float* __restrict__ A, const TB* __restrict__ B,
                      double* __restrict__ C, int M, int K, int Nc) {
  int idx = blockIdx.x * 256 + threadIdx.x;
  if (idx >= M * Nc) return;
  int i = idx / Nc, j = idx % Nc;
  double acc = 0.0;
  for (int k = 0; k < K; ++k) acc += (double)A[i * K + k] * (double)B[k * Nc + j];
  C[idx] = acc;
}

__global__ void k_d2f(const double* __restrict__ in, float* __restrict__ out, int n) {
  int i = blockIdx.x * 256 + threadIdx.x;
  if (i < n) out[i] = (float)in[i];
}

__global__ void k_cvec(const float* __restrict__ b2, const float* __restrict__ b3,
                       const float* __restrict__ b4, const float* __restrict__ b5,
                       const float* __restrict__ bl, const float* __restrict__ Wl,
                       const double* __restrict__ R3, const double* __restrict__ R4,
                       const double* __restrict__ R5, double* __restrict__ corr) {
  int j = threadIdx.x;
  if (j >= 100) return;
  double a2 = 0.0, a3 = 0.0, a4 = 0.0, acb = 0.0;
  for (int k = 0; k < 128; ++k) {
    a2 += (double)b2[k] * R3[k * 100 + j];
    a3 += (double)b3[k] * R4[k * 100 + j];
    a4 += (double)b4[k] * R5[k * 100 + j];
  }
  for (int k = 0; k < 100; ++k) acb += (double)b5[k] * (double)Wl[k * 100 + j];
  corr[j] = a2; corr[128 + j] = a3; corr[256 + j] = a4; corr[384 + j] = acb + (double)bl[j];
}

// ---- matmul: out[r][c] = (X@W)[r][c]*dinv[r], fp16 out, stride OS (linear).
// Split-K chunks of 32 -> LDS ~35 KB -> ~3 blocks/CU.
// AUG: col 100 = dinv[r] (s-chain seed), cols in [M,OS) except 100 -> 0.
// Epilogue stores NORMAL (cached): output feeds the next gather pass.
template <typename TX, int K, int M, int OS, int AUG>
__launch_bounds__(256)
__global__ void k_mm(const TX* __restrict__ X, const float* __restrict__ W,
                     const float* __restrict__ dinv, h16* __restrict__ out, int n) {
  __shared__ float Xs[128 * 36];
  __shared__ float Ws[32 * 132];
  int tid = threadIdx.x;
  int row0 = blockIdx.x * 128;
  int tc = tid & 15, tr = tid >> 4;
  int c0 = tc * 8;
  float acc[8][8];
#pragma unroll
  for (int i = 0; i < 8; ++i)
#pragma unroll
    for (int j = 0; j < 8; ++j) acc[i][j] = 0.f;

  for (int kc = 0; kc < K; kc += 32) {
    __syncthreads();
    // stage W chunk rows kc..kc+31, cols 0..127 (zero-pad past M)
    for (int idx = tid * 4; idx < 32 * 128; idx += 1024) {
      int r = idx >> 7, c = idx & 127;
      float4 v = make_float4(0.f, 0.f, 0.f, 0.f);
      if (c < M) v = *(const float4*)&W[(size_t)(kc + r) * M + c];
      *(float4*)&Ws[r * 132 + c] = v;
    }
    // stage X chunk rows 0..127, cols kc..kc+31 (nt: streaming, never re-read)
    if (sizeof(TX) == 4) {
      for (int idx = tid * 4; idx < 128 * 32; idx += 1024) {
        int r = idx >> 5, c = idx & 31;
        f32x4 v = {0.f, 0.f, 0.f, 0.f};
        if (row0 + r < n)
          v = __builtin_nontemporal_load(
              (const f32x4*)&((const float*)X)[(size_t)(row0 + r) * K + kc + c]);
        *(f32x4*)&Xs[r * 36 + c] = v;
      }
    } else {
      for (int idx = tid * 8; idx < 128 * 32; idx += 2048) {
        int r = idx >> 5, c = idx & 31;      // c in {0,8,16,24}
        float f[8];
#pragma unroll
        for (int q = 0; q < 8; ++q) f[q] = 0.f;
        if (row0 + r < n) {
          const h16* p = &((const h16*)X)[(size_t)(row0 + r) * K + kc + c];
          h16x8 v8 = __builtin_nontemporal_load((const h16x8*)p);
#pragma unroll
          for (int q = 0; q < 8; ++q) f[q] = (float)v8[q];
        }
        *(float4*)&Xs[r * 36 + c]     = make_float4(f[0], f[1], f[2], f[3]);
        *(float4*)&Xs[r * 36 + c + 4] = make_float4(f[4], f[5], f[6], f[7]);
      }
    }
    __syncthreads();

    for (int k = 0; k < 32; k += 4) {
      float4 xf[8];
#pragma unroll
      for (int i = 0; i < 8; ++i) xf[i] = *(const float4*)&Xs[(tr + 16 * i) * 36 + k];
      float4 wa[4], wb[4];
#pragma unroll
      for (int kk = 0; kk < 4; ++kk) {
        wa[kk] = *(const float4*)&Ws[(k + kk) * 132 + c0];
        wb[kk] = *(const float4*)&Ws[(k + kk) * 132 + c0 + 4];
      }
#pragma unroll
      for (int i = 0; i < 8; ++i) {
#pragma unroll
        for (int kk = 0; kk < 4; ++kk) {
          float xv = f4get(xf[i], kk);
          acc[i][0] = fmaf(xv, wa[kk].x, acc[i][0]);
          acc[i][1] = fmaf(xv, wa[kk].y, acc[i][1]);
          acc[i][2] = fmaf(xv, wa[kk].z, acc[i][2]);
          acc[i][3] = fmaf(xv, wa[kk].w, acc[i][3]);
          acc[i][4] = fmaf(xv, wb[kk].x, acc[i][4]);
          acc[i][5] = fmaf(xv, wb[kk].y, acc[i][5]);
          acc[i][6] = fmaf(xv, wb[kk].z, acc[i][6]);
          acc[i][7] = fmaf(xv, wb[kk].w, acc[i][7]);
        }
      }
    }
  }

  // epilogue: linear fp16 rows, normal stores (populate L2 for gathers)
#pragma unroll
  for (int i = 0; i < 8; ++i) {
    int grow = row0 + tr + 16 * i;
    if (grow >= n) continue;
    if (c0 >= OS) continue;
    float sc = dinv[grow];
    h16x8 pk;
#pragma unroll
    for (int j = 0; j < 8; ++j) {
      int colj = c0 + j;
      float vv = (colj < M) ? acc[i][j] * sc : ((AUG && colj == 100) ? sc : 0.f);
      pk[j] = (h16)vv;
    }
    *(h16x8*)&out[(size_t)grow * OS + c0] = pk;
  }
}

// ---- aggregation: TWO nodes per wave.  Each half-wave (32 lanes) owns one
// node; lane covers 4 cols (h16x4 = 8B -> 32*8B = 256B row).  16 edge-rows
// in flight per node -> 64 L2 lines per wave.
// MODE 0: relu(dinv*(sum+self)+bias)  [width 128]
// MODE 1: dinv^2*(sum+self) (pre-scaled), fresh col seeded = dinv [width 104]
// MODE 2: final + rank-1 corrections -> fp32 out [n][100]  [width 100]
template <int WIDTH, int MODE>
__global__ void k_agg(const h16* __restrict__ hs, const int* __restrict__ offsets,
                      const int* __restrict__ col, const float* __restrict__ dinv,
                      const float* __restrict__ bias, const double* __restrict__ corr,
                      void* __restrict__ out, int n, int fresh) {
  const int STRIDE = 128;
  int gw = (blockIdx.x * 256 + threadIdx.x) >> 6;   // global wave id
  int lane = threadIdx.x & 63;
  int half = lane >> 5, sl = lane & 31;
  int v = gw * 2 + half;
  int c = sl * 4;
  if (v >= n) return;
  if (c >= WIDTH) return;
  const h16* row = &hs[(size_t)v * STRIDE];
  h16x4 selfv = *(const h16x4*)&row[c];
  float a0 = (float)selfv[0], a1 = (float)selfv[1];
  float a2 = (float)selfv[2], a3 = (float)selfv[3];
  int s = offsets[v], e = offsets[v + 1];
  for (int i = s; i < e; i += 16) {
    h16x4 m[16];
#pragma unroll
    for (int j = 0; j < 16; ++j) {
      h16x4 z = {(h16)0.f, (h16)0.f, (h16)0.f, (h16)0.f};
      m[j] = z;
      if (i + j < e) {
        int u = col[i + j];
        m[j] = *(const h16x4*)&hs[(size_t)u * STRIDE + c];
      }
    }
#pragma unroll
    for (int j = 0; j < 16; ++j) {
      a0 += (float)m[j][0]; a1 += (float)m[j][1];
      a2 += (float)m[j][2]; a3 += (float)m[j][3];
    }
  }
  float w = dinv[v];
  if (MODE == 0) {
    float r0 = fmaxf(fmaf(a0, w, bias[c]),     0.f);
    float r1 = fmaxf(fmaf(a1, w, bias[c + 1]), 0.f);
    float r2 = fmaxf(fmaf(a2, w, bias[c + 2]), 0.f);
    float r3 = fmaxf(fmaf(a3, w, bias[c + 3]), 0.f);
    h16x4 p = {(h16)r0, (h16)r1, (h16)r2, (h16)r3};
    *(h16x4*)&((h16*)out)[(size_t)v * STRIDE + c] = p;
  } else if (MODE == 1) {
    float w2 = w * w;
    float r0 = a0 * w2, r1 = a1 * w2, r2 = a2 * w2, r3 = a3 * w2;
    if (c == fresh) r0 = w;
    else if (c + 1 == fresh) r1 = w;
    else if (c + 2 == fresh) r2 = w;
    else if (c + 3 == fresh) r3 = w;
    h16x4 p = {(h16)r0, (h16)r1, (h16)r2, (h16)r3};
    *(h16x4*)&((h16*)out)[(size_t)v * STRIDE + c] = p;
  } else {
    float inv_w = 1.0f / w;
    float v3 = (float)row[100] * inv_w;
    float v2 = (float)row[101] * inv_w;
    float v1 = (float)row[102] * inv_w;
    float r[4] = {a0, a1, a2, a3};
    float4 o;
    float* op = &o.x;
#pragma unroll
    for (int q = 0; q < 4; ++q) {
      op[q] = r[q] * w + v3 * (float)corr[c + q] + v2 * (float)corr[128 + c + q]
            + v1 * (float)corr[256 + c + q] + (float)corr[384 + c + q];
    }
    *(float4*)&((float*)out)[(size_t)v * 100 + c] = o;
  }
}

// ---------------------------------------------------------------------------
extern "C" void kernel_launch(void* const* d_in, const int* in_sizes, int n_in,
                              void* d_out, int out_size, void* d_ws, size_t ws_size,
                              hipStream_t stream) {
  const float* x    = (const float*)d_in[0];
  const int*   edge = (const int*)d_in[1];
  const float* W1 = (const float*)d_in[2];  const float* b1 = (const float*)d_in[3];
  const float* W2 = (const float*)d_in[4];  const float* b2 = (const float*)d_in[5];
  const float* W3 = (const float*)d_in[6];  const float* b3 = (const float*)d_in[7];
  const float* W4 = (const float*)d_in[8];  const float* b4 = (const float*)d_in[9];
  const float* W5 = (const float*)d_in[10]; const float* b5 = (const float*)d_in[11];
  const float* Wl = (const float*)d_in[12]; const float* bl = (const float*)d_in[13];

  const int N = in_sizes[0] / 128;
  const int E = in_sizes[1] / 2;

  char* ws = (char*)d_ws;
  size_t cur = 0;
  auto alloc = [&](size_t bytes) -> char* {
    char* p = ws + cur;
    cur = (cur + bytes + 255) & ~(size_t)255;
    return p;
  };
  int*    counts    = (int*)alloc((size_t)N * 4);
  int*    flag      = (int*)alloc(4);
  int*    offsets   = (int*)alloc((size_t)(N + 1) * 4);
  float*  dinv      = (float*)alloc((size_t)N * 4);
  int*    chunksums = (int*)alloc(128 * 4);
  int*    chunkbase = (int*)alloc(128 * 4);
  double* R5        = (double*)alloc(128 * 100 * 8);
  double* R4        = (double*)alloc(128 * 100 * 8);
  double* R3        = (double*)alloc(128 * 100 * 8);
  double* Wcd       = (double*)alloc(128 * 100 * 8);
  float*  Wc        = (float*)alloc(128 * 100 * 4);
  double* corr      = (double*)alloc(512 * 8);
  int*    rank      = (int*)alloc((size_t)E * 4);
  int*    col       = (int*)alloc(((size_t)E + 16) * 4);  // +pad for group reads
  h16*    bufA      = (h16*)alloc((size_t)N * 128 * 2);   // stride 128, 256B rows
  h16*    bufB      = (h16*)alloc((size_t)N * 128 * 2);
  (void)ws_size; (void)n_in; (void)out_size;

  hipMemsetAsync(counts, 0, (size_t)N * 4, stream);
  hipMemsetAsync(flag, 0, 4, stream);

  const int nchunks = (N + 1023) / 1024;
  const int egrid = (E + 255) / 256;
  const int ngrid = (N + 255) / 256;

  k_detect<<<1, 256, 0, stream>>>(edge, flag);
  k_count<<<egrid, 256, 0, stream>>>(edge, flag, counts, rank, E);
  k_dinv<<<ngrid, 256, 0, stream>>>(counts, dinv, N);
  k_chunksum<<<nchunks, 256, 0, stream>>>(counts, chunksums, N);
  k_root<<<1, 128, 0, stream>>>(chunksums, chunkbase, nchunks);
  k_scan3<<<nchunks, 256, 0, stream>>>(counts, chunkbase, offsets, N, E);
  k_fill<<<egrid, 256, 0, stream>>>(edge, flag, offsets, rank, col, E);

  // weight chain (fp64): R5 = W5 Wl; R4 = W4 R5; R3 = W3 R4; Wc = W2 R3
  const int sgrid = (128 * 100 + 255) / 256;
  k_smm<float><<<sgrid, 256, 0, stream>>>(W5, Wl, R5, 128, 100, 100);
  k_smm<double><<<sgrid, 256, 0, stream>>>(W4, R5, R4, 128, 128, 100);
  k_smm<double><<<sgrid, 256, 0, stream>>>(W3, R4, R3, 128, 128, 100);
  k_smm<double><<<sgrid, 256, 0, stream>>>(W2, R3, Wcd, 128, 128, 100);
  k_d2f<<<sgrid, 256, 0, stream>>>(Wcd, Wc, 128 * 100);
  k_cvec<<<1, 128, 0, stream>>>(b2, b3, b4, b5, bl, Wl, R3, R4, R5, corr);

  const int mmgrid = (N + 127) / 128;
  const int agrid = (N + 7) / 8;   // 2 nodes/wave, 4 waves/block

  // hs0 = (x W1) * dinv  [fp16, stride 128]
  k_mm<float, 128, 128, 128, 0><<<mmgrid, 256, 0, stream>>>(x, W1, dinv, bufA, N);
  // h1 = relu(dinv*(gather+self) + b1)  [fp16, stride 128]
  k_agg<128, 0><<<agrid, 256, 0, stream>>>(bufA, offsets, col, dinv, b1, nullptr, bufB, N, 0);
  // g_scaled = (h1 Wc) * dinv, col100 = dinv seed  [fp16, stride 128]
  k_mm<h16, 128, 100, 128, 1><<<mmgrid, 256, 0, stream>>>(bufB, Wc, dinv, bufA, N);
  // three chained S applications (pre-scaled); s-chain in cols 100..102
  k_agg<104, 1><<<agrid, 256, 0, stream>>>(bufA, offsets, col, dinv, nullptr, nullptr, bufB, N, 101);
  k_agg<104, 1><<<agrid, 256, 0, stream>>>(bufB, offsets, col, dinv, nullptr, nullptr, bufA, N, 102);
  k_agg<104, 1><<<agrid, 256, 0, stream>>>(bufA, offsets, col, dinv, nullptr, nullptr, bufB, N, -1);
  // final S application + corrections -> d_out [fp32, N x 100]
  k_agg<100, 2><<<agrid, 256, 0, stream>>>(bufB, offsets, col, dinv, nullptr, corr, (float*)d_out, N, -1);
}

// Round 11
// 743.786 us; speedup vs baseline: 1.8096x; 1.0026x over previous
//
#include <hip/hip_runtime.h>

// ---------------------------------------------------------------------------
// GCN: 5x GCNConv + final linear.  N=100000, E=1.6M, D_IN=D_H=128, N_CLS=100.
//
// Collapsed algebra (R1-R3): h1 = relu(S x W1 + 1 b1^T),
//   out = S^4 h1 Wc + S^3 1 c2^T + S^2 1 c3^T + S 1 c4^T + 1 cb^T,
// weight chain in fp64 on device.  s_k = S^k 1 ride as feature cols 100..102.
// Feature buffers fp16 row-major, stride 128 (256B aligned rows = 2 L2 lines).
// Aggregation: FOUR nodes per wave (16 lanes x h16x8 = one 256B row per
// quarter-wave), 16 edge-rows in flight per node -> 128 lines/wave MLP.
// Ladder: 1 node/wave=110us -> 2/wave=82us -> this (4/wave).
// Lessons: R6 column slicing REVERTED; R7 nt stores REVERTED; R9 line-fetch
// reduction time-neutral (latency/MLP-bound, not byte-bound).
// ---------------------------------------------------------------------------

typedef _Float16 h16;
typedef _Float16 __attribute__((ext_vector_type(8))) h16x8;
typedef float __attribute__((ext_vector_type(4))) f32x4;

static __device__ __forceinline__ float f4get(const float4& v, int k) {
  switch (k) { case 0: return v.x; case 1: return v.y; case 2: return v.z; default: return v.w; }
}

// ---- edge dtype detection: if input is int64, odd int32 slots (hi words) are 0
__global__ void k_detect(const int* __restrict__ edge, int* __restrict__ flag) {
  int t = threadIdx.x;
  if (edge[2 * t + 1] != 0) atomicOr(flag, 1);
}

static __device__ __forceinline__ int load_idx(const int* edge, const int* flag, size_t pos) {
  bool is64 = (*flag == 0);
  if (is64) return (int)((const long long*)edge)[pos];
  return edge[pos];
}

__global__ void k_count(const int* __restrict__ edge, const int* __restrict__ flag,
                        int* __restrict__ counts, int* __restrict__ rank, int E) {
  int i = blockIdx.x * 256 + threadIdx.x;
  if (i >= E) return;
  int d = load_idx(edge, flag, (size_t)E + i);
  rank[i] = atomicAdd(&counts[d], 1);
}

__global__ void k_dinv(const int* __restrict__ counts, float* __restrict__ dinv, int n) {
  int i = blockIdx.x * 256 + threadIdx.x;
  if (i < n) dinv[i] = rsqrtf((float)counts[i] + 1.0f);
}

// ---- CSR build: chunk sums -> root scan -> per-chunk rescan ----
__global__ void k_chunksum(const int* __restrict__ counts, int* __restrict__ chunksums, int n) {
  __shared__ int sd[256];
  int t = threadIdx.x;
  int base = blockIdx.x * 1024 + t * 4;
  int s = 0;
#pragma unroll
  for (int j = 0; j < 4; ++j) { int i = base + j; if (i < n) s += counts[i]; }
  sd[t] = s; __syncthreads();
  for (int off = 128; off > 0; off >>= 1) {
    if (t < off) sd[t] += sd[t + off];
    __syncthreads();
  }
  if (t == 0) chunksums[blockIdx.x] = sd[0];
}

__global__ void k_root(const int* __restrict__ chunksums, int* __restrict__ chunkbase, int nchunks) {
  __shared__ int sc[128];
  int t = threadIdx.x;
  int v = (t < nchunks) ? chunksums[t] : 0;
  sc[t] = v; __syncthreads();
  for (int off = 1; off < 128; off <<= 1) {
    int x = (t >= off) ? sc[t - off] : 0;
    __syncthreads();
    sc[t] += x;
    __syncthreads();
  }
  if (t < nchunks) chunkbase[t] = sc[t] - v;
}

__global__ void k_scan3(const int* __restrict__ counts, const int* __restrict__ chunkbase,
                        int* __restrict__ offsets, int n, int E) {
  __shared__ int sd[256];
  int t = threadIdx.x;
  int base = blockIdx.x * 1024 + t * 4;
  int c[4]; int s = 0;
#pragma unroll
  for (int j = 0; j < 4; ++j) { int i = base + j; c[j] = (i < n) ? counts[i] : 0; s += c[j]; }
  sd[t] = s; __syncthreads();
  int v = s;
  for (int off = 1; off < 256; off <<= 1) {
    int x = (t >= off) ? sd[t - off] : 0;
    __syncthreads();
    sd[t] += x;
    __syncthreads();
  }
  int run = chunkbase[blockIdx.x] + sd[t] - v;
#pragma unroll
  for (int j = 0; j < 4; ++j) {
    int i = base + j;
    if (i < n) offsets[i] = run;
    run += c[j];
  }
  if (blockIdx.x == 0 && t == 0) offsets[n] = E;
}

__global__ void k_fill(const int* __restrict__ edge, const int* __restrict__ flag,
                       const int* __restrict__ offsets, const int* __restrict__ rank,
                       int* __restrict__ col, int E) {
  int i = blockIdx.x * 256 + threadIdx.x;
  if (i >= E) return;
  int s = load_idx(edge, flag, (size_t)i);
  int d = load_idx(edge, flag, (size_t)E + i);
  col[offsets[d] + rank[i]] = s;
}

// ---- tiny fp64 matmul for the weight chain ----
template <typename TB>
__global__ void k_smm(const float* __restrict__ A, const TB* __restrict__ B,
                      double* __restrict__ C, int M, int K, int Nc) {
  int idx = blockIdx.x * 256 + threadIdx.x;
  if (idx >= M * Nc) return;
  int i = idx / Nc, j = idx % Nc;
  double acc = 0.0;
  for (int k = 0; k < K; ++k) acc += (double)A[i * K + k] * (double)B[k * Nc + j];
  C[idx] = acc;
}

__global__ void k_d2f(const double* __restrict__ in, float* __restrict__ out, int n) {
  int i = blockIdx.x * 256 + threadIdx.x;
  if (i < n) out[i] = (float)in[i];
}

__global__ void k_cvec(const float* __restrict__ b2, const float* __restrict__ b3,
                       const float* __restrict__ b4, const float* __restrict__ b5,
                       const float* __restrict__ bl, const float* __restrict__ Wl,
                       const double* __restrict__ R3, const double* __restrict__ R4,
                       const double* __restrict__ R5, double* __restrict__ corr) {
  int j = threadIdx.x;
  if (j >= 100) return;
  double a2 = 0.0, a3 = 0.0, a4 = 0.0, acb = 0.0;
  for (int k = 0; k < 128; ++k) {
    a2 += (double)b2[k] * R3[k * 100 + j];
    a3 += (double)b3[k] * R4[k * 100 + j];
    a4 += (double)b4[k] * R5[k * 100 + j];
  }
  for (int k = 0; k < 100; ++k) acb += (double)b5[k] * (double)Wl[k * 100 + j];
  corr[j] = a2; corr[128 + j] = a3; corr[256 + j] = a4; corr[384 + j] = acb + (double)bl[j];
}

// ---- matmul: out[r][c] = (X@W)[r][c]*dinv[r], fp16 out, stride OS (linear).
// Split-K chunks of 32 -> LDS ~35 KB -> ~3 blocks/CU.
// AUG: col 100 = dinv[r] (s-chain seed), cols in [M,OS) except 100 -> 0.
// Epilogue stores NORMAL (cached): output feeds the next gather pass.
template <typename TX, int K, int M, int OS, int AUG>
__launch_bounds__(256)
__global__ void k_mm(const TX* __restrict__ X, const float* __restrict__ W,
                     const float* __restrict__ dinv, h16* __restrict__ out, int n) {
  __shared__ float Xs[128 * 36];
  __shared__ float Ws[32 * 132];
  int tid = threadIdx.x;
  int row0 = blockIdx.x * 128;
  int tc = tid & 15, tr = tid >> 4;
  int c0 = tc * 8;
  float acc[8][8];
#pragma unroll
  for (int i = 0; i < 8; ++i)
#pragma unroll
    for (int j = 0; j < 8; ++j) acc[i][j] = 0.f;

  for (int kc = 0; kc < K; kc += 32) {
    __syncthreads();
    // stage W chunk rows kc..kc+31, cols 0..127 (zero-pad past M)
    for (int idx = tid * 4; idx < 32 * 128; idx += 1024) {
      int r = idx >> 7, c = idx & 127;
      float4 v = make_float4(0.f, 0.f, 0.f, 0.f);
      if (c < M) v = *(const float4*)&W[(size_t)(kc + r) * M + c];
      *(float4*)&Ws[r * 132 + c] = v;
    }
    // stage X chunk rows 0..127, cols kc..kc+31 (nt: streaming, never re-read)
    if (sizeof(TX) == 4) {
      for (int idx = tid * 4; idx < 128 * 32; idx += 1024) {
        int r = idx >> 5, c = idx & 31;
        f32x4 v = {0.f, 0.f, 0.f, 0.f};
        if (row0 + r < n)
          v = __builtin_nontemporal_load(
              (const f32x4*)&((const float*)X)[(size_t)(row0 + r) * K + kc + c]);
        *(f32x4*)&Xs[r * 36 + c] = v;
      }
    } else {
      for (int idx = tid * 8; idx < 128 * 32; idx += 2048) {
        int r = idx >> 5, c = idx & 31;      // c in {0,8,16,24}
        float f[8];
#pragma unroll
        for (int q = 0; q < 8; ++q) f[q] = 0.f;
        if (row0 + r < n) {
          const h16* p = &((const h16*)X)[(size_t)(row0 + r) * K + kc + c];
          h16x8 v8 = __builtin_nontemporal_load((const h16x8*)p);
#pragma unroll
          for (int q = 0; q < 8; ++q) f[q] = (float)v8[q];
        }
        *(float4*)&Xs[r * 36 + c]     = make_float4(f[0], f[1], f[2], f[3]);
        *(float4*)&Xs[r * 36 + c + 4] = make_float4(f[4], f[5], f[6], f[7]);
      }
    }
    __syncthreads();

    for (int k = 0; k < 32; k += 4) {
      float4 xf[8];
#pragma unroll
      for (int i = 0; i < 8; ++i) xf[i] = *(const float4*)&Xs[(tr + 16 * i) * 36 + k];
      float4 wa[4], wb[4];
#pragma unroll
      for (int kk = 0; kk < 4; ++kk) {
        wa[kk] = *(const float4*)&Ws[(k + kk) * 132 + c0];
        wb[kk] = *(const float4*)&Ws[(k + kk) * 132 + c0 + 4];
      }
#pragma unroll
      for (int i = 0; i < 8; ++i) {
#pragma unroll
        for (int kk = 0; kk < 4; ++kk) {
          float xv = f4get(xf[i], kk);
          acc[i][0] = fmaf(xv, wa[kk].x, acc[i][0]);
          acc[i][1] = fmaf(xv, wa[kk].y, acc[i][1]);
          acc[i][2] = fmaf(xv, wa[kk].z, acc[i][2]);
          acc[i][3] = fmaf(xv, wa[kk].w, acc[i][3]);
          acc[i][4] = fmaf(xv, wb[kk].x, acc[i][4]);
          acc[i][5] = fmaf(xv, wb[kk].y, acc[i][5]);
          acc[i][6] = fmaf(xv, wb[kk].z, acc[i][6]);
          acc[i][7] = fmaf(xv, wb[kk].w, acc[i][7]);
        }
      }
    }
  }

  // epilogue: linear fp16 rows, normal stores (populate L2 for gathers)
#pragma unroll
  for (int i = 0; i < 8; ++i) {
    int grow = row0 + tr + 16 * i;
    if (grow >= n) continue;
    if (c0 >= OS) continue;
    float sc = dinv[grow];
    h16x8 pk;
#pragma unroll
    for (int j = 0; j < 8; ++j) {
      int colj = c0 + j;
      float vv = (colj < M) ? acc[i][j] * sc : ((AUG && colj == 100) ? sc : 0.f);
      pk[j] = (h16)vv;
    }
    *(h16x8*)&out[(size_t)grow * OS + c0] = pk;
  }
}

// ---- aggregation: FOUR nodes per wave.  Each quarter-wave (16 lanes) owns
// one node; lane covers 8 cols (h16x8 = 16B -> 16*16B = 256B row).  16
// edge-rows in flight per node -> 128 L2 lines per wave.
// MODE 0: relu(dinv*(sum+self)+bias)  [width 128]
// MODE 1: dinv^2*(sum+self) (pre-scaled), fresh col seeded = dinv [width 104]
// MODE 2: final + rank-1 corrections -> fp32 out [n][100]  [width 100]
template <int WIDTH, int MODE>
__global__ void k_agg(const h16* __restrict__ hs, const int* __restrict__ offsets,
                      const int* __restrict__ col, const float* __restrict__ dinv,
                      const float* __restrict__ bias, const double* __restrict__ corr,
                      void* __restrict__ out, int n, int fresh) {
  const int STRIDE = 128;
  int gw = (blockIdx.x * 256 + threadIdx.x) >> 6;   // global wave id
  int lane = threadIdx.x & 63;
  int q4 = lane >> 4, sl = lane & 15;
  int v = gw * 4 + q4;
  int c = sl * 8;
  if (v >= n) return;
  if (WIDTH != 128 && c >= WIDTH) return;   // width 104/100: lanes 13..15 idle
  const h16* row = &hs[(size_t)v * STRIDE];
  h16x8 selfv = *(const h16x8*)&row[c];
  float a[8];
#pragma unroll
  for (int q = 0; q < 8; ++q) a[q] = (float)selfv[q];
  int s = offsets[v], e = offsets[v + 1];
  for (int i = s; i < e; i += 16) {
    h16x8 m[16];
#pragma unroll
    for (int j = 0; j < 16; ++j) {
      h16x8 z = {(h16)0.f, (h16)0.f, (h16)0.f, (h16)0.f,
                 (h16)0.f, (h16)0.f, (h16)0.f, (h16)0.f};
      m[j] = z;
      if (i + j < e) {
        int u = col[i + j];
        m[j] = *(const h16x8*)&hs[(size_t)u * STRIDE + c];
      }
    }
#pragma unroll
    for (int j = 0; j < 16; ++j) {
#pragma unroll
      for (int q = 0; q < 8; ++q) a[q] += (float)m[j][q];
    }
  }
  float w = dinv[v];
  if (MODE == 0) {
    h16x8 p;
#pragma unroll
    for (int q = 0; q < 8; ++q)
      p[q] = (h16)fmaxf(fmaf(a[q], w, bias[c + q]), 0.f);
    *(h16x8*)&((h16*)out)[(size_t)v * STRIDE + c] = p;
  } else if (MODE == 1) {
    float w2 = w * w;
    h16x8 p;
#pragma unroll
    for (int q = 0; q < 8; ++q) {
      float r = a[q] * w2;
      if (c + q == fresh) r = w;        // seed column: dinv * 1
      p[q] = (h16)r;
    }
    *(h16x8*)&((h16*)out)[(size_t)v * STRIDE + c] = p;
  } else {
    float inv_w = 1.0f / w;
    float v3 = (float)row[100] * inv_w;
    float v2 = (float)row[101] * inv_w;
    float v1 = (float)row[102] * inv_w;
    float r[8];
#pragma unroll
    for (int q = 0; q < 8; ++q) {
      int cc = c + q;
      r[q] = (cc < 100)
           ? a[q] * w + v3 * (float)corr[cc] + v2 * (float)corr[128 + cc]
             + v1 * (float)corr[256 + cc] + (float)corr[384 + cc]
           : 0.f;
    }
    float* o = &((float*)out)[(size_t)v * 100 + c];
    if (c + 4 <= 100) *(float4*)&o[0] = make_float4(r[0], r[1], r[2], r[3]);
    if (c + 8 <= 100) *(float4*)&o[4] = make_float4(r[4], r[5], r[6], r[7]);
  }
}

// ---------------------------------------------------------------------------
extern "C" void kernel_launch(void* const* d_in, const int* in_sizes, int n_in,
                              void* d_out, int out_size, void* d_ws, size_t ws_size,
                              hipStream_t stream) {
  const float* x    = (const float*)d_in[0];
  const int*   edge = (const int*)d_in[1];
  const float* W1 = (const float*)d_in[2];  const float* b1 = (const float*)d_in[3];
  const float* W2 = (const float*)d_in[4];  const float* b2 = (const float*)d_in[5];
  const float* W3 = (const float*)d_in[6];  const float* b3 = (const float*)d_in[7];
  const float* W4 = (const float*)d_in[8];  const float* b4 = (const float*)d_in[9];
  const float* W5 = (const float*)d_in[10]; const float* b5 = (const float*)d_in[11];
  const float* Wl = (const float*)d_in[12]; const float* bl = (const float*)d_in[13];

  const int N = in_sizes[0] / 128;
  const int E = in_sizes[1] / 2;

  char* ws = (char*)d_ws;
  size_t cur = 0;
  auto alloc = [&](size_t bytes) -> char* {
    char* p = ws + cur;
    cur = (cur + bytes + 255) & ~(size_t)255;
    return p;
  };
  int*    counts    = (int*)alloc((size_t)N * 4);
  int*    flag      = (int*)alloc(4);
  int*    offsets   = (int*)alloc((size_t)(N + 1) * 4);
  float*  dinv      = (float*)alloc((size_t)N * 4);
  int*    chunksums = (int*)alloc(128 * 4);
  int*    chunkbase = (int*)alloc(128 * 4);
  double* R5        = (double*)alloc(128 * 100 * 8);
  double* R4        = (double*)alloc(128 * 100 * 8);
  double* R3        = (double*)alloc(128 * 100 * 8);
  double* Wcd       = (double*)alloc(128 * 100 * 8);
  float*  Wc        = (float*)alloc(128 * 100 * 4);
  double* corr      = (double*)alloc(512 * 8);
  int*    rank      = (int*)alloc((size_t)E * 4);
  int*    col       = (int*)alloc(((size_t)E + 16) * 4);  // +pad for group reads
  h16*    bufA      = (h16*)alloc((size_t)N * 128 * 2);   // stride 128, 256B rows
  h16*    bufB      = (h16*)alloc((size_t)N * 128 * 2);
  (void)ws_size; (void)n_in; (void)out_size;

  hipMemsetAsync(counts, 0, (size_t)N * 4, stream);
  hipMemsetAsync(flag, 0, 4, stream);

  const int nchunks = (N + 1023) / 1024;
  const int egrid = (E + 255) / 256;
  const int ngrid = (N + 255) / 256;

  k_detect<<<1, 256, 0, stream>>>(edge, flag);
  k_count<<<egrid, 256, 0, stream>>>(edge, flag, counts, rank, E);
  k_dinv<<<ngrid, 256, 0, stream>>>(counts, dinv, N);
  k_chunksum<<<nchunks, 256, 0, stream>>>(counts, chunksums, N);
  k_root<<<1, 128, 0, stream>>>(chunksums, chunkbase, nchunks);
  k_scan3<<<nchunks, 256, 0, stream>>>(counts, chunkbase, offsets, N, E);
  k_fill<<<egrid, 256, 0, stream>>>(edge, flag, offsets, rank, col, E);

  // weight chain (fp64): R5 = W5 Wl; R4 = W4 R5; R3 = W3 R4; Wc = W2 R3
  const int sgrid = (128 * 100 + 255) / 256;
  k_smm<float><<<sgrid, 256, 0, stream>>>(W5, Wl, R5, 128, 100, 100);
  k_smm<double><<<sgrid, 256, 0, stream>>>(W4, R5, R4, 128, 128, 100);
  k_smm<double><<<sgrid, 256, 0, stream>>>(W3, R4, R3, 128, 128, 100);
  k_smm<double><<<sgrid, 256, 0, stream>>>(W2, R3, Wcd, 128, 128, 100);
  k_d2f<<<sgrid, 256, 0, stream>>>(Wcd, Wc, 128 * 100);
  k_cvec<<<1, 128, 0, stream>>>(b2, b3, b4, b5, bl, Wl, R3, R4, R5, corr);

  const int mmgrid = (N + 127) / 128;
  const int agrid = (N + 15) / 16;   // 4 nodes/wave, 4 waves/block

  // hs0 = (x W1) * dinv  [fp16, stride 128]
  k_mm<float, 128, 128, 128, 0><<<mmgrid, 256, 0, stream>>>(x, W1, dinv, bufA, N);
  // h1 = relu(dinv*(gather+self) + b1)  [fp16, stride 128]
  k_agg<128, 0><<<agrid, 256, 0, stream>>>(bufA, offsets, col, dinv, b1, nullptr, bufB, N, 0);
  // g_scaled = (h1 Wc) * dinv, col100 = dinv seed  [fp16, stride 128]
  k_mm<h16, 128, 100, 128, 1><<<mmgrid, 256, 0, stream>>>(bufB, Wc, dinv, bufA, N);
  // three chained S applications (pre-scaled); s-chain in cols 100..102
  k_agg<104, 1><<<agrid, 256, 0, stream>>>(bufA, offsets, col, dinv, nullptr, nullptr, bufB, N, 101);
  k_agg<104, 1><<<agrid, 256, 0, stream>>>(bufB, offsets, col, dinv, nullptr, nullptr, bufA, N, 102);
  k_agg<104, 1><<<agrid, 256, 0, stream>>>(bufA, offsets, col, dinv, nullptr, nullptr, bufB, N, -1);
  // final S application + corrections -> d_out [fp32, N x 100]
  k_agg<100, 2><<<agrid, 256, 0, stream>>>(bufB, offsets, col, dinv, nullptr, corr, (float*)d_out, N, -1);
}

// Round 12
// 736.466 us; speedup vs baseline: 1.8276x; 1.0099x over previous
//
#include <hip/hip_runtime.h>

// ---------------------------------------------------------------------------
// GCN: 5x GCNConv + final linear.  N=100000, E=1.6M, D_IN=D_H=128, N_CLS=100.
//
// Collapsed algebra (R1-R3): h1 = relu(S x W1 + 1 b1^T),
//   out = S^4 h1 Wc + S^3 1 c2^T + S^2 1 c3^T + S 1 c4^T + 1 cb^T,
// weight chain fp32 on device (rel err ~1e-6; R12 change from fp64 —
// the fp64 chain was latency-bound at ~1/16 rate).
// s_k = S^k 1 ride as feature cols 100..102.
// Feature buffers fp16 row-major, stride 128 (256B aligned rows = 2 L2 lines).
// Aggregation: TWO nodes per wave (32 lanes x h16x4/lane = one 256B row per
// half-wave), 16 edge-rows in flight per node.  PROVEN OPTIMUM:
// 1/wave=110us, 2/wave=82us, 4/wave=88us (VGPR/occupancy cliff).
// Gather is at the random-line fetch-throughput wall (~2.9TB/s): R9 fewer
// bytes = null, R11 more MLP = null.  Lessons: R6 column slicing REVERTED;
// R7 nt stores REVERTED (outputs must land in L2 for the next gather).
// ---------------------------------------------------------------------------

typedef _Float16 h16;
typedef _Float16 __attribute__((ext_vector_type(4))) h16x4;
typedef _Float16 __attribute__((ext_vector_type(8))) h16x8;
typedef float __attribute__((ext_vector_type(4))) f32x4;

static __device__ __forceinline__ float f4get(const float4& v, int k) {
  switch (k) { case 0: return v.x; case 1: return v.y; case 2: return v.z; default: return v.w; }
}

// ---- edge dtype detection: if input is int64, odd int32 slots (hi words) are 0
__global__ void k_detect(const int* __restrict__ edge, int* __restrict__ flag) {
  int t = threadIdx.x;
  if (edge[2 * t + 1] != 0) atomicOr(flag, 1);
}

static __device__ __forceinline__ int load_idx(const int* edge, const int* flag, size_t pos) {
  bool is64 = (*flag == 0);
  if (is64) return (int)((const long long*)edge)[pos];
  return edge[pos];
}

// count degrees, record per-edge rank within dst, emit compact dst stream
__global__ void k_count(const int* __restrict__ edge, const int* __restrict__ flag,
                        int* __restrict__ counts, int* __restrict__ rank,
                        int* __restrict__ dstc, int E) {
  int i = blockIdx.x * 256 + threadIdx.x;
  if (i >= E) return;
  int d = load_idx(edge, flag, (size_t)E + i);
  dstc[i] = d;
  rank[i] = atomicAdd(&counts[d], 1);
}

__global__ void k_dinv(const int* __restrict__ counts, float* __restrict__ dinv, int n) {
  int i = blockIdx.x * 256 + threadIdx.x;
  if (i < n) dinv[i] = rsqrtf((float)counts[i] + 1.0f);
}

// ---- CSR build: chunk sums -> root scan -> per-chunk rescan ----
__global__ void k_chunksum(const int* __restrict__ counts, int* __restrict__ chunksums, int n) {
  __shared__ int sd[256];
  int t = threadIdx.x;
  int base = blockIdx.x * 1024 + t * 4;
  int s = 0;
#pragma unroll
  for (int j = 0; j < 4; ++j) { int i = base + j; if (i < n) s += counts[i]; }
  sd[t] = s; __syncthreads();
  for (int off = 128; off > 0; off >>= 1) {
    if (t < off) sd[t] += sd[t + off];
    __syncthreads();
  }
  if (t == 0) chunksums[blockIdx.x] = sd[0];
}

__global__ void k_root(const int* __restrict__ chunksums, int* __restrict__ chunkbase, int nchunks) {
  __shared__ int sc[128];
  int t = threadIdx.x;
  int v = (t < nchunks) ? chunksums[t] : 0;
  sc[t] = v; __syncthreads();
  for (int off = 1; off < 128; off <<= 1) {
    int x = (t >= off) ? sc[t - off] : 0;
    __syncthreads();
    sc[t] += x;
    __syncthreads();
  }
  if (t < nchunks) chunkbase[t] = sc[t] - v;
}

__global__ void k_scan3(const int* __restrict__ counts, const int* __restrict__ chunkbase,
                        int* __restrict__ offsets, int n, int E) {
  __shared__ int sd[256];
  int t = threadIdx.x;
  int base = blockIdx.x * 1024 + t * 4;
  int c[4]; int s = 0;
#pragma unroll
  for (int j = 0; j < 4; ++j) { int i = base + j; c[j] = (i < n) ? counts[i] : 0; s += c[j]; }
  sd[t] = s; __syncthreads();
  int v = s;
  for (int off = 1; off < 256; off <<= 1) {
    int x = (t >= off) ? sd[t - off] : 0;
    __syncthreads();
    sd[t] += x;
    __syncthreads();
  }
  int run = chunkbase[blockIdx.x] + sd[t] - v;
#pragma unroll
  for (int j = 0; j < 4; ++j) {
    int i = base + j;
    if (i < n) offsets[i] = run;
    run += c[j];
  }
  if (blockIdx.x == 0 && t == 0) offsets[n] = E;
}

// atomic-free fill: position = offsets[dst] + rank; src from edge, dst compact
__global__ void k_fill(const int* __restrict__ edge, const int* __restrict__ flag,
                       const int* __restrict__ offsets, const int* __restrict__ rank,
                       const int* __restrict__ dstc, int* __restrict__ col, int E) {
  int i = blockIdx.x * 256 + threadIdx.x;
  if (i >= E) return;
  int s = load_idx(edge, flag, (size_t)i);
  int d = dstc[i];
  col[offsets[d] + rank[i]] = s;
}

// ---- small fp32 matmul for the weight chain: C[MxNc] = A[MxK] B[KxNc] ----
__global__ void k_smm(const float* __restrict__ A, const float* __restrict__ B,
                      float* __restrict__ C, int M, int K, int Nc) {
  int idx = blockIdx.x * 256 + threadIdx.x;
  if (idx >= M * Nc) return;
  int i = idx / Nc, j = idx % Nc;
  float acc = 0.f;
  for (int k = 0; k < K; ++k) acc = fmaf(A[i * K + k], B[k * Nc + j], acc);
  C[idx] = acc;
}

__global__ void k_cvec(const float* __restrict__ b2, const float* __restrict__ b3,
                       const float* __restrict__ b4, const float* __restrict__ b5,
                       const float* __restrict__ bl, const float* __restrict__ Wl,
                       const float* __restrict__ R3, const float* __restrict__ R4,
                       const float* __restrict__ R5, float* __restrict__ corr) {
  int j = threadIdx.x;
  if (j >= 100) return;
  float a2 = 0.f, a3 = 0.f, a4 = 0.f, acb = 0.f;
  for (int k = 0; k < 128; ++k) {
    a2 = fmaf(b2[k], R3[k * 100 + j], a2);
    a3 = fmaf(b3[k], R4[k * 100 + j], a3);
    a4 = fmaf(b4[k], R5[k * 100 + j], a4);
  }
  for (int k = 0; k < 100; ++k) acb = fmaf(b5[k], Wl[k * 100 + j], acb);
  corr[j] = a2; corr[128 + j] = a3; corr[256 + j] = a4; corr[384 + j] = acb + bl[j];
}

// ---- matmul: out[r][c] = (X@W)[r][c]*dinv[r], fp16 out, stride OS (linear).
// Split-K chunks of 32 -> LDS ~35 KB -> ~3 blocks/CU.
// AUG: col 100 = dinv[r] (s-chain seed), cols in [M,OS) except 100 -> 0.
// Epilogue stores NORMAL (cached): output feeds the next gather pass.
template <typename TX, int K, int M, int OS, int AUG>
__launch_bounds__(256)
__global__ void k_mm(const TX* __restrict__ X, const float* __restrict__ W,
                     const float* __restrict__ dinv, h16* __restrict__ out, int n) {
  __shared__ float Xs[128 * 36];
  __shared__ float Ws[32 * 132];
  int tid = threadIdx.x;
  int row0 = blockIdx.x * 128;
  int tc = tid & 15, tr = tid >> 4;
  int c0 = tc * 8;
  float acc[8][8];
#pragma unroll
  for (int i = 0; i < 8; ++i)
#pragma unroll
    for (int j = 0; j < 8; ++j) acc[i][j] = 0.f;

  for (int kc = 0; kc < K; kc += 32) {
    __syncthreads();
    // stage W chunk rows kc..kc+31, cols 0..127 (zero-pad past M)
    for (int idx = tid * 4; idx < 32 * 128; idx += 1024) {
      int r = idx >> 7, c = idx & 127;
      float4 v = make_float4(0.f, 0.f, 0.f, 0.f);
      if (c < M) v = *(const float4*)&W[(size_t)(kc + r) * M + c];
      *(float4*)&Ws[r * 132 + c] = v;
    }
    // stage X chunk rows 0..127, cols kc..kc+31 (nt: streaming, never re-read)
    if (sizeof(TX) == 4) {
      for (int idx = tid * 4; idx < 128 * 32; idx += 1024) {
        int r = idx >> 5, c = idx & 31;
        f32x4 v = {0.f, 0.f, 0.f, 0.f};
        if (row0 + r < n)
          v = __builtin_nontemporal_load(
              (const f32x4*)&((const float*)X)[(size_t)(row0 + r) * K + kc + c]);
        *(f32x4*)&Xs[r * 36 + c] = v;
      }
    } else {
      for (int idx = tid * 8; idx < 128 * 32; idx += 2048) {
        int r = idx >> 5, c = idx & 31;      // c in {0,8,16,24}
        float f[8];
#pragma unroll
        for (int q = 0; q < 8; ++q) f[q] = 0.f;
        if (row0 + r < n) {
          const h16* p = &((const h16*)X)[(size_t)(row0 + r) * K + kc + c];
          h16x8 v8 = __builtin_nontemporal_load((const h16x8*)p);
#pragma unroll
          for (int q = 0; q < 8; ++q) f[q] = (float)v8[q];
        }
        *(float4*)&Xs[r * 36 + c]     = make_float4(f[0], f[1], f[2], f[3]);
        *(float4*)&Xs[r * 36 + c + 4] = make_float4(f[4], f[5], f[6], f[7]);
      }
    }
    __syncthreads();

    for (int k = 0; k < 32; k += 4) {
      float4 xf[8];
#pragma unroll
      for (int i = 0; i < 8; ++i) xf[i] = *(const float4*)&Xs[(tr + 16 * i) * 36 + k];
      float4 wa[4], wb[4];
#pragma unroll
      for (int kk = 0; kk < 4; ++kk) {
        wa[kk] = *(const float4*)&Ws[(k + kk) * 132 + c0];
        wb[kk] = *(const float4*)&Ws[(k + kk) * 132 + c0 + 4];
      }
#pragma unroll
      for (int i = 0; i < 8; ++i) {
#pragma unroll
        for (int kk = 0; kk < 4; ++kk) {
          float xv = f4get(xf[i], kk);
          acc[i][0] = fmaf(xv, wa[kk].x, acc[i][0]);
          acc[i][1] = fmaf(xv, wa[kk].y, acc[i][1]);
          acc[i][2] = fmaf(xv, wa[kk].z, acc[i][2]);
          acc[i][3] = fmaf(xv, wa[kk].w, acc[i][3]);
          acc[i][4] = fmaf(xv, wb[kk].x, acc[i][4]);
          acc[i][5] = fmaf(xv, wb[kk].y, acc[i][5]);
          acc[i][6] = fmaf(xv, wb[kk].z, acc[i][6]);
          acc[i][7] = fmaf(xv, wb[kk].w, acc[i][7]);
        }
      }
    }
  }

  // epilogue: linear fp16 rows, normal stores (populate L2 for gathers)
#pragma unroll
  for (int i = 0; i < 8; ++i) {
    int grow = row0 + tr + 16 * i;
    if (grow >= n) continue;
    if (c0 >= OS) continue;
    float sc = dinv[grow];
    h16x8 pk;
#pragma unroll
    for (int j = 0; j < 8; ++j) {
      int colj = c0 + j;
      float vv = (colj < M) ? acc[i][j] * sc : ((AUG && colj == 100) ? sc : 0.f);
      pk[j] = (h16)vv;
    }
    *(h16x8*)&out[(size_t)grow * OS + c0] = pk;
  }
}

// ---- aggregation: TWO nodes per wave (proven optimum).  Each half-wave
// (32 lanes) owns one node; lane covers 4 cols (h16x4 = 8B -> 256B row).
// 16 edge-rows in flight per node.
// MODE 0: relu(dinv*(sum+self)+bias)  [width 128]
// MODE 1: dinv^2*(sum+self) (pre-scaled), fresh col seeded = dinv [width 104]
// MODE 2: final + rank-1 corrections -> fp32 out [n][100]  [width 100]
template <int WIDTH, int MODE>
__global__ void k_agg(const h16* __restrict__ hs, const int* __restrict__ offsets,
                      const int* __restrict__ col, const float* __restrict__ dinv,
                      const float* __restrict__ bias, const float* __restrict__ corr,
                      void* __restrict__ out, int n, int fresh) {
  const int STRIDE = 128;
  int gw = (blockIdx.x * 256 + threadIdx.x) >> 6;   // global wave id
  int lane = threadIdx.x & 63;
  int half = lane >> 5, sl = lane & 31;
  int v = gw * 2 + half;
  int c = sl * 4;
  if (v >= n) return;
  if (c >= WIDTH) return;
  const h16* row = &hs[(size_t)v * STRIDE];
  h16x4 selfv = *(const h16x4*)&row[c];
  float a0 = (float)selfv[0], a1 = (float)selfv[1];
  float a2 = (float)selfv[2], a3 = (float)selfv[3];
  int s = offsets[v], e = offsets[v + 1];
  for (int i = s; i < e; i += 16) {
    h16x4 m[16];
#pragma unroll
    for (int j = 0; j < 16; ++j) {
      h16x4 z = {(h16)0.f, (h16)0.f, (h16)0.f, (h16)0.f};
      m[j] = z;
      if (i + j < e) {
        int u = col[i + j];
        m[j] = *(const h16x4*)&hs[(size_t)u * STRIDE + c];
      }
    }
#pragma unroll
    for (int j = 0; j < 16; ++j) {
      a0 += (float)m[j][0]; a1 += (float)m[j][1];
      a2 += (float)m[j][2]; a3 += (float)m[j][3];
    }
  }
  float w = dinv[v];
  if (MODE == 0) {
    float r0 = fmaxf(fmaf(a0, w, bias[c]),     0.f);
    float r1 = fmaxf(fmaf(a1, w, bias[c + 1]), 0.f);
    float r2 = fmaxf(fmaf(a2, w, bias[c + 2]), 0.f);
    float r3 = fmaxf(fmaf(a3, w, bias[c + 3]), 0.f);
    h16x4 p = {(h16)r0, (h16)r1, (h16)r2, (h16)r3};
    *(h16x4*)&((h16*)out)[(size_t)v * STRIDE + c] = p;
  } else if (MODE == 1) {
    float w2 = w * w;
    float r0 = a0 * w2, r1 = a1 * w2, r2 = a2 * w2, r3 = a3 * w2;
    if (c == fresh) r0 = w;
    else if (c + 1 == fresh) r1 = w;
    else if (c + 2 == fresh) r2 = w;
    else if (c + 3 == fresh) r3 = w;
    h16x4 p = {(h16)r0, (h16)r1, (h16)r2, (h16)r3};
    *(h16x4*)&((h16*)out)[(size_t)v * STRIDE + c] = p;
  } else {
    float inv_w = 1.0f / w;
    float v3 = (float)row[100] * inv_w;
    float v2 = (float)row[101] * inv_w;
    float v1 = (float)row[102] * inv_w;
    float r[4] = {a0, a1, a2, a3};
    float4 o;
    float* op = &o.x;
#pragma unroll
    for (int q = 0; q < 4; ++q) {
      op[q] = r[q] * w + v3 * corr[c + q] + v2 * corr[128 + c + q]
            + v1 * corr[256 + c + q] + corr[384 + c + q];
    }
    *(float4*)&((float*)out)[(size_t)v * 100 + c] = o;
  }
}

// ---------------------------------------------------------------------------
extern "C" void kernel_launch(void* const* d_in, const int* in_sizes, int n_in,
                              void* d_out, int out_size, void* d_ws, size_t ws_size,
                              hipStream_t stream) {
  const float* x    = (const float*)d_in[0];
  const int*   edge = (const int*)d_in[1];
  const float* W1 = (const float*)d_in[2];  const float* b1 = (const float*)d_in[3];
  const float* W2 = (const float*)d_in[4];  const float* b2 = (const float*)d_in[5];
  const float* W3 = (const float*)d_in[6];  const float* b3 = (const float*)d_in[7];
  const float* W4 = (const float*)d_in[8];  const float* b4 = (const float*)d_in[9];
  const float* W5 = (const float*)d_in[10]; const float* b5 = (const float*)d_in[11];
  const float* Wl = (const float*)d_in[12]; const float* bl = (const float*)d_in[13];

  const int N = in_sizes[0] / 128;
  const int E = in_sizes[1] / 2;

  char* ws = (char*)d_ws;
  size_t cur = 0;
  auto alloc = [&](size_t bytes) -> char* {
    char* p = ws + cur;
    cur = (cur + bytes + 255) & ~(size_t)255;
    return p;
  };
  int*    counts    = (int*)alloc((size_t)N * 4);
  int*    flag      = (int*)alloc(4);
  int*    offsets   = (int*)alloc((size_t)(N + 1) * 4);
  float*  dinv      = (float*)alloc((size_t)N * 4);
  int*    chunksums = (int*)alloc(128 * 4);
  int*    chunkbase = (int*)alloc(128 * 4);
  float*  R5        = (float*)alloc(128 * 100 * 4);
  float*  R4        = (float*)alloc(128 * 100 * 4);
  float*  R3        = (float*)alloc(128 * 100 * 4);
  float*  Wc        = (float*)alloc(128 * 100 * 4);
  float*  corr      = (float*)alloc(512 * 4);
  int*    rank      = (int*)alloc((size_t)E * 4);
  int*    dstc      = (int*)alloc((size_t)E * 4);
  int*    col       = (int*)alloc(((size_t)E + 16) * 4);  // +pad for group reads
  h16*    bufA      = (h16*)alloc((size_t)N * 128 * 2);   // stride 128, 256B rows
  h16*    bufB      = (h16*)alloc((size_t)N * 128 * 2);
  (void)ws_size; (void)n_in; (void)out_size;

  hipMemsetAsync(counts, 0, (size_t)N * 4, stream);
  hipMemsetAsync(flag, 0, 4, stream);

  const int nchunks = (N + 1023) / 1024;
  const int egrid = (E + 255) / 256;
  const int ngrid = (N + 255) / 256;

  k_detect<<<1, 256, 0, stream>>>(edge, flag);
  k_count<<<egrid, 256, 0, stream>>>(edge, flag, counts, rank, dstc, E);
  k_dinv<<<ngrid, 256, 0, stream>>>(counts, dinv, N);
  k_chunksum<<<nchunks, 256, 0, stream>>>(counts, chunksums, N);
  k_root<<<1, 128, 0, stream>>>(chunksums, chunkbase, nchunks);
  k_scan3<<<nchunks, 256, 0, stream>>>(counts, chunkbase, offsets, N, E);
  k_fill<<<egrid, 256, 0, stream>>>(edge, flag, offsets, rank, dstc, col, E);

  // weight chain (fp32): R5 = W5 Wl; R4 = W4 R5; R3 = W3 R4; Wc = W2 R3
  const int sgrid = (128 * 100 + 255) / 256;
  k_smm<<<sgrid, 256, 0, stream>>>(W5, Wl, R5, 128, 100, 100);
  k_smm<<<sgrid, 256, 0, stream>>>(W4, R5, R4, 128, 128, 100);
  k_smm<<<sgrid, 256, 0, stream>>>(W3, R4, R3, 128, 128, 100);
  k_smm<<<sgrid, 256, 0, stream>>>(W2, R3, Wc, 128, 128, 100);
  k_cvec<<<1, 128, 0, stream>>>(b2, b3, b4, b5, bl, Wl, R3, R4, R5, corr);

  const int mmgrid = (N + 127) / 128;
  const int agrid = (N + 7) / 8;   // 2 nodes/wave, 4 waves/block

  // hs0 = (x W1) * dinv  [fp16, stride 128]
  k_mm<float, 128, 128, 128, 0><<<mmgrid, 256, 0, stream>>>(x, W1, dinv, bufA, N);
  // h1 = relu(dinv*(gather+self) + b1)  [fp16, stride 128]
  k_agg<128, 0><<<agrid, 256, 0, stream>>>(bufA, offsets, col, dinv, b1, nullptr, bufB, N, 0);
  // g_scaled = (h1 Wc) * dinv, col100 = dinv seed  [fp16, stride 128]
  k_mm<h16, 128, 100, 128, 1><<<mmgrid, 256, 0, stream>>>(bufB, Wc, dinv, bufA, N);
  // three chained S applications (pre-scaled); s-chain in cols 100..102
  k_agg<104, 1><<<agrid, 256, 0, stream>>>(bufA, offsets, col, dinv, nullptr, nullptr, bufB, N, 101);
  k_agg<104, 1><<<agrid, 256, 0, stream>>>(bufB, offsets, col, dinv, nullptr, nullptr, bufA, N, 102);
  k_agg<104, 1><<<agrid, 256, 0, stream>>>(bufA, offsets, col, dinv, nullptr, nullptr, bufB, N, -1);
  // final S application + corrections -> d_out [fp32, N x 100]
  k_agg<100, 2><<<agrid, 256, 0, stream>>>(bufB, offsets, col, dinv, nullptr, corr, (float*)d_out, N, -1);
}

// Round 13
// 693.107 us; speedup vs baseline: 1.9420x; 1.0626x over previous
//
#include <hip/hip_runtime.h>

// ---------------------------------------------------------------------------
// GCN: 5x GCNConv + final linear.  N=100000, E=1.6M, D_IN=D_H=128, N_CLS=100.
//
// Collapsed algebra (R1-R3): h1 = relu(S x W1 + 1 b1^T),
//   out = S^4 h1 Wc + S^3 1 c2^T + S^2 1 c3^T + S 1 c4^T + 1 cb^T,
// weight chain fp32 on device.  s_k = S^k 1 ride as feature cols 100..102.
// Feature buffers fp16 row-major, stride 128 (256B aligned rows).
// Matmuls: MFMA f32_16x16x32_f16 (R13) — 4 waves x 32rows x 128cols/block,
// fp16 LDS tiles, W transposed in LDS for contiguous B-fragments.
// Aggregation: TWO nodes per wave (proven optimum: 1/w=110, 2/w=79, 4/w=88us);
// pinned at random-line L2-miss throughput (~3TB/s): R9 fewer bytes null,
// R11 more MLP null.  R6 column slicing REVERTED; R7 nt stores REVERTED.
// ---------------------------------------------------------------------------

typedef _Float16 h16;
typedef _Float16 __attribute__((ext_vector_type(4))) h16x4;
typedef _Float16 __attribute__((ext_vector_type(8))) h16x8;
typedef float __attribute__((ext_vector_type(4))) f32x4;

// ---- edge dtype detection: if input is int64, odd int32 slots (hi words) are 0
__global__ void k_detect(const int* __restrict__ edge, int* __restrict__ flag) {
  int t = threadIdx.x;
  if (edge[2 * t + 1] != 0) atomicOr(flag, 1);
}

static __device__ __forceinline__ int load_idx(const int* edge, const int* flag, size_t pos) {
  bool is64 = (*flag == 0);
  if (is64) return (int)((const long long*)edge)[pos];
  return edge[pos];
}

// count degrees, record per-edge rank within dst, emit compact dst stream
__global__ void k_count(const int* __restrict__ edge, const int* __restrict__ flag,
                        int* __restrict__ counts, int* __restrict__ rank,
                        int* __restrict__ dstc, int E) {
  int i = blockIdx.x * 256 + threadIdx.x;
  if (i >= E) return;
  int d = load_idx(edge, flag, (size_t)E + i);
  dstc[i] = d;
  rank[i] = atomicAdd(&counts[d], 1);
}

// ---- CSR build: chunk sums -> root scan -> per-chunk rescan ----
__global__ void k_chunksum(const int* __restrict__ counts, int* __restrict__ chunksums, int n) {
  __shared__ int sd[256];
  int t = threadIdx.x;
  int base = blockIdx.x * 1024 + t * 4;
  int s = 0;
#pragma unroll
  for (int j = 0; j < 4; ++j) { int i = base + j; if (i < n) s += counts[i]; }
  sd[t] = s; __syncthreads();
  for (int off = 128; off > 0; off >>= 1) {
    if (t < off) sd[t] += sd[t + off];
    __syncthreads();
  }
  if (t == 0) chunksums[blockIdx.x] = sd[0];
}

__global__ void k_root(const int* __restrict__ chunksums, int* __restrict__ chunkbase, int nchunks) {
  __shared__ int sc[128];
  int t = threadIdx.x;
  int v = (t < nchunks) ? chunksums[t] : 0;
  sc[t] = v; __syncthreads();
  for (int off = 1; off < 128; off <<= 1) {
    int x = (t >= off) ? sc[t - off] : 0;
    __syncthreads();
    sc[t] += x;
    __syncthreads();
  }
  if (t < nchunks) chunkbase[t] = sc[t] - v;
}

// scan + offsets + dinv (folded k_dinv)
__global__ void k_scan3(const int* __restrict__ counts, const int* __restrict__ chunkbase,
                        int* __restrict__ offsets, float* __restrict__ dinv, int n, int E) {
  __shared__ int sd[256];
  int t = threadIdx.x;
  int base = blockIdx.x * 1024 + t * 4;
  int c[4]; int s = 0;
#pragma unroll
  for (int j = 0; j < 4; ++j) { int i = base + j; c[j] = (i < n) ? counts[i] : 0; s += c[j]; }
  sd[t] = s; __syncthreads();
  int v = s;
  for (int off = 1; off < 256; off <<= 1) {
    int x = (t >= off) ? sd[t - off] : 0;
    __syncthreads();
    sd[t] += x;
    __syncthreads();
  }
  int run = chunkbase[blockIdx.x] + sd[t] - v;
#pragma unroll
  for (int j = 0; j < 4; ++j) {
    int i = base + j;
    if (i < n) {
      offsets[i] = run;
      dinv[i] = rsqrtf((float)c[j] + 1.0f);
    }
    run += c[j];
  }
  if (blockIdx.x == 0 && t == 0) offsets[n] = E;
}

// atomic-free fill: position = offsets[dst] + rank; src from edge, dst compact
__global__ void k_fill(const int* __restrict__ edge, const int* __restrict__ flag,
                       const int* __restrict__ offsets, const int* __restrict__ rank,
                       const int* __restrict__ dstc, int* __restrict__ col, int E) {
  int i = blockIdx.x * 256 + threadIdx.x;
  if (i >= E) return;
  int s = load_idx(edge, flag, (size_t)i);
  int d = dstc[i];
  col[offsets[d] + rank[i]] = s;
}

// ---- small fp32 matmul for the weight chain: C[MxNc] = A[MxK] B[KxNc] ----
__global__ void k_smm(const float* __restrict__ A, const float* __restrict__ B,
                      float* __restrict__ C, int M, int K, int Nc) {
  int idx = blockIdx.x * 256 + threadIdx.x;
  if (idx >= M * Nc) return;
  int i = idx / Nc, j = idx % Nc;
  float acc = 0.f;
  for (int k = 0; k < K; ++k) acc = fmaf(A[i * K + k], B[k * Nc + j], acc);
  C[idx] = acc;
}

__global__ void k_cvec(const float* __restrict__ b2, const float* __restrict__ b3,
                       const float* __restrict__ b4, const float* __restrict__ b5,
                       const float* __restrict__ bl, const float* __restrict__ Wl,
                       const float* __restrict__ R3, const float* __restrict__ R4,
                       const float* __restrict__ R5, float* __restrict__ corr) {
  int j = threadIdx.x;
  if (j >= 100) return;
  float a2 = 0.f, a3 = 0.f, a4 = 0.f, acb = 0.f;
  for (int k = 0; k < 128; ++k) {
    a2 = fmaf(b2[k], R3[k * 100 + j], a2);
    a3 = fmaf(b3[k], R4[k * 100 + j], a3);
    a4 = fmaf(b4[k], R5[k * 100 + j], a4);
  }
  for (int k = 0; k < 100; ++k) acb = fmaf(b5[k], Wl[k * 100 + j], acb);
  corr[j] = a2; corr[128 + j] = a3; corr[256 + j] = a4; corr[384 + j] = acb + bl[j];
}

// ---- MFMA matmul: out[r][c] = (X@W)[r][c]*dinv[r], fp16 out, stride OS=128.
// mfma_f32_16x16x32_f16.  Block = 256 thr = 4 waves; tile 128 rows x 128 cols;
// wave w owns rows w*32..w*32+31 (2 frag-rows x 8 frag-cols, 64 acc VGPR).
// LDS: Xs[128][40] fp16 (K-chunk 32 + pad), Wt[128][40] = W^T (B-frags are
// contiguous 16B ds_reads).  A/B k-order errors self-cancel (same bijection
// both sides); C/D mapping col=lane&15,row=(lane>>4)*4+reg (HW-verified).
// AUG: col 100 = dinv[r] (s-chain seed), cols in [M,128) except 100 -> 0.
template <typename TX, int M, int AUG>
__launch_bounds__(256)
__global__ void k_mm(const TX* __restrict__ X, const float* __restrict__ W,
                     const float* __restrict__ dinv, h16* __restrict__ out, int n) {
  const int K = 128, OS = 128;
  __shared__ h16 Xs[128 * 40];
  __shared__ h16 Wt[128 * 40];
  __shared__ float dv[128];
  int tid = threadIdx.x;
  int row0 = blockIdx.x * 128;
  int w = tid >> 6, lane = tid & 63;
  int lhi = lane >> 4, llo = lane & 15;

  if (tid < 128) dv[tid] = (row0 + tid < n) ? dinv[row0 + tid] : 0.f;

  f32x4 acc[2][8];
#pragma unroll
  for (int fr = 0; fr < 2; ++fr)
#pragma unroll
    for (int fc = 0; fc < 8; ++fc) {
      f32x4 z = {0.f, 0.f, 0.f, 0.f};
      acc[fr][fc] = z;
    }

  for (int kc = 0; kc < K; kc += 32) {
    __syncthreads();
    // stage X rows 0..127, cols kc..kc+31 -> Xs[r][k] fp16
    if (sizeof(TX) == 4) {
      for (int idx = tid * 4; idx < 128 * 32; idx += 1024) {
        int r = idx >> 5, c = idx & 31;
        f32x4 v = {0.f, 0.f, 0.f, 0.f};
        if (row0 + r < n)
          v = __builtin_nontemporal_load(
              (const f32x4*)&((const float*)X)[(size_t)(row0 + r) * K + kc + c]);
        h16x4 h = {(h16)v[0], (h16)v[1], (h16)v[2], (h16)v[3]};
        *(h16x4*)&Xs[r * 40 + c] = h;
      }
    } else {
      for (int idx = tid * 8; idx < 128 * 32; idx += 2048) {
        int r = idx >> 5, c = idx & 31;
        h16x8 v = {(h16)0.f, (h16)0.f, (h16)0.f, (h16)0.f,
                   (h16)0.f, (h16)0.f, (h16)0.f, (h16)0.f};
        if (row0 + r < n)
          v = __builtin_nontemporal_load(
              (const h16x8*)&((const h16*)X)[(size_t)(row0 + r) * K + kc + c]);
        *(h16x8*)&Xs[r * 40 + c] = v;
      }
    }
    // stage W^T: rows kc..kc+31 (k), cols 0..127 (nn) -> Wt[nn][k]
    for (int idx = tid * 4; idx < 32 * 128; idx += 1024) {
      int k = idx >> 7, nn = idx & 127;
      float4 v = make_float4(0.f, 0.f, 0.f, 0.f);
      if (nn < M) v = *(const float4*)&W[(size_t)(kc + k) * M + nn];
      Wt[(nn + 0) * 40 + k] = (h16)v.x;
      Wt[(nn + 1) * 40 + k] = (h16)v.y;
      Wt[(nn + 2) * 40 + k] = (h16)v.z;
      Wt[(nn + 3) * 40 + k] = (h16)v.w;
    }
    __syncthreads();

    // fragments: A = rows (w*32 + fr*16 + llo), k-slice lhi*8..+7
    h16x8 af0 = *(const h16x8*)&Xs[(w * 32 + llo) * 40 + lhi * 8];
    h16x8 af1 = *(const h16x8*)&Xs[(w * 32 + 16 + llo) * 40 + lhi * 8];
#pragma unroll
    for (int fc = 0; fc < 8; ++fc) {
      h16x8 bf = *(const h16x8*)&Wt[(fc * 16 + llo) * 40 + lhi * 8];
      acc[0][fc] = __builtin_amdgcn_mfma_f32_16x16x32_f16(af0, bf, acc[0][fc], 0, 0, 0);
      acc[1][fc] = __builtin_amdgcn_mfma_f32_16x16x32_f16(af1, bf, acc[1][fc], 0, 0, 0);
    }
  }

  // epilogue: D mapping col=lane&15, row=(lane>>4)*4+reg
#pragma unroll
  for (int fr = 0; fr < 2; ++fr) {
#pragma unroll
    for (int r = 0; r < 4; ++r) {
      int lrow = w * 32 + fr * 16 + lhi * 4 + r;
      int grow = row0 + lrow;
      if (grow >= n) continue;
      float sc = dv[lrow];
#pragma unroll
      for (int fc = 0; fc < 8; ++fc) {
        int colj = fc * 16 + llo;
        float vv = (colj < M) ? acc[fr][fc][r] * sc
                 : ((AUG && colj == 100) ? sc : 0.f);
        out[(size_t)grow * OS + colj] = (h16)vv;
      }
    }
  }
}

// ---- aggregation: TWO nodes per wave (proven optimum).  Each half-wave
// (32 lanes) owns one node; lane covers 4 cols (h16x4 = 8B -> 256B row).
// 16 edge-rows in flight per node.
// MODE 0: relu(dinv*(sum+self)+bias)  [width 128]
// MODE 1: dinv^2*(sum+self) (pre-scaled), fresh col seeded = dinv [width 104]
// MODE 2: final + rank-1 corrections -> fp32 out [n][100]  [width 100]
template <int WIDTH, int MODE>
__global__ void k_agg(const h16* __restrict__ hs, const int* __restrict__ offsets,
                      const int* __restrict__ col, const float* __restrict__ dinv,
                      const float* __restrict__ bias, const float* __restrict__ corr,
                      void* __restrict__ out, int n, int fresh) {
  const int STRIDE = 128;
  int gw = (blockIdx.x * 256 + threadIdx.x) >> 6;   // global wave id
  int lane = threadIdx.x & 63;
  int half = lane >> 5, sl = lane & 31;
  int v = gw * 2 + half;
  int c = sl * 4;
  if (v >= n) return;
  if (c >= WIDTH) return;
  const h16* row = &hs[(size_t)v * STRIDE];
  h16x4 selfv = *(const h16x4*)&row[c];
  float a0 = (float)selfv[0], a1 = (float)selfv[1];
  float a2 = (float)selfv[2], a3 = (float)selfv[3];
  int s = offsets[v], e = offsets[v + 1];
  for (int i = s; i < e; i += 16) {
    h16x4 m[16];
#pragma unroll
    for (int j = 0; j < 16; ++j) {
      h16x4 z = {(h16)0.f, (h16)0.f, (h16)0.f, (h16)0.f};
      m[j] = z;
      if (i + j < e) {
        int u = col[i + j];
        m[j] = *(const h16x4*)&hs[(size_t)u * STRIDE + c];
      }
    }
#pragma unroll
    for (int j = 0; j < 16; ++j) {
      a0 += (float)m[j][0]; a1 += (float)m[j][1];
      a2 += (float)m[j][2]; a3 += (float)m[j][3];
    }
  }
  float w = dinv[v];
  if (MODE == 0) {
    float r0 = fmaxf(fmaf(a0, w, bias[c]),     0.f);
    float r1 = fmaxf(fmaf(a1, w, bias[c + 1]), 0.f);
    float r2 = fmaxf(fmaf(a2, w, bias[c + 2]), 0.f);
    float r3 = fmaxf(fmaf(a3, w, bias[c + 3]), 0.f);
    h16x4 p = {(h16)r0, (h16)r1, (h16)r2, (h16)r3};
    *(h16x4*)&((h16*)out)[(size_t)v * STRIDE + c] = p;
  } else if (MODE == 1) {
    float w2 = w * w;
    float r0 = a0 * w2, r1 = a1 * w2, r2 = a2 * w2, r3 = a3 * w2;
    if (c == fresh) r0 = w;
    else if (c + 1 == fresh) r1 = w;
    else if (c + 2 == fresh) r2 = w;
    else if (c + 3 == fresh) r3 = w;
    h16x4 p = {(h16)r0, (h16)r1, (h16)r2, (h16)r3};
    *(h16x4*)&((h16*)out)[(size_t)v * STRIDE + c] = p;
  } else {
    float inv_w = 1.0f / w;
    float v3 = (float)row[100] * inv_w;
    float v2 = (float)row[101] * inv_w;
    float v1 = (float)row[102] * inv_w;
    float r[4] = {a0, a1, a2, a3};
    float4 o;
    float* op = &o.x;
#pragma unroll
    for (int q = 0; q < 4; ++q) {
      op[q] = r[q] * w + v3 * corr[c + q] + v2 * corr[128 + c + q]
            + v1 * corr[256 + c + q] + corr[384 + c + q];
    }
    *(float4*)&((float*)out)[(size_t)v * 100 + c] = o;
  }
}

// ---------------------------------------------------------------------------
extern "C" void kernel_launch(void* const* d_in, const int* in_sizes, int n_in,
                              void* d_out, int out_size, void* d_ws, size_t ws_size,
                              hipStream_t stream) {
  const float* x    = (const float*)d_in[0];
  const int*   edge = (const int*)d_in[1];
  const float* W1 = (const float*)d_in[2];  const float* b1 = (const float*)d_in[3];
  const float* W2 = (const float*)d_in[4];  const float* b2 = (const float*)d_in[5];
  const float* W3 = (const float*)d_in[6];  const float* b3 = (const float*)d_in[7];
  const float* W4 = (const float*)d_in[8];  const float* b4 = (const float*)d_in[9];
  const float* W5 = (const float*)d_in[10]; const float* b5 = (const float*)d_in[11];
  const float* Wl = (const float*)d_in[12]; const float* bl = (const float*)d_in[13];

  const int N = in_sizes[0] / 128;
  const int E = in_sizes[1] / 2;

  char* ws = (char*)d_ws;
  size_t cur = 0;
  auto alloc = [&](size_t bytes) -> char* {
    char* p = ws + cur;
    cur = (cur + bytes + 255) & ~(size_t)255;
    return p;
  };
  int*    counts    = (int*)alloc((size_t)N * 4);
  int*    flag      = (int*)alloc(4);
  int*    offsets   = (int*)alloc((size_t)(N + 1) * 4);
  float*  dinv      = (float*)alloc((size_t)N * 4);
  int*    chunksums = (int*)alloc(128 * 4);
  int*    chunkbase = (int*)alloc(128 * 4);
  float*  R5        = (float*)alloc(128 * 100 * 4);
  float*  R4        = (float*)alloc(128 * 100 * 4);
  float*  R3        = (float*)alloc(128 * 100 * 4);
  float*  Wc        = (float*)alloc(128 * 100 * 4);
  float*  corr      = (float*)alloc(512 * 4);
  int*    rank      = (int*)alloc((size_t)E * 4);
  int*    dstc      = (int*)alloc((size_t)E * 4);
  int*    col       = (int*)alloc(((size_t)E + 16) * 4);  // +pad for group reads
  h16*    bufA      = (h16*)alloc((size_t)N * 128 * 2);   // stride 128, 256B rows
  h16*    bufB      = (h16*)alloc((size_t)N * 128 * 2);
  (void)ws_size; (void)n_in; (void)out_size;

  hipMemsetAsync(counts, 0, (size_t)N * 4, stream);
  hipMemsetAsync(flag, 0, 4, stream);

  const int nchunks = (N + 1023) / 1024;
  const int egrid = (E + 255) / 256;

  k_detect<<<1, 256, 0, stream>>>(edge, flag);
  k_count<<<egrid, 256, 0, stream>>>(edge, flag, counts, rank, dstc, E);
  k_chunksum<<<nchunks, 256, 0, stream>>>(counts, chunksums, N);
  k_root<<<1, 128, 0, stream>>>(chunksums, chunkbase, nchunks);
  k_scan3<<<nchunks, 256, 0, stream>>>(counts, chunkbase, offsets, dinv, N, E);
  k_fill<<<egrid, 256, 0, stream>>>(edge, flag, offsets, rank, dstc, col, E);

  // weight chain (fp32): R5 = W5 Wl; R4 = W4 R5; R3 = W3 R4; Wc = W2 R3
  const int sgrid = (128 * 100 + 255) / 256;
  k_smm<<<sgrid, 256, 0, stream>>>(W5, Wl, R5, 128, 100, 100);
  k_smm<<<sgrid, 256, 0, stream>>>(W4, R5, R4, 128, 128, 100);
  k_smm<<<sgrid, 256, 0, stream>>>(W3, R4, R3, 128, 128, 100);
  k_smm<<<sgrid, 256, 0, stream>>>(W2, R3, Wc, 128, 128, 100);
  k_cvec<<<1, 128, 0, stream>>>(b2, b3, b4, b5, bl, Wl, R3, R4, R5, corr);

  const int mmgrid = (N + 127) / 128;
  const int agrid = (N + 7) / 8;   // 2 nodes/wave, 4 waves/block

  // hs0 = (x W1) * dinv  [fp16, stride 128]  (MFMA)
  k_mm<float, 128, 0><<<mmgrid, 256, 0, stream>>>(x, W1, dinv, bufA, N);
  // h1 = relu(dinv*(gather+self) + b1)  [fp16, stride 128]
  k_agg<128, 0><<<agrid, 256, 0, stream>>>(bufA, offsets, col, dinv, b1, nullptr, bufB, N, 0);
  // g_scaled = (h1 Wc) * dinv, col100 = dinv seed  [fp16, stride 128]  (MFMA)
  k_mm<h16, 100, 1><<<mmgrid, 256, 0, stream>>>(bufB, Wc, dinv, bufA, N);
  // three chained S applications (pre-scaled); s-chain in cols 100..102
  k_agg<104, 1><<<agrid, 256, 0, stream>>>(bufA, offsets, col, dinv, nullptr, nullptr, bufB, N, 101);
  k_agg<104, 1><<<agrid, 256, 0, stream>>>(bufB, offsets, col, dinv, nullptr, nullptr, bufA, N, 102);
  k_agg<104, 1><<<agrid, 256, 0, stream>>>(bufA, offsets, col, dinv, nullptr, nullptr, bufB, N, -1);
  // final S application + corrections -> d_out [fp32, N x 100]
  k_agg<100, 2><<<agrid, 256, 0, stream>>>(bufB, offsets, col, dinv, nullptr, corr, (float*)d_out, N, -1);
}

// Round 14
// 678.158 us; speedup vs baseline: 1.9848x; 1.0220x over previous
//
#include <hip/hip_runtime.h>

// ---------------------------------------------------------------------------
// GCN: 5x GCNConv + final linear.  N=100000, E=1.6M, D_IN=D_H=128, N_CLS=100.
//
// Collapsed algebra (R1-R3): h1 = relu(S x W1 + 1 b1^T),
//   out = S^4 h1 Wc + S^3 1 c2^T + S^2 1 c3^T + S 1 c4^T + 1 cb^T,
// weight chain fp32, fused into ONE single-block kernel (R14).
// s_k = S^k 1 ride as feature cols 100..102.
// Feature buffers fp16 row-major, stride 128 (256B aligned rows).
// Matmuls: MFMA f32_16x16x32_f16 (4 waves x 32rows x 128cols/block).
// Aggregation: TWO nodes per wave (proven optimum 1/w=110, 2/w=79, 4/w=88us),
// with col-index prefetch pipelining (R14).  Gather pinned at random-line
// L2-miss throughput ~2.45TB/s: R9 fewer bytes null, R11 more MLP null,
// R6 column slicing REVERTED, R7 nt stores REVERTED.
// ---------------------------------------------------------------------------

typedef _Float16 h16;
typedef _Float16 __attribute__((ext_vector_type(4))) h16x4;
typedef _Float16 __attribute__((ext_vector_type(8))) h16x8;
typedef float __attribute__((ext_vector_type(4))) f32x4;

static __device__ __forceinline__ int load_idx(const int* edge, const int* flag, size_t pos) {
  bool is64 = (*flag == 0);
  if (is64) return (int)((const long long*)edge)[pos];
  return edge[pos];
}

// ---- fused: edge-dtype detect + fp32 weight chain + bias corrections ------
// single block, 1024 threads.  R5=W5@Wl, R4=W4@R5, R3=W3@R4, Wc=W2@R3,
// corr = [R3^T b2, R4^T b3, R5^T b4, Wl^T b5 + bl].
__launch_bounds__(1024)
__global__ void k_wchain(const int* __restrict__ edge, int* __restrict__ flag,
                         const float* __restrict__ W2, const float* __restrict__ W3,
                         const float* __restrict__ W4, const float* __restrict__ W5,
                         const float* __restrict__ Wl,
                         const float* __restrict__ b2, const float* __restrict__ b3,
                         const float* __restrict__ b4, const float* __restrict__ b5,
                         const float* __restrict__ bl,
                         float* __restrict__ R5, float* __restrict__ R4,
                         float* __restrict__ R3, float* __restrict__ Wc,
                         float* __restrict__ corr) {
  __shared__ float Bs[128 * 100];   // 51.2 KB
  int tid = threadIdx.x;
  if (tid < 256 && edge[2 * tid + 1] != 0) atomicOr(flag, 1);
  for (int idx = tid; idx < 100 * 100; idx += 1024) Bs[idx] = Wl[idx];
  __syncthreads();
  // stage 0: R5 = W5 @ Wl  (K=100)
  for (int idx = tid; idx < 12800; idx += 1024) {
    int i = idx / 100, j = idx % 100;
    float acc = 0.f;
    for (int k = 0; k < 100; ++k) acc = fmaf(W5[i * 100 + k], Bs[k * 100 + j], acc);
    R5[idx] = acc;
  }
  __syncthreads();
  for (int idx = tid; idx < 12800; idx += 1024) Bs[idx] = R5[idx];
  __syncthreads();
  // stage 1: R4 = W4 @ R5  (K=128)
  for (int idx = tid; idx < 12800; idx += 1024) {
    int i = idx / 100, j = idx % 100;
    float acc = 0.f;
    for (int k = 0; k < 128; ++k) acc = fmaf(W4[i * 128 + k], Bs[k * 100 + j], acc);
    R4[idx] = acc;
  }
  __syncthreads();
  for (int idx = tid; idx < 12800; idx += 1024) Bs[idx] = R4[idx];
  __syncthreads();
  // stage 2: R3 = W3 @ R4  (K=128)
  for (int idx = tid; idx < 12800; idx += 1024) {
    int i = idx / 100, j = idx % 100;
    float acc = 0.f;
    for (int k = 0; k < 128; ++k) acc = fmaf(W3[i * 128 + k], Bs[k * 100 + j], acc);
    R3[idx] = acc;
  }
  __syncthreads();
  for (int idx = tid; idx < 12800; idx += 1024) Bs[idx] = R3[idx];
  __syncthreads();
  // stage 3: Wc = W2 @ R3  (K=128)
  for (int idx = tid; idx < 12800; idx += 1024) {
    int i = idx / 100, j = idx % 100;
    float acc = 0.f;
    for (int k = 0; k < 128; ++k) acc = fmaf(W2[i * 128 + k], Bs[k * 100 + j], acc);
    Wc[idx] = acc;
  }
  __syncthreads();
  // cvec (global R3/R4/R5 writes are block-visible after __syncthreads)
  if (tid < 100) {
    int j = tid;
    float a2 = 0.f, a3 = 0.f, a4 = 0.f, acb = 0.f;
    for (int k = 0; k < 128; ++k) {
      a2 = fmaf(b2[k], R3[k * 100 + j], a2);
      a3 = fmaf(b3[k], R4[k * 100 + j], a3);
      a4 = fmaf(b4[k], R5[k * 100 + j], a4);
    }
    for (int k = 0; k < 100; ++k) acb = fmaf(b5[k], Wl[k * 100 + j], acb);
    corr[j] = a2; corr[128 + j] = a3; corr[256 + j] = a4; corr[384 + j] = acb + bl[j];
  }
}

// count degrees, record per-edge rank within dst, emit compact dst stream
__global__ void k_count(const int* __restrict__ edge, const int* __restrict__ flag,
                        int* __restrict__ counts, int* __restrict__ rank,
                        int* __restrict__ dstc, int E) {
  int i = blockIdx.x * 256 + threadIdx.x;
  if (i >= E) return;
  int d = load_idx(edge, flag, (size_t)E + i);
  dstc[i] = d;
  rank[i] = atomicAdd(&counts[d], 1);
}

// ---- CSR build: chunk sums -> root scan -> per-chunk rescan ----
__global__ void k_chunksum(const int* __restrict__ counts, int* __restrict__ chunksums, int n) {
  __shared__ int sd[256];
  int t = threadIdx.x;
  int base = blockIdx.x * 1024 + t * 4;
  int s = 0;
#pragma unroll
  for (int j = 0; j < 4; ++j) { int i = base + j; if (i < n) s += counts[i]; }
  sd[t] = s; __syncthreads();
  for (int off = 128; off > 0; off >>= 1) {
    if (t < off) sd[t] += sd[t + off];
    __syncthreads();
  }
  if (t == 0) chunksums[blockIdx.x] = sd[0];
}

__global__ void k_root(const int* __restrict__ chunksums, int* __restrict__ chunkbase, int nchunks) {
  __shared__ int sc[128];
  int t = threadIdx.x;
  int v = (t < nchunks) ? chunksums[t] : 0;
  sc[t] = v; __syncthreads();
  for (int off = 1; off < 128; off <<= 1) {
    int x = (t >= off) ? sc[t - off] : 0;
    __syncthreads();
    sc[t] += x;
    __syncthreads();
  }
  if (t < nchunks) chunkbase[t] = sc[t] - v;
}

// scan + offsets + dinv
__global__ void k_scan3(const int* __restrict__ counts, const int* __restrict__ chunkbase,
                        int* __restrict__ offsets, float* __restrict__ dinv, int n, int E) {
  __shared__ int sd[256];
  int t = threadIdx.x;
  int base = blockIdx.x * 1024 + t * 4;
  int c[4]; int s = 0;
#pragma unroll
  for (int j = 0; j < 4; ++j) { int i = base + j; c[j] = (i < n) ? counts[i] : 0; s += c[j]; }
  sd[t] = s; __syncthreads();
  int v = s;
  for (int off = 1; off < 256; off <<= 1) {
    int x = (t >= off) ? sd[t - off] : 0;
    __syncthreads();
    sd[t] += x;
    __syncthreads();
  }
  int run = chunkbase[blockIdx.x] + sd[t] - v;
#pragma unroll
  for (int j = 0; j < 4; ++j) {
    int i = base + j;
    if (i < n) {
      offsets[i] = run;
      dinv[i] = rsqrtf((float)c[j] + 1.0f);
    }
    run += c[j];
  }
  if (blockIdx.x == 0 && t == 0) offsets[n] = E;
}

// atomic-free fill: position = offsets[dst] + rank
__global__ void k_fill(const int* __restrict__ edge, const int* __restrict__ flag,
                       const int* __restrict__ offsets, const int* __restrict__ rank,
                       const int* __restrict__ dstc, int* __restrict__ col, int E) {
  int i = blockIdx.x * 256 + threadIdx.x;
  if (i >= E) return;
  int s = load_idx(edge, flag, (size_t)i);
  int d = dstc[i];
  col[offsets[d] + rank[i]] = s;
}

// ---- MFMA matmul: out[r][c] = (X@W)[r][c]*dinv[r], fp16 out, stride OS=128.
template <typename TX, int M, int AUG>
__launch_bounds__(256)
__global__ void k_mm(const TX* __restrict__ X, const float* __restrict__ W,
                     const float* __restrict__ dinv, h16* __restrict__ out, int n) {
  const int K = 128, OS = 128;
  __shared__ h16 Xs[128 * 40];
  __shared__ h16 Wt[128 * 40];
  __shared__ float dv[128];
  int tid = threadIdx.x;
  int row0 = blockIdx.x * 128;
  int w = tid >> 6, lane = tid & 63;
  int lhi = lane >> 4, llo = lane & 15;

  if (tid < 128) dv[tid] = (row0 + tid < n) ? dinv[row0 + tid] : 0.f;

  f32x4 acc[2][8];
#pragma unroll
  for (int fr = 0; fr < 2; ++fr)
#pragma unroll
    for (int fc = 0; fc < 8; ++fc) {
      f32x4 z = {0.f, 0.f, 0.f, 0.f};
      acc[fr][fc] = z;
    }

  for (int kc = 0; kc < K; kc += 32) {
    __syncthreads();
    if (sizeof(TX) == 4) {
      for (int idx = tid * 4; idx < 128 * 32; idx += 1024) {
        int r = idx >> 5, c = idx & 31;
        f32x4 v = {0.f, 0.f, 0.f, 0.f};
        if (row0 + r < n)
          v = __builtin_nontemporal_load(
              (const f32x4*)&((const float*)X)[(size_t)(row0 + r) * K + kc + c]);
        h16x4 h = {(h16)v[0], (h16)v[1], (h16)v[2], (h16)v[3]};
        *(h16x4*)&Xs[r * 40 + c] = h;
      }
    } else {
      for (int idx = tid * 8; idx < 128 * 32; idx += 2048) {
        int r = idx >> 5, c = idx & 31;
        h16x8 v = {(h16)0.f, (h16)0.f, (h16)0.f, (h16)0.f,
                   (h16)0.f, (h16)0.f, (h16)0.f, (h16)0.f};
        if (row0 + r < n)
          v = __builtin_nontemporal_load(
              (const h16x8*)&((const h16*)X)[(size_t)(row0 + r) * K + kc + c]);
        *(h16x8*)&Xs[r * 40 + c] = v;
      }
    }
    for (int idx = tid * 4; idx < 32 * 128; idx += 1024) {
      int k = idx >> 7, nn = idx & 127;
      float4 v = make_float4(0.f, 0.f, 0.f, 0.f);
      if (nn < M) v = *(const float4*)&W[(size_t)(kc + k) * M + nn];
      Wt[(nn + 0) * 40 + k] = (h16)v.x;
      Wt[(nn + 1) * 40 + k] = (h16)v.y;
      Wt[(nn + 2) * 40 + k] = (h16)v.z;
      Wt[(nn + 3) * 40 + k] = (h16)v.w;
    }
    __syncthreads();

    h16x8 af0 = *(const h16x8*)&Xs[(w * 32 + llo) * 40 + lhi * 8];
    h16x8 af1 = *(const h16x8*)&Xs[(w * 32 + 16 + llo) * 40 + lhi * 8];
#pragma unroll
    for (int fc = 0; fc < 8; ++fc) {
      h16x8 bf = *(const h16x8*)&Wt[(fc * 16 + llo) * 40 + lhi * 8];
      acc[0][fc] = __builtin_amdgcn_mfma_f32_16x16x32_f16(af0, bf, acc[0][fc], 0, 0, 0);
      acc[1][fc] = __builtin_amdgcn_mfma_f32_16x16x32_f16(af1, bf, acc[1][fc], 0, 0, 0);
    }
  }

#pragma unroll
  for (int fr = 0; fr < 2; ++fr) {
#pragma unroll
    for (int r = 0; r < 4; ++r) {
      int lrow = w * 32 + fr * 16 + lhi * 4 + r;
      int grow = row0 + lrow;
      if (grow >= n) continue;
      float sc = dv[lrow];
#pragma unroll
      for (int fc = 0; fc < 8; ++fc) {
        int colj = fc * 16 + llo;
        float vv = (colj < M) ? acc[fr][fc][r] * sc
                 : ((AUG && colj == 100) ? sc : 0.f);
        out[(size_t)grow * OS + colj] = (h16)vv;
      }
    }
  }
}

// ---- aggregation: TWO nodes per wave, col-prefetch pipelined (R14).
// MODE 0: relu(dinv*(sum+self)+bias)  [width 128]
// MODE 1: dinv^2*(sum+self) (pre-scaled), fresh col seeded = dinv [width 104]
// MODE 2: final + rank-1 corrections -> fp32 out [n][100]  [width 100]
template <int WIDTH, int MODE>
__global__ void k_agg(const h16* __restrict__ hs, const int* __restrict__ offsets,
                      const int* __restrict__ col, const float* __restrict__ dinv,
                      const float* __restrict__ bias, const float* __restrict__ corr,
                      void* __restrict__ out, int n, int fresh) {
  const int STRIDE = 128;
  int gw = (blockIdx.x * 256 + threadIdx.x) >> 6;   // global wave id
  int lane = threadIdx.x & 63;
  int half = lane >> 5, sl = lane & 31;
  int v = gw * 2 + half;
  int c = sl * 4;
  if (v >= n) return;
  if (c >= WIDTH) return;
  const h16* row = &hs[(size_t)v * STRIDE];
  h16x4 selfv = *(const h16x4*)&row[c];
  float a0 = (float)selfv[0], a1 = (float)selfv[1];
  float a2 = (float)selfv[2], a3 = (float)selfv[3];
  int s = offsets[v], e = offsets[v + 1];
  int cc[16];
#pragma unroll
  for (int j = 0; j < 16; ++j) cc[j] = (s + j < e) ? col[s + j] : -1;
  for (int i = s; i < e; i += 16) {
    int cn[16];
#pragma unroll
    for (int j = 0; j < 16; ++j) {
      int idx = i + 16 + j;
      cn[j] = (idx < e) ? col[idx] : -1;     // prefetch next group's indices
    }
    h16x4 m[16];
#pragma unroll
    for (int j = 0; j < 16; ++j) {
      h16x4 z = {(h16)0.f, (h16)0.f, (h16)0.f, (h16)0.f};
      m[j] = z;
      if (cc[j] >= 0)
        m[j] = *(const h16x4*)&hs[(size_t)cc[j] * STRIDE + c];
    }
#pragma unroll
    for (int j = 0; j < 16; ++j) {
      a0 += (float)m[j][0]; a1 += (float)m[j][1];
      a2 += (float)m[j][2]; a3 += (float)m[j][3];
    }
#pragma unroll
    for (int j = 0; j < 16; ++j) cc[j] = cn[j];
  }
  float w = dinv[v];
  if (MODE == 0) {
    float r0 = fmaxf(fmaf(a0, w, bias[c]),     0.f);
    float r1 = fmaxf(fmaf(a1, w, bias[c + 1]), 0.f);
    float r2 = fmaxf(fmaf(a2, w, bias[c + 2]), 0.f);
    float r3 = fmaxf(fmaf(a3, w, bias[c + 3]), 0.f);
    h16x4 p = {(h16)r0, (h16)r1, (h16)r2, (h16)r3};
    *(h16x4*)&((h16*)out)[(size_t)v * STRIDE + c] = p;
  } else if (MODE == 1) {
    float w2 = w * w;
    float r0 = a0 * w2, r1 = a1 * w2, r2 = a2 * w2, r3 = a3 * w2;
    if (c == fresh) r0 = w;
    else if (c + 1 == fresh) r1 = w;
    else if (c + 2 == fresh) r2 = w;
    else if (c + 3 == fresh) r3 = w;
    h16x4 p = {(h16)r0, (h16)r1, (h16)r2, (h16)r3};
    *(h16x4*)&((h16*)out)[(size_t)v * STRIDE + c] = p;
  } else {
    float inv_w = 1.0f / w;
    float v3 = (float)row[100] * inv_w;
    float v2 = (float)row[101] * inv_w;
    float v1 = (float)row[102] * inv_w;
    float r[4] = {a0, a1, a2, a3};
    float4 o;
    float* op = &o.x;
#pragma unroll
    for (int q = 0; q < 4; ++q) {
      op[q] = r[q] * w + v3 * corr[c + q] + v2 * corr[128 + c + q]
            + v1 * corr[256 + c + q] + corr[384 + c + q];
    }
    *(float4*)&((float*)out)[(size_t)v * 100 + c] = o;
  }
}

// ---------------------------------------------------------------------------
extern "C" void kernel_launch(void* const* d_in, const int* in_sizes, int n_in,
                              void* d_out, int out_size, void* d_ws, size_t ws_size,
                              hipStream_t stream) {
  const float* x    = (const float*)d_in[0];
  const int*   edge = (const int*)d_in[1];
  const float* W1 = (const float*)d_in[2];  const float* b1 = (const float*)d_in[3];
  const float* W2 = (const float*)d_in[4];  const float* b2 = (const float*)d_in[5];
  const float* W3 = (const float*)d_in[6];  const float* b3 = (const float*)d_in[7];
  const float* W4 = (const float*)d_in[8];  const float* b4 = (const float*)d_in[9];
  const float* W5 = (const float*)d_in[10]; const float* b5 = (const float*)d_in[11];
  const float* Wl = (const float*)d_in[12]; const float* bl = (const float*)d_in[13];

  const int N = in_sizes[0] / 128;
  const int E = in_sizes[1] / 2;

  char* ws = (char*)d_ws;
  size_t cur = 0;
  auto alloc = [&](size_t bytes) -> char* {
    char* p = ws + cur;
    cur = (cur + bytes + 255) & ~(size_t)255;
    return p;
  };
  int*    counts    = (int*)alloc((size_t)N * 4);
  int*    flag      = (int*)alloc(4);
  int*    offsets   = (int*)alloc((size_t)(N + 1) * 4);
  float*  dinv      = (float*)alloc((size_t)N * 4);
  int*    chunksums = (int*)alloc(128 * 4);
  int*    chunkbase = (int*)alloc(128 * 4);
  float*  R5        = (float*)alloc(128 * 100 * 4);
  float*  R4        = (float*)alloc(128 * 100 * 4);
  float*  R3        = (float*)alloc(128 * 100 * 4);
  float*  Wc        = (float*)alloc(128 * 100 * 4);
  float*  corr      = (float*)alloc(512 * 4);
  int*    rank      = (int*)alloc((size_t)E * 4);
  int*    dstc      = (int*)alloc((size_t)E * 4);
  int*    col       = (int*)alloc(((size_t)E + 32) * 4);  // +pad for group reads
  h16*    bufA      = (h16*)alloc((size_t)N * 128 * 2);   // stride 128, 256B rows
  h16*    bufB      = (h16*)alloc((size_t)N * 128 * 2);
  (void)ws_size; (void)n_in; (void)out_size;

  hipMemsetAsync(counts, 0, (size_t)N * 4, stream);
  hipMemsetAsync(flag, 0, 4, stream);

  const int nchunks = (N + 1023) / 1024;
  const int egrid = (E + 255) / 256;

  // fused detect + weight chain + corrections (one single-block kernel)
  k_wchain<<<1, 1024, 0, stream>>>(edge, flag, W2, W3, W4, W5, Wl,
                                   b2, b3, b4, b5, bl, R5, R4, R3, Wc, corr);
  k_count<<<egrid, 256, 0, stream>>>(edge, flag, counts, rank, dstc, E);
  k_chunksum<<<nchunks, 256, 0, stream>>>(counts, chunksums, N);
  k_root<<<1, 128, 0, stream>>>(chunksums, chunkbase, nchunks);
  k_scan3<<<nchunks, 256, 0, stream>>>(counts, chunkbase, offsets, dinv, N, E);
  k_fill<<<egrid, 256, 0, stream>>>(edge, flag, offsets, rank, dstc, col, E);

  const int mmgrid = (N + 127) / 128;
  const int agrid = (N + 7) / 8;   // 2 nodes/wave, 4 waves/block

  // hs0 = (x W1) * dinv  [fp16, stride 128]  (MFMA)
  k_mm<float, 128, 0><<<mmgrid, 256, 0, stream>>>(x, W1, dinv, bufA, N);
  // h1 = relu(dinv*(gather+self) + b1)  [fp16, stride 128]
  k_agg<128, 0><<<agrid, 256, 0, stream>>>(bufA, offsets, col, dinv, b1, nullptr, bufB, N, 0);
  // g_scaled = (h1 Wc) * dinv, col100 = dinv seed  [fp16, stride 128]  (MFMA)
  k_mm<h16, 100, 1><<<mmgrid, 256, 0, stream>>>(bufB, Wc, dinv, bufA, N);
  // three chained S applications (pre-scaled); s-chain in cols 100..102
  k_agg<104, 1><<<agrid, 256, 0, stream>>>(bufA, offsets, col, dinv, nullptr, nullptr, bufB, N, 101);
  k_agg<104, 1><<<agrid, 256, 0, stream>>>(bufB, offsets, col, dinv, nullptr, nullptr, bufA, N, 102);
  k_agg<104, 1><<<agrid, 256, 0, stream>>>(bufA, offsets, col, dinv, nullptr, nullptr, bufB, N, -1);
  // final S application + corrections -> d_out [fp32, N x 100]
  k_agg<100, 2><<<agrid, 256, 0, stream>>>(bufB, offsets, col, dinv, nullptr, corr, (float*)d_out, N, -1);
}

// Round 15
// 625.186 us; speedup vs baseline: 2.1529x; 1.0847x over previous
//
#include <hip/hip_runtime.h>

// ---------------------------------------------------------------------------
// GCN: 5x GCNConv + final linear.  N=100000, E=1.6M, D_IN=D_H=128, N_CLS=100.
//
// Collapsed algebra (R1-R3): h1 = relu(S x W1 + 1 b1^T),
//   out = S^4 h1 Wc + S^3 1 c2^T + S^2 1 c3^T + S 1 c4^T + 1 cb^T,
// weight chain fp32, SEPARATE small kernels (R14's single-block fusion was
// 220us of idle GPU — one block serializes the chip; REVERTED).
// s_k = S^k 1 ride as feature cols 100..102.
// Feature buffers fp16 row-major, stride 128 (256B aligned rows).
// Matmuls: MFMA f32_16x16x32_f16 (4 waves x 32rows x 128cols/block).
// Aggregation: TWO nodes per wave + col-index prefetch (R14, kept — aggs
// 79 -> ~67us).  Gather pinned at random-line L2-miss throughput: R9 fewer
// bytes null, R11 more MLP null, R6 column slicing REVERTED, R7 nt stores
// REVERTED.
// ---------------------------------------------------------------------------

typedef _Float16 h16;
typedef _Float16 __attribute__((ext_vector_type(4))) h16x4;
typedef _Float16 __attribute__((ext_vector_type(8))) h16x8;
typedef float __attribute__((ext_vector_type(4))) f32x4;

static __device__ __forceinline__ int load_idx(const int* edge, const int* flag, size_t pos) {
  bool is64 = (*flag == 0);
  if (is64) return (int)((const long long*)edge)[pos];
  return edge[pos];
}

// ---- edge dtype detection: if input is int64, odd int32 slots (hi words) are 0
__global__ void k_detect(const int* __restrict__ edge, int* __restrict__ flag) {
  int t = threadIdx.x;
  if (edge[2 * t + 1] != 0) atomicOr(flag, 1);
}

// count degrees, record per-edge rank within dst, emit compact dst stream
__global__ void k_count(const int* __restrict__ edge, const int* __restrict__ flag,
                        int* __restrict__ counts, int* __restrict__ rank,
                        int* __restrict__ dstc, int E) {
  int i = blockIdx.x * 256 + threadIdx.x;
  if (i >= E) return;
  int d = load_idx(edge, flag, (size_t)E + i);
  dstc[i] = d;
  rank[i] = atomicAdd(&counts[d], 1);
}

// ---- CSR build: chunk sums -> root scan -> per-chunk rescan ----
__global__ void k_chunksum(const int* __restrict__ counts, int* __restrict__ chunksums, int n) {
  __shared__ int sd[256];
  int t = threadIdx.x;
  int base = blockIdx.x * 1024 + t * 4;
  int s = 0;
#pragma unroll
  for (int j = 0; j < 4; ++j) { int i = base + j; if (i < n) s += counts[i]; }
  sd[t] = s; __syncthreads();
  for (int off = 128; off > 0; off >>= 1) {
    if (t < off) sd[t] += sd[t + off];
    __syncthreads();
  }
  if (t == 0) chunksums[blockIdx.x] = sd[0];
}

__global__ void k_root(const int* __restrict__ chunksums, int* __restrict__ chunkbase, int nchunks) {
  __shared__ int sc[128];
  int t = threadIdx.x;
  int v = (t < nchunks) ? chunksums[t] : 0;
  sc[t] = v; __syncthreads();
  for (int off = 1; off < 128; off <<= 1) {
    int x = (t >= off) ? sc[t - off] : 0;
    __syncthreads();
    sc[t] += x;
    __syncthreads();
  }
  if (t < nchunks) chunkbase[t] = sc[t] - v;
}

// scan + offsets + dinv
__global__ void k_scan3(const int* __restrict__ counts, const int* __restrict__ chunkbase,
                        int* __restrict__ offsets, float* __restrict__ dinv, int n, int E) {
  __shared__ int sd[256];
  int t = threadIdx.x;
  int base = blockIdx.x * 1024 + t * 4;
  int c[4]; int s = 0;
#pragma unroll
  for (int j = 0; j < 4; ++j) { int i = base + j; c[j] = (i < n) ? counts[i] : 0; s += c[j]; }
  sd[t] = s; __syncthreads();
  int v = s;
  for (int off = 1; off < 256; off <<= 1) {
    int x = (t >= off) ? sd[t - off] : 0;
    __syncthreads();
    sd[t] += x;
    __syncthreads();
  }
  int run = chunkbase[blockIdx.x] + sd[t] - v;
#pragma unroll
  for (int j = 0; j < 4; ++j) {
    int i = base + j;
    if (i < n) {
      offsets[i] = run;
      dinv[i] = rsqrtf((float)c[j] + 1.0f);
    }
    run += c[j];
  }
  if (blockIdx.x == 0 && t == 0) offsets[n] = E;
}

// atomic-free fill: position = offsets[dst] + rank
__global__ void k_fill(const int* __restrict__ edge, const int* __restrict__ flag,
                       const int* __restrict__ offsets, const int* __restrict__ rank,
                       const int* __restrict__ dstc, int* __restrict__ col, int E) {
  int i = blockIdx.x * 256 + threadIdx.x;
  if (i >= E) return;
  int s = load_idx(edge, flag, (size_t)i);
  int d = dstc[i];
  col[offsets[d] + rank[i]] = s;
}

// ---- small fp32 matmul for the weight chain: C[MxNc] = A[MxK] B[KxNc] ----
__global__ void k_smm(const float* __restrict__ A, const float* __restrict__ B,
                      float* __restrict__ C, int M, int K, int Nc) {
  int idx = blockIdx.x * 256 + threadIdx.x;
  if (idx >= M * Nc) return;
  int i = idx / Nc, j = idx % Nc;
  float acc = 0.f;
  for (int k = 0; k < K; ++k) acc = fmaf(A[i * K + k], B[k * Nc + j], acc);
  C[idx] = acc;
}

__global__ void k_cvec(const float* __restrict__ b2, const float* __restrict__ b3,
                       const float* __restrict__ b4, const float* __restrict__ b5,
                       const float* __restrict__ bl, const float* __restrict__ Wl,
                       const float* __restrict__ R3, const float* __restrict__ R4,
                       const float* __restrict__ R5, float* __restrict__ corr) {
  int j = threadIdx.x;
  if (j >= 100) return;
  float a2 = 0.f, a3 = 0.f, a4 = 0.f, acb = 0.f;
  for (int k = 0; k < 128; ++k) {
    a2 = fmaf(b2[k], R3[k * 100 + j], a2);
    a3 = fmaf(b3[k], R4[k * 100 + j], a3);
    a4 = fmaf(b4[k], R5[k * 100 + j], a4);
  }
  for (int k = 0; k < 100; ++k) acb = fmaf(b5[k], Wl[k * 100 + j], acb);
  corr[j] = a2; corr[128 + j] = a3; corr[256 + j] = a4; corr[384 + j] = acb + bl[j];
}

// ---- MFMA matmul: out[r][c] = (X@W)[r][c]*dinv[r], fp16 out, stride OS=128.
template <typename TX, int M, int AUG>
__launch_bounds__(256)
__global__ void k_mm(const TX* __restrict__ X, const float* __restrict__ W,
                     const float* __restrict__ dinv, h16* __restrict__ out, int n) {
  const int K = 128, OS = 128;
  __shared__ h16 Xs[128 * 40];
  __shared__ h16 Wt[128 * 40];
  __shared__ float dv[128];
  int tid = threadIdx.x;
  int row0 = blockIdx.x * 128;
  int w = tid >> 6, lane = tid & 63;
  int lhi = lane >> 4, llo = lane & 15;

  if (tid < 128) dv[tid] = (row0 + tid < n) ? dinv[row0 + tid] : 0.f;

  f32x4 acc[2][8];
#pragma unroll
  for (int fr = 0; fr < 2; ++fr)
#pragma unroll
    for (int fc = 0; fc < 8; ++fc) {
      f32x4 z = {0.f, 0.f, 0.f, 0.f};
      acc[fr][fc] = z;
    }

  for (int kc = 0; kc < K; kc += 32) {
    __syncthreads();
    if (sizeof(TX) == 4) {
      for (int idx = tid * 4; idx < 128 * 32; idx += 1024) {
        int r = idx >> 5, c = idx & 31;
        f32x4 v = {0.f, 0.f, 0.f, 0.f};
        if (row0 + r < n)
          v = __builtin_nontemporal_load(
              (const f32x4*)&((const float*)X)[(size_t)(row0 + r) * K + kc + c]);
        h16x4 h = {(h16)v[0], (h16)v[1], (h16)v[2], (h16)v[3]};
        *(h16x4*)&Xs[r * 40 + c] = h;
      }
    } else {
      for (int idx = tid * 8; idx < 128 * 32; idx += 2048) {
        int r = idx >> 5, c = idx & 31;
        h16x8 v = {(h16)0.f, (h16)0.f, (h16)0.f, (h16)0.f,
                   (h16)0.f, (h16)0.f, (h16)0.f, (h16)0.f};
        if (row0 + r < n)
          v = __builtin_nontemporal_load(
              (const h16x8*)&((const h16*)X)[(size_t)(row0 + r) * K + kc + c]);
        *(h16x8*)&Xs[r * 40 + c] = v;
      }
    }
    for (int idx = tid * 4; idx < 32 * 128; idx += 1024) {
      int k = idx >> 7, nn = idx & 127;
      float4 v = make_float4(0.f, 0.f, 0.f, 0.f);
      if (nn < M) v = *(const float4*)&W[(size_t)(kc + k) * M + nn];
      Wt[(nn + 0) * 40 + k] = (h16)v.x;
      Wt[(nn + 1) * 40 + k] = (h16)v.y;
      Wt[(nn + 2) * 40 + k] = (h16)v.z;
      Wt[(nn + 3) * 40 + k] = (h16)v.w;
    }
    __syncthreads();

    h16x8 af0 = *(const h16x8*)&Xs[(w * 32 + llo) * 40 + lhi * 8];
    h16x8 af1 = *(const h16x8*)&Xs[(w * 32 + 16 + llo) * 40 + lhi * 8];
#pragma unroll
    for (int fc = 0; fc < 8; ++fc) {
      h16x8 bf = *(const h16x8*)&Wt[(fc * 16 + llo) * 40 + lhi * 8];
      acc[0][fc] = __builtin_amdgcn_mfma_f32_16x16x32_f16(af0, bf, acc[0][fc], 0, 0, 0);
      acc[1][fc] = __builtin_amdgcn_mfma_f32_16x16x32_f16(af1, bf, acc[1][fc], 0, 0, 0);
    }
  }

#pragma unroll
  for (int fr = 0; fr < 2; ++fr) {
#pragma unroll
    for (int r = 0; r < 4; ++r) {
      int lrow = w * 32 + fr * 16 + lhi * 4 + r;
      int grow = row0 + lrow;
      if (grow >= n) continue;
      float sc = dv[lrow];
#pragma unroll
      for (int fc = 0; fc < 8; ++fc) {
        int colj = fc * 16 + llo;
        float vv = (colj < M) ? acc[fr][fc][r] * sc
                 : ((AUG && colj == 100) ? sc : 0.f);
        out[(size_t)grow * OS + colj] = (h16)vv;
      }
    }
  }
}

// ---- aggregation: TWO nodes per wave, col-prefetch pipelined.
// MODE 0: relu(dinv*(sum+self)+bias)  [width 128]
// MODE 1: dinv^2*(sum+self) (pre-scaled), fresh col seeded = dinv [width 104]
// MODE 2: final + rank-1 corrections -> fp32 out [n][100]  [width 100]
template <int WIDTH, int MODE>
__global__ void k_agg(const h16* __restrict__ hs, const int* __restrict__ offsets,
                      const int* __restrict__ col, const float* __restrict__ dinv,
                      const float* __restrict__ bias, const float* __restrict__ corr,
                      void* __restrict__ out, int n, int fresh) {
  const int STRIDE = 128;
  int gw = (blockIdx.x * 256 + threadIdx.x) >> 6;   // global wave id
  int lane = threadIdx.x & 63;
  int half = lane >> 5, sl = lane & 31;
  int v = gw * 2 + half;
  int c = sl * 4;
  if (v >= n) return;
  if (c >= WIDTH) return;
  const h16* row = &hs[(size_t)v * STRIDE];
  h16x4 selfv = *(const h16x4*)&row[c];
  float a0 = (float)selfv[0], a1 = (float)selfv[1];
  float a2 = (float)selfv[2], a3 = (float)selfv[3];
  int s = offsets[v], e = offsets[v + 1];
  int cc[16];
#pragma unroll
  for (int j = 0; j < 16; ++j) cc[j] = (s + j < e) ? col[s + j] : -1;
  for (int i = s; i < e; i += 16) {
    int cn[16];
#pragma unroll
    for (int j = 0; j < 16; ++j) {
      int idx = i + 16 + j;
      cn[j] = (idx < e) ? col[idx] : -1;     // prefetch next group's indices
    }
    h16x4 m[16];
#pragma unroll
    for (int j = 0; j < 16; ++j) {
      h16x4 z = {(h16)0.f, (h16)0.f, (h16)0.f, (h16)0.f};
      m[j] = z;
      if (cc[j] >= 0)
        m[j] = *(const h16x4*)&hs[(size_t)cc[j] * STRIDE + c];
    }
#pragma unroll
    for (int j = 0; j < 16; ++j) {
      a0 += (float)m[j][0]; a1 += (float)m[j][1];
      a2 += (float)m[j][2]; a3 += (float)m[j][3];
    }
#pragma unroll
    for (int j = 0; j < 16; ++j) cc[j] = cn[j];
  }
  float w = dinv[v];
  if (MODE == 0) {
    float r0 = fmaxf(fmaf(a0, w, bias[c]),     0.f);
    float r1 = fmaxf(fmaf(a1, w, bias[c + 1]), 0.f);
    float r2 = fmaxf(fmaf(a2, w, bias[c + 2]), 0.f);
    float r3 = fmaxf(fmaf(a3, w, bias[c + 3]), 0.f);
    h16x4 p = {(h16)r0, (h16)r1, (h16)r2, (h16)r3};
    *(h16x4*)&((h16*)out)[(size_t)v * STRIDE + c] = p;
  } else if (MODE == 1) {
    float w2 = w * w;
    float r0 = a0 * w2, r1 = a1 * w2, r2 = a2 * w2, r3 = a3 * w2;
    if (c == fresh) r0 = w;
    else if (c + 1 == fresh) r1 = w;
    else if (c + 2 == fresh) r2 = w;
    else if (c + 3 == fresh) r3 = w;
    h16x4 p = {(h16)r0, (h16)r1, (h16)r2, (h16)r3};
    *(h16x4*)&((h16*)out)[(size_t)v * STRIDE + c] = p;
  } else {
    float inv_w = 1.0f / w;
    float v3 = (float)row[100] * inv_w;
    float v2 = (float)row[101] * inv_w;
    float v1 = (float)row[102] * inv_w;
    float r[4] = {a0, a1, a2, a3};
    float4 o;
    float* op = &o.x;
#pragma unroll
    for (int q = 0; q < 4; ++q) {
      op[q] = r[q] * w + v3 * corr[c + q] + v2 * corr[128 + c + q]
            + v1 * corr[256 + c + q] + corr[384 + c + q];
    }
    *(float4*)&((float*)out)[(size_t)v * 100 + c] = o;
  }
}

// ---------------------------------------------------------------------------
extern "C" void kernel_launch(void* const* d_in, const int* in_sizes, int n_in,
                              void* d_out, int out_size, void* d_ws, size_t ws_size,
                              hipStream_t stream) {
  const float* x    = (const float*)d_in[0];
  const int*   edge = (const int*)d_in[1];
  const float* W1 = (const float*)d_in[2];  const float* b1 = (const float*)d_in[3];
  const float* W2 = (const float*)d_in[4];  const float* b2 = (const float*)d_in[5];
  const float* W3 = (const float*)d_in[6];  const float* b3 = (const float*)d_in[7];
  const float* W4 = (const float*)d_in[8];  const float* b4 = (const float*)d_in[9];
  const float* W5 = (const float*)d_in[10]; const float* b5 = (const float*)d_in[11];
  const float* Wl = (const float*)d_in[12]; const float* bl = (const float*)d_in[13];

  const int N = in_sizes[0] / 128;
  const int E = in_sizes[1] / 2;

  char* ws = (char*)d_ws;
  size_t cur = 0;
  auto alloc = [&](size_t bytes) -> char* {
    char* p = ws + cur;
    cur = (cur + bytes + 255) & ~(size_t)255;
    return p;
  };
  int*    counts    = (int*)alloc((size_t)N * 4);
  int*    flag      = (int*)alloc(4);
  int*    offsets   = (int*)alloc((size_t)(N + 1) * 4);
  float*  dinv      = (float*)alloc((size_t)N * 4);
  int*    chunksums = (int*)alloc(128 * 4);
  int*    chunkbase = (int*)alloc(128 * 4);
  float*  R5        = (float*)alloc(128 * 100 * 4);
  float*  R4        = (float*)alloc(128 * 100 * 4);
  float*  R3        = (float*)alloc(128 * 100 * 4);
  float*  Wc        = (float*)alloc(128 * 100 * 4);
  float*  corr      = (float*)alloc(512 * 4);
  int*    rank      = (int*)alloc((size_t)E * 4);
  int*    dstc      = (int*)alloc((size_t)E * 4);
  int*    col       = (int*)alloc(((size_t)E + 32) * 4);  // +pad for group reads
  h16*    bufA      = (h16*)alloc((size_t)N * 128 * 2);   // stride 128, 256B rows
  h16*    bufB      = (h16*)alloc((size_t)N * 128 * 2);
  (void)ws_size; (void)n_in; (void)out_size;

  hipMemsetAsync(counts, 0, (size_t)N * 4, stream);
  hipMemsetAsync(flag, 0, 4, stream);

  const int nchunks = (N + 1023) / 1024;
  const int egrid = (E + 255) / 256;

  k_detect<<<1, 256, 0, stream>>>(edge, flag);
  k_count<<<egrid, 256, 0, stream>>>(edge, flag, counts, rank, dstc, E);
  k_chunksum<<<nchunks, 256, 0, stream>>>(counts, chunksums, N);
  k_root<<<1, 128, 0, stream>>>(chunksums, chunkbase, nchunks);
  k_scan3<<<nchunks, 256, 0, stream>>>(counts, chunkbase, offsets, dinv, N, E);
  k_fill<<<egrid, 256, 0, stream>>>(edge, flag, offsets, rank, dstc, col, E);

  // weight chain (fp32, separate small kernels): R5=W5@Wl; R4=W4@R5;
  // R3=W3@R4; Wc=W2@R3; corr vectors.
  const int sgrid = (128 * 100 + 255) / 256;
  k_smm<<<sgrid, 256, 0, stream>>>(W5, Wl, R5, 128, 100, 100);
  k_smm<<<sgrid, 256, 0, stream>>>(W4, R5, R4, 128, 128, 100);
  k_smm<<<sgrid, 256, 0, stream>>>(W3, R4, R3, 128, 128, 100);
  k_smm<<<sgrid, 256, 0, stream>>>(W2, R3, Wc, 128, 128, 100);
  k_cvec<<<1, 128, 0, stream>>>(b2, b3, b4, b5, bl, Wl, R3, R4, R5, corr);

  const int mmgrid = (N + 127) / 128;
  const int agrid = (N + 7) / 8;   // 2 nodes/wave, 4 waves/block

  // hs0 = (x W1) * dinv  [fp16, stride 128]  (MFMA)
  k_mm<float, 128, 0><<<mmgrid, 256, 0, stream>>>(x, W1, dinv, bufA, N);
  // h1 = relu(dinv*(gather+self) + b1)  [fp16, stride 128]
  k_agg<128, 0><<<agrid, 256, 0, stream>>>(bufA, offsets, col, dinv, b1, nullptr, bufB, N, 0);
  // g_scaled = (h1 Wc) * dinv, col100 = dinv seed  [fp16, stride 128]  (MFMA)
  k_mm<h16, 100, 1><<<mmgrid, 256, 0, stream>>>(bufB, Wc, dinv, bufA, N);
  // three chained S applications (pre-scaled); s-chain in cols 100..102
  k_agg<104, 1><<<agrid, 256, 0, stream>>>(bufA, offsets, col, dinv, nullptr, nullptr, bufB, N, 101);
  k_agg<104, 1><<<agrid, 256, 0, stream>>>(bufB, offsets, col, dinv, nullptr, nullptr, bufA, N, 102);
  k_agg<104, 1><<<agrid, 256, 0, stream>>>(bufA, offsets, col, dinv, nullptr, nullptr, bufB, N, -1);
  // final S application + corrections -> d_out [fp32, N x 100]
  k_agg<100, 2><<<agrid, 256, 0, stream>>>(bufB, offsets, col, dinv, nullptr, corr, (float*)d_out, N, -1);
}